// Round 12
// baseline (502.018 us; speedup 1.0000x reference)
//
#include <hip/hip_runtime.h>
#include <hip/hip_bf16.h>

#define BN 8
#define SS 1024
#define CC 512
#define HH 8
#define DD 64
#define PP 16
#define KT 1040

typedef __hip_bfloat16 bf16;
typedef unsigned char uchar;
typedef unsigned short ushort;
typedef __attribute__((ext_vector_type(8))) short short8;
typedef __attribute__((ext_vector_type(4))) float f32x4;
typedef __attribute__((ext_vector_type(2))) float f32x2;

__device__ __forceinline__ short f2s(float v){ bf16 b = __float2bfloat16(v); return *(short*)&b; }
__device__ __forceinline__ float s2f(short s){ bf16 b; *(short*)&b = s; return __bfloat162float(b); }
__device__ __forceinline__ uchar f2q(float v){          // f32 -> fp8 e4m3 byte
    return (uchar)__builtin_amdgcn_cvt_pk_fp8_f32(v, v, 0, false);
}

#define MFMA16(a,b,c)  __builtin_amdgcn_mfma_f32_16x16x32_bf16(a,b,c,0,0,0)
#define MFMAF8(a,b,c)  __builtin_amdgcn_mfma_f32_16x16x32_fp8_fp8(a,b,c,0,0,0)

// ---------------------------------------------------------------------------
// P0: weight pre-conversion to bf16 NT layouts.
// ---------------------------------------------------------------------------
__global__ __launch_bounds__(256) void prep_kernel(
    const float* __restrict__ fc_w, const float* __restrict__ c1w,
    const float* __restrict__ c2w, const float* __restrict__ Wq,
    const float* __restrict__ Wk, const float* __restrict__ Wv,
    short* __restrict__ Bfc, short* __restrict__ Bc1,
    short* __restrict__ Bc2, short* __restrict__ Bqkv)
{
    int i = blockIdx.x*256 + threadIdx.x;
    const int NFC = 512*512, NCV = 512*1536, NQ = 3*64*64;
    if (i < NFC) { Bfc[i] = f2s(fc_w[i]); return; }
    i -= NFC;
    if (i < NCV) {
        int o = i/1536, r = i%1536, dk = r>>9, ci = r&511;
        Bc1[i] = f2s(c1w[(o*512+ci)*3+dk]); return;
    }
    i -= NCV;
    if (i < NCV) {
        int o = i/1536, r = i%1536, dk = r>>9, ci = r&511;
        Bc2[i] = f2s(c2w[(o*512+ci)*3+dk]); return;
    }
    i -= NCV;
    if (i < NQ) {
        int w = i >> 12, rest = i & 4095;
        const float* W = (w==0)?Wq:(w==1)?Wk:Wv;
        Bqkv[i] = f2s(W[((rest>>6)&63)*64 + (rest&63)]);
    }
}

// ---------------------------------------------------------------------------
// K1: QKV projection, MFMA (bf16 compute). q/k out fp8, v out bf16.
// ---------------------------------------------------------------------------
__global__ __launch_bounds__(256) void qkv_mfma(
    const float* __restrict__ x, const short* __restrict__ Bqkv,
    uchar* __restrict__ qf, uchar* __restrict__ kf, short* __restrict__ vf)
{
    __shared__ short Xs[64*72];
    __shared__ short Ws[192*72];
    const int tid = threadIdx.x;
    const int m0 = blockIdx.x * 64;
    const int h = blockIdx.y;
    const int wave = tid >> 6, lane = tid & 63;
    const int lr = lane & 15, lq = lane >> 4;

    for (int i = tid; i < 1024; i += 256) {
        int r = i >> 4, cg = (i & 15)*4;
        float4 v = *(const float4*)(x + (size_t)(m0+r)*CC + h*64 + cg);
        Xs[r*72+cg+0] = f2s(v.x); Xs[r*72+cg+1] = f2s(v.y);
        Xs[r*72+cg+2] = f2s(v.z); Xs[r*72+cg+3] = f2s(v.w);
    }
    for (int i = tid; i < 3072; i += 256) {
        int r = i >> 4, cg = (i & 15)*4;
        *(short4*)(Ws + r*72 + cg) = *(const short4*)(Bqkv + (size_t)r*64 + cg);
    }
    __syncthreads();

    f32x4 acc[12];
    #pragma unroll
    for (int nt = 0; nt < 12; ++nt) acc[nt] = {0.f,0.f,0.f,0.f};
    #pragma unroll
    for (int ks = 0; ks < 2; ++ks) {
        int ko = ks*32 + lq*8;
        short8 a = *(const short8*)(Xs + (wave*16 + lr)*72 + ko);
        #pragma unroll
        for (int nt = 0; nt < 12; ++nt) {
            short8 b = *(const short8*)(Ws + (nt*16 + lr)*72 + ko);
            acc[nt] = MFMA16(a, b, acc[nt]);
        }
    }
    #pragma unroll
    for (int nt = 0; nt < 12; ++nt) {
        int ep = nt*16 + lr;
        int w = ep >> 6, e = ep & 63;
        #pragma unroll
        for (int reg = 0; reg < 4; ++reg) {
            int m = m0 + wave*16 + lq*4 + reg;
            int n = m >> 10, s = m & 1023;
            float v = acc[nt][reg];
            if (w == 0)      qf[((size_t)(n*HH+h)*SS + s)*DD + e] = f2q(v);
            else if (w == 1) kf[((size_t)(n*HH+h)*KT + s)*DD + e] = f2q(v);
            else             vf[((size_t)(n*HH+h)*KT + s)*DD + e] = f2s(v);
        }
    }
}

// ---------------------------------------------------------------------------
// K1b: persistent tokens -> kf(fp8)/vf(bf16) tails.
// ---------------------------------------------------------------------------
__global__ __launch_bounds__(256) void persist_kernel(
    const float* __restrict__ pk, const float* __restrict__ pv,
    uchar* __restrict__ kf, short* __restrict__ vf)
{
    int idx = blockIdx.x*256 + threadIdx.x;
    if (idx >= BN*HH*PP*DD) return;
    int d = idx & 63, p = (idx >> 6) & 15, h = (idx >> 10) & 7, n = idx >> 13;
    size_t dst = (((size_t)(n*HH+h))*KT + SS + p)*DD + d;
    size_t src = ((size_t)p*HH + h)*DD + d;
    kf[dst] = f2q(pk[src]);
    vf[dst] = f2s(pv[src]);
}

// ---------------------------------------------------------------------------
// K1c: V transpose + fp8 quant: vt[nh][d][k] (fp8) = vf[nh][k][d] (bf16).
// ---------------------------------------------------------------------------
__global__ __launch_bounds__(256) void vtrans_kernel(
    const short* __restrict__ vf, uchar* __restrict__ vt)
{
    __shared__ short Ts[64*65];
    const int tid = threadIdx.x;
    const int k0 = blockIdx.x * 64;
    const int nh = blockIdx.y;
    for (int i = tid; i < 1024; i += 256) {
        int kk = i >> 4, dg = (i & 15)*4;
        int k = k0 + kk;
        short4 v = {0,0,0,0};
        if (k < KT) v = *(const short4*)(vf + ((size_t)nh*KT + k)*DD + dg);
        Ts[(dg+0)*65 + kk] = v.x;
        Ts[(dg+1)*65 + kk] = v.y;
        Ts[(dg+2)*65 + kk] = v.z;
        Ts[(dg+3)*65 + kk] = v.w;
    }
    __syncthreads();
    for (int i = tid; i < 1024; i += 256) {
        int d = i >> 4, kg = (i & 15)*4;
        int k = k0 + kg;
        if (k < KT) {
            float f0 = s2f(Ts[d*65 + kg+0]), f1 = s2f(Ts[d*65 + kg+1]);
            float f2 = s2f(Ts[d*65 + kg+2]), f3 = s2f(Ts[d*65 + kg+3]);
            int p0 = __builtin_amdgcn_cvt_pk_fp8_f32(f0, f1, 0, false);
            int p1 = __builtin_amdgcn_cvt_pk_fp8_f32(f2, f3, 0, false);
            unsigned int w = (unsigned int)(p0 & 0xffff) | ((unsigned int)p1 << 16);
            *(unsigned int*)(vt + ((size_t)nh*DD + d)*KT + k) = w;
        }
    }
}

// ---------------------------------------------------------------------------
// K2: all-heads energy + PREMIX epilogue. Block = (ktile64, qtile16, n),
// fp8 MFMA over all 8 heads (16 MFMA/wave), then per-lane 8x8 premix and
// fp8 store of PREMIXED scores E'[(n,q),h,k]. LDS ~42 KB.
// ---------------------------------------------------------------------------
__global__ __launch_bounds__(256) void energy_premix(
    const uchar* __restrict__ qf, const uchar* __restrict__ kf,
    const float* __restrict__ th_pre, uchar* __restrict__ E)
{
    __shared__ uchar Qs[16*520];
    __shared__ uchar Ks[64*520];
    __shared__ float thp[64];
    const int tid = threadIdx.x;
    const int kt = blockIdx.x;      // 0..16
    const int qt = blockIdx.y;      // 0..63
    const int n  = blockIdx.z;      // 0..7
    const int wave = tid >> 6, lane = tid & 63;
    const int lr = lane & 15, lq = lane >> 4;
    const int q0 = qt*16, k0 = kt*64;

    if (tid < 64) thp[tid] = th_pre[tid];
    #pragma unroll
    for (int j = 0; j < 4; ++j) {               // Q: 16 rows x 512 B
        int i = tid + j*256;
        int r = i >> 6, c8 = i & 63;
        int h = c8 >> 3, d8 = (c8 & 7)*8;
        *(uint2*)(Qs + r*520 + h*64 + d8) =
            *(const uint2*)(qf + ((size_t)(n*HH+h)*SS + q0 + r)*DD + d8);
    }
    #pragma unroll
    for (int j = 0; j < 16; ++j) {              // K: 64 rows x 512 B
        int i = tid + j*256;
        int r = i >> 6, c8 = i & 63;
        int h = c8 >> 3, d8 = (c8 & 7)*8;
        int kc = k0 + r;
        uint2 v = {0u, 0u};
        if (kc < KT)
            v = *(const uint2*)(kf + ((size_t)(n*HH+h)*KT + kc)*DD + d8);
        *(uint2*)(Ks + r*520 + h*64 + d8) = v;
    }
    __syncthreads();

    f32x4 acc[8];
    #pragma unroll
    for (int g = 0; g < 8; ++g) acc[g] = {0.f,0.f,0.f,0.f};
    #pragma unroll
    for (int g = 0; g < 8; ++g) {
        #pragma unroll
        for (int ks = 0; ks < 2; ++ks) {
            long a = *(const long*)(Qs + lr*520 + g*64 + ks*32 + lq*8);
            long b = *(const long*)(Ks + (wave*16 + lr)*520 + g*64 + ks*32 + lq*8);
            acc[g] = MFMAF8(a, b, acc[g]);
        }
    }
    const int kcol = k0 + wave*16 + lr;
    if (kcol < KT) {
        #pragma unroll
        for (int reg = 0; reg < 4; ++reg) {
            int q = q0 + lq*4 + reg;
            uchar* dst = E + ((size_t)(n*SS + q)*HH)*KT + kcol;
            #pragma unroll
            for (int h = 0; h < 8; ++h) {
                float t = 0.f;
                #pragma unroll
                for (int g = 0; g < 8; ++g) t = fmaf(thp[h*8+g], acc[g][reg], t);
                dst[(size_t)h*KT] = f2q(t);
            }
        }
    }
}

// ---------------------------------------------------------------------------
// K3: THIN softmax (premixed input). Per column: -dist*c[h], mask, exp2,
// sum; postmix (1/l folded) out fp8. No-max safe (bounded exponents).
// ---------------------------------------------------------------------------
__global__ __launch_bounds__(256) void softmax_kernel(
    uchar* __restrict__ E, const int* __restrict__ mask,
    const float* __restrict__ th_pre, const float* __restrict__ th_post)
{
    __shared__ float thq[64];
    __shared__ float ch[8];              // (sum_g thp[h,g]*sl[g]) * invs*l2e
    __shared__ float wred[4][8];
    const int tid = threadIdx.x;
    const int wave = tid >> 6, lane = tid & 63;
    const int blk = blockIdx.x;          // n*SS + q
    const int n = blk >> 10, q = blk & 1023;
    const float invs = 0.044194173824159216f;   // 1/sqrt(512)
    const float l2e  = 1.4426950408889634f;
    const float k1   = invs*l2e;
    if (tid < 64) thq[tid] = th_post[tid];
    if (tid < 8) {
        const float sl[8] = {0.5f,0.25f,0.125f,0.0625f,
                             0.03125f,0.015625f,0.0078125f,0.00390625f};
        float c = 0.f;
        #pragma unroll
        for (int g = 0; g < 8; ++g) c += th_pre[tid*8+g]*sl[g];
        ch[tid] = c * k1;
    }
    __syncthreads();
    uchar* Eb = E + (size_t)blk*HH*KT;
    const int* mrow = mask + (size_t)n*SS*SS + (size_t)q*SS;

    f32x2 tp[2][8];
    float tl[8];
    float sm[8];
    #pragma unroll
    for (int g = 0; g < 8; ++g) { sm[g] = 0.f; tl[g] = 0.f; }

    #pragma unroll
    for (int jj = 0; jj < 2; ++jj) {
        const int k0 = (tid + jj*256)*2;          // adjacent pair
        const int2 mk = *(const int2*)(mrow + k0);
        const f32x2 dist = { fabsf((float)(q - k0)), fabsf((float)(q - k0 - 1)) };
        #pragma unroll
        for (int h = 0; h < 8; ++h) {
            ushort u = *(const ushort*)(Eb + h*KT + k0);
            f32x2 raw = __builtin_amdgcn_cvt_pk_f32_fp8((int)u, false);
            float tx = fmaf(raw.x, k1, -dist.x*ch[h]);
            float ty = fmaf(raw.y, k1, -dist.y*ch[h]);
            f32x2 e;
            e.x = (mk.x == 0) ? 0.f : exp2f(tx);
            e.y = (mk.y == 0) ? 0.f : exp2f(ty);
            tp[jj][h] = e;
            sm[h] += e.x + e.y;
        }
    }
    if (tid < 16) {                               // persistent keys
        const int k = 1024 + tid;
        #pragma unroll
        for (int h = 0; h < 8; ++h) {
            f32x2 r = __builtin_amdgcn_cvt_pk_f32_fp8((int)Eb[h*KT + k], false);
            float e = exp2f(r.x * k1);
            tl[h] = e;
            sm[h] += e;
        }
    }
    #pragma unroll
    for (int g = 0; g < 8; ++g) {
        #pragma unroll
        for (int off = 32; off > 0; off >>= 1)
            sm[g] += __shfl_xor(sm[g], off);
    }
    if (lane == 0) {
        #pragma unroll
        for (int g = 0; g < 8; ++g) wred[wave][g] = sm[g];
    }
    __syncthreads();
    float lred[8];
    #pragma unroll
    for (int g = 0; g < 8; ++g)
        lred[g] = 1.0f / (wred[0][g] + wred[1][g] + wred[2][g] + wred[3][g]);

    #pragma unroll
    for (int jj = 0; jj < 2; ++jj) {
        const int k0 = (tid + jj*256)*2;
        f32x2 e[8];
        #pragma unroll
        for (int g = 0; g < 8; ++g) {
            e[g].x = tp[jj][g].x * lred[g];
            e[g].y = tp[jj][g].y * lred[g];
        }
        #pragma unroll
        for (int h = 0; h < 8; ++h) {
            f32x2 t = {0.f, 0.f};
            #pragma unroll
            for (int g = 0; g < 8; ++g) {
                float c = thq[h*8 + g];
                t.x = fmaf(c, e[g].x, t.x);
                t.y = fmaf(c, e[g].y, t.y);
            }
            int p = __builtin_amdgcn_cvt_pk_fp8_f32(t.x, t.y, 0, false);
            *(ushort*)(Eb + h*KT + k0) = (ushort)p;
        }
    }
    if (tid < 16) {
        const int k = 1024 + tid;
        #pragma unroll
        for (int h = 0; h < 8; ++h) {
            float t = 0.f;
            #pragma unroll
            for (int g = 0; g < 8; ++g) t = fmaf(thq[h*8 + g], tl[g]*lred[g], t);
            Eb[h*KT + k] = f2q(t);
        }
    }
}

// ---------------------------------------------------------------------------
// K4: PV via fp8 MFMA (P' fp8 x V fp8), q-tile 32, register-prefetch dbuf.
// ---------------------------------------------------------------------------
__device__ __forceinline__ void pv_loadP(const uchar* __restrict__ E,
    int n, int h, int ql0, int kt, int tid, uint2* rp)
{
    int r = tid >> 3, cg = (tid & 7)*8;
    int k = kt*64 + cg;
    uint2 v = {0u, 0u};
    if (k < KT)
        v = *(const uint2*)(E + (((size_t)(n*SS + ql0 + r))*HH + h)*KT + k);
    rp[0] = v;
}
__device__ __forceinline__ void pv_loadV(const uchar* __restrict__ vt,
    int nh, int kt, int tid, uint2* rv)
{
    #pragma unroll
    for (int j = 0; j < 2; ++j) {
        int i = tid + j*256;
        int r = i >> 3, cg = (i & 7)*8;
        int k = kt*64 + cg;
        uint2 v = {0u, 0u};
        if (k < KT)
            v = *(const uint2*)(vt + ((size_t)nh*DD + r)*KT + k);
        rv[j] = v;
    }
}

__global__ __launch_bounds__(256) void pv_mfma(
    const uchar* __restrict__ E, const uchar* __restrict__ vt,
    short* __restrict__ AO)
{
    __shared__ uchar Ps[32*72];
    __shared__ uchar Vs[64*72];
    const int tid = threadIdx.x;
    const int ql0 = blockIdx.x * 32;
    const int nh = blockIdx.y;
    const int n = nh >> 3, h = nh & 7;
    const int wave = tid >> 6, lane = tid & 63;
    const int lr = lane & 15, lq = lane >> 4;
    const int mh = wave & 1, nb = (wave >> 1)*32;

    uint2 rp[1], rv[2];
    pv_loadP(E, n, h, ql0, 0, tid, rp);
    pv_loadV(vt, nh, 0, tid, rv);

    f32x4 acc[2];
    acc[0] = {0.f,0.f,0.f,0.f}; acc[1] = {0.f,0.f,0.f,0.f};

    for (int kt = 0; kt < 17; ++kt) {
        if (kt) __syncthreads();
        {
            int r = tid >> 3, cg = (tid & 7)*8;
            *(uint2*)(Ps + r*72 + cg) = rp[0];
        }
        #pragma unroll
        for (int j = 0; j < 2; ++j) {
            int i = tid + j*256;
            *(uint2*)(Vs + (i >> 3)*72 + (i & 7)*8) = rv[j];
        }
        __syncthreads();
        if (kt + 1 < 17) {
            pv_loadP(E, n, h, ql0, kt+1, tid, rp);
            pv_loadV(vt, nh, kt+1, tid, rv);
        }
        #pragma unroll
        for (int ks = 0; ks < 2; ++ks) {
            int ko = ks*32 + lq*8;
            long a = *(const long*)(Ps + (mh*16 + lr)*72 + ko);
            #pragma unroll
            for (int nt = 0; nt < 2; ++nt) {
                long b = *(const long*)(Vs + (nb + nt*16 + lr)*72 + ko);
                acc[nt] = MFMAF8(a, b, acc[nt]);
            }
        }
    }
    #pragma unroll
    for (int nt = 0; nt < 2; ++nt) {
        int d = nb + nt*16 + lr;
        #pragma unroll
        for (int reg = 0; reg < 4; ++reg) {
            int qg = ql0 + mh*16 + lq*4 + reg;
            AO[((size_t)(n*SS) + qg)*CC + h*64 + d] = f2s(acc[nt][reg]);
        }
    }
}

// ---------------------------------------------------------------------------
// K5: fc, 64x64 tile, XCD-swizzled, register-prefetch dbuf. K=512.
// ---------------------------------------------------------------------------
__device__ __forceinline__ void g_load4(const short* __restrict__ src,
    size_t rowstride, int row0, int col0, int tid, short4* r)
{
    #pragma unroll
    for (int j = 0; j < 4; ++j) {
        int i = tid + j*256;
        int rr = i >> 4, cg = (i & 15)*4;
        r[j] = *(const short4*)(src + (size_t)(row0 + rr)*rowstride + col0 + cg);
    }
}
__device__ __forceinline__ void lds_store4(short* __restrict__ dst,
    int tid, const short4* r)
{
    #pragma unroll
    for (int j = 0; j < 4; ++j) {
        int i = tid + j*256;
        *(short4*)(dst + (i >> 4)*72 + (i & 15)*4) = r[j];
    }
}

__global__ __launch_bounds__(256) void fc_mfma(
    const short* __restrict__ A, const short* __restrict__ Bt,
    const float* __restrict__ bias, const float* __restrict__ x,
    short* __restrict__ out)
{
    __shared__ short As[64*72];
    __shared__ short Bs[64*72];
    const int tid = threadIdx.x;
    const int lin = blockIdx.x + 8*blockIdx.y;      // grid (8,128)
    const int xcd = lin & 7, slot = lin >> 3;
    const int m0 = (xcd*16 + (slot & 15))*64;
    const int n0 = (slot >> 4)*64;
    const int wave = tid >> 6, lane = tid & 63;
    const int lr = lane & 15, lq = lane >> 4;

    short4 ra[4], rb[4];
    g_load4(A, CC, m0, 0, tid, ra);
    g_load4(Bt, CC, n0, 0, tid, rb);

    f32x4 acc[4];
    #pragma unroll
    for (int nt = 0; nt < 4; ++nt) acc[nt] = {0.f,0.f,0.f,0.f};

    for (int kt = 0; kt < CC; kt += 64) {
        if (kt) __syncthreads();
        lds_store4(As, tid, ra);
        lds_store4(Bs, tid, rb);
        __syncthreads();
        if (kt + 64 < CC) {
            g_load4(A, CC, m0, kt+64, tid, ra);
            g_load4(Bt, CC, n0, kt+64, tid, rb);
        }
        #pragma unroll
        for (int ks = 0; ks < 2; ++ks) {
            int ko = ks*32 + lq*8;
            short8 a = *(const short8*)(As + (wave*16 + lr)*72 + ko);
            #pragma unroll
            for (int nt = 0; nt < 4; ++nt) {
                short8 b = *(const short8*)(Bs + (nt*16 + lr)*72 + ko);
                acc[nt] = MFMA16(a, b, acc[nt]);
            }
        }
    }
    #pragma unroll
    for (int nt = 0; nt < 4; ++nt) {
        int nn = n0 + nt*16 + lr;
        #pragma unroll
        for (int reg = 0; reg < 4; ++reg) {
            int m = m0 + wave*16 + lq*4 + reg;
            out[(size_t)m*CC + nn] =
                f2s(acc[nt][reg] + bias[nn] + x[(size_t)m*CC + nn]);
        }
    }
}

// ---------------------------------------------------------------------------
// K6: causal conv as NT GEMM K=1536, 64x64, XCD-swizzled, prefetch dbuf.
// ---------------------------------------------------------------------------
__device__ __forceinline__ void conv_loadA(const short* __restrict__ A,
    int m0, int kt, int tid, short4* ra)
{
    const int shift = (kt >> 9) - 2;
    const int ci0 = kt & 511;
    #pragma unroll
    for (int j = 0; j < 4; ++j) {
        int i = tid + j*256;
        int rr = i >> 4, cg = (i & 15)*4;
        int m = m0 + rr;
        int s = m & (SS-1);
        short4 v = {0,0,0,0};
        if (s + shift >= 0)
            v = *(const short4*)(A + (size_t)(m + shift)*CC + ci0 + cg);
        ra[j] = v;
    }
}

__global__ __launch_bounds__(256) void conv_mfma(
    const short* __restrict__ A, const short* __restrict__ Bt,
    const float* __restrict__ bias, short* __restrict__ out)
{
    __shared__ short As[64*72];
    __shared__ short Bs[64*72];
    const int tid = threadIdx.x;
    const int lin = blockIdx.x + 8*blockIdx.y;      // grid (8,128)
    const int xcd = lin & 7, slot = lin >> 3;
    const int m0 = (xcd*16 + (slot & 15))*64;
    const int n0 = (slot >> 4)*64;
    const int wave = tid >> 6, lane = tid & 63;
    const int lr = lane & 15, lq = lane >> 4;

    short4 ra[4], rb[4];
    conv_loadA(A, m0, 0, tid, ra);
    g_load4(Bt, 1536, n0, 0, tid, rb);

    f32x4 acc[4];
    #pragma unroll
    for (int nt = 0; nt < 4; ++nt) acc[nt] = {0.f,0.f,0.f,0.f};

    for (int kt = 0; kt < 1536; kt += 64) {
        if (kt) __syncthreads();
        lds_store4(As, tid, ra);
        lds_store4(Bs, tid, rb);
        __syncthreads();
        if (kt + 64 < 1536) {
            conv_loadA(A, m0, kt+64, tid, ra);
            g_load4(Bt, 1536, n0, kt+64, tid, rb);
        }
        #pragma unroll
        for (int ks = 0; ks < 2; ++ks) {
            int ko = ks*32 + lq*8;
            short8 a = *(const short8*)(As + (wave*16 + lr)*72 + ko);
            #pragma unroll
            for (int nt = 0; nt < 4; ++nt) {
                short8 b = *(const short8*)(Bs + (nt*16 + lr)*72 + ko);
                acc[nt] = MFMA16(a, b, acc[nt]);
            }
        }
    }
    #pragma unroll
    for (int nt = 0; nt < 4; ++nt) {
        int nn = n0 + nt*16 + lr;
        #pragma unroll
        for (int reg = 0; reg < 4; ++reg) {
            int m = m0 + wave*16 + lq*4 + reg;
            float v = acc[nt][reg] + bias[nn];
            out[(size_t)m*CC + nn] = f2s(fmaxf(v, 0.f));
        }
    }
}

// ---------------------------------------------------------------------------
// K7: out = LN(relu(c2 + xres) masked) * g + b.  short2 in / float2 out.
// ---------------------------------------------------------------------------
__global__ __launch_bounds__(256) void final_kernel(
    const short* __restrict__ c2, const short* __restrict__ xres,
    const int* __restrict__ mask, const float* __restrict__ g,
    const float* __restrict__ b, float* __restrict__ out)
{
    __shared__ float red[256];
    const int tid = threadIdx.x;
    const int m = blockIdx.x;
    const int n = m >> 10, s = m & 1023;
    const int mk = mask[(size_t)n*SS*SS + (size_t)s*SS];
    const int c0 = tid*2;

    short2 ca = *(const short2*)(c2 + (size_t)m*CC + c0);
    short2 xa = *(const short2*)(xres + (size_t)m*CC + c0);
    float v0 = fmaxf(s2f(ca.x) + s2f(xa.x), 0.f);
    float v1 = fmaxf(s2f(ca.y) + s2f(xa.y), 0.f);
    if (mk == 0) { v0 = 0.f; v1 = 0.f; }

    red[tid] = v0 + v1;
    __syncthreads();
    for (int off = 128; off > 0; off >>= 1) {
        if (tid < off) red[tid] += red[tid + off];
        __syncthreads();
    }
    float mu = red[0] * (1.0f/512.0f);
    __syncthreads();
    float d0 = v0 - mu, d1 = v1 - mu;
    red[tid] = d0*d0 + d1*d1;
    __syncthreads();
    for (int off = 128; off > 0; off >>= 1) {
        if (tid < off) red[tid] += red[tid + off];
        __syncthreads();
    }
    float rstd = rsqrtf(red[0] * (1.0f/512.0f) + 1e-5f);
    float2 gg = *(const float2*)(g + c0);
    float2 bb = *(const float2*)(b + c0);
    float2 o;
    o.x = d0*rstd*gg.x + bb.x;
    o.y = d1*rstd*gg.y + bb.y;
    *(float2*)(out + (size_t)m*CC + c0) = o;
}

// ---------------------------------------------------------------------------
extern "C" void kernel_launch(void* const* d_in, const int* in_sizes, int n_in,
                              void* d_out, int out_size, void* d_ws, size_t ws_size,
                              hipStream_t stream)
{
    const float* x      = (const float*)d_in[0];
    const int*   mask   = (const int*)  d_in[1];
    const float* Wq     = (const float*)d_in[2];
    const float* Wk     = (const float*)d_in[3];
    const float* Wv     = (const float*)d_in[4];
    const float* pk     = (const float*)d_in[5];
    const float* pv     = (const float*)d_in[6];
    const float* th_pre = (const float*)d_in[7];
    const float* th_post= (const float*)d_in[8];
    const float* fc_w   = (const float*)d_in[9];
    const float* fc_b   = (const float*)d_in[10];
    const float* c1w    = (const float*)d_in[11];
    const float* c1b    = (const float*)d_in[12];
    const float* c2w    = (const float*)d_in[13];
    const float* c2b    = (const float*)d_in[14];
    const float* lng    = (const float*)d_in[15];
    const float* lnb    = (const float*)d_in[16];
    float* out = (float*)d_out;
    (void)in_sizes; (void)n_in; (void)out_size; (void)ws_size;

    char* ws = (char*)d_ws;
    const size_t SZ_Q  = (size_t)BN*HH*SS*DD;      //  4.19 MB (fp8)
    const size_t SZ_K  = (size_t)BN*HH*KT*DD;      //  4.26 MB (fp8)
    const size_t SZ_V  = (size_t)BN*HH*KT*DD*2;    //  8.52 MB (bf16)
    const size_t SZ_VT = (size_t)BN*HH*DD*KT;      //  4.26 MB (fp8)
    const size_t SZ_E  = (size_t)BN*SS*HH*KT;      // 68.2 MB (fp8)
    const size_t SZ_A  = (size_t)BN*SS*CC*2;       //  8.39 MB (bf16)

    uchar* qf  = (uchar*)(ws);
    uchar* kf  = (uchar*)(ws + SZ_Q);
    short* vf  = (short*)(ws + SZ_Q + SZ_K);
    uchar* vt  = (uchar*)(ws + SZ_Q + SZ_K + SZ_V);
    uchar* E   = (uchar*)(ws + SZ_Q + SZ_K + SZ_V + SZ_VT);
    short* AO  = (short*)(ws + SZ_Q + SZ_K + SZ_V + SZ_VT + SZ_E);
    char*  wend = ws + SZ_Q + SZ_K + SZ_V + SZ_VT + SZ_E + SZ_A;
    short* Bfc = (short*)(wend);
    short* Bc1 = (short*)(wend + 512*512*2);
    short* Bc2 = (short*)(wend + 512*512*2 + 512*1536*2);
    short* Bqkv= (short*)(wend + 512*512*2 + 2*512*1536*2);
    // Aliases (dead regions): xres over qf+kf (8.45 MB >= 8.39, dead after
    // energy); h1 over E (dead after pv); c2 over vf (dead after vtrans).
    short* xres = (short*)(ws);
    short* h1   = (short*)E;
    short* c2   = (short*)vf;
    // total ws ~= 101.4 MB (ws_size >= 256 MiB)

    {
        int total = 512*512 + 2*512*1536 + 3*64*64;
        prep_kernel<<<(total + 255)/256, 256, 0, stream>>>(
            fc_w, c1w, c2w, Wq, Wk, Wv, Bfc, Bc1, Bc2, Bqkv);
    }
    qkv_mfma<<<dim3(BN*SS/64, HH), 256, 0, stream>>>(x, Bqkv, qf, kf, vf);
    persist_kernel<<<(BN*HH*PP*DD + 255)/256, 256, 0, stream>>>(pk, pv, kf, vf);
    vtrans_kernel<<<dim3(17, BN*HH), 256, 0, stream>>>(vf, vt);

    energy_premix<<<dim3(17, SS/16, BN), 256, 0, stream>>>(qf, kf, th_pre, E);
    softmax_kernel<<<BN*SS, 256, 0, stream>>>(E, mask, th_pre, th_post);
    pv_mfma<<<dim3(SS/32, BN*HH), 256, 0, stream>>>(E, vt, AO);

    fc_mfma<<<dim3(8, 128), 256, 0, stream>>>(AO, Bfc, fc_b, x, xres);
    conv_mfma<<<dim3(8, 128), 256, 0, stream>>>(xres, Bc1, c1b, h1);
    conv_mfma<<<dim3(8, 128), 256, 0, stream>>>(h1, Bc2, c2b, c2);
    final_kernel<<<BN*SS, 256, 0, stream>>>(c2, xres, mask, lng, lnb, out);
}

// Round 13
// 327.205 us; speedup vs baseline: 1.5343x; 1.5343x over previous
//
#include <hip/hip_runtime.h>
#include <hip/hip_bf16.h>

#define BN 8
#define SS 1024
#define CC 512
#define HH 8
#define DD 64
#define PP 16
#define KT 1040

typedef __hip_bfloat16 bf16;
typedef unsigned char uchar;
typedef unsigned short ushort;
typedef __attribute__((ext_vector_type(8))) short short8;
typedef __attribute__((ext_vector_type(4))) float f32x4;
typedef __attribute__((ext_vector_type(2))) float f32x2;

__device__ __forceinline__ short f2s(float v){ bf16 b = __float2bfloat16(v); return *(short*)&b; }
__device__ __forceinline__ float s2f(short s){ bf16 b; *(short*)&b = s; return __bfloat162float(b); }
__device__ __forceinline__ uchar f2q(float v){          // f32 -> fp8 e4m3 byte
    return (uchar)__builtin_amdgcn_cvt_pk_fp8_f32(v, v, 0, false);
}

#define MFMA16(a,b,c)  __builtin_amdgcn_mfma_f32_16x16x32_bf16(a,b,c,0,0,0)
#define MFMAF8(a,b,c)  __builtin_amdgcn_mfma_f32_16x16x32_fp8_fp8(a,b,c,0,0,0)

// ---------------------------------------------------------------------------
// P0: weight pre-conversion. fc->bf16; conv weights -> fp8 scaled x16;
// qkv -> bf16.
// ---------------------------------------------------------------------------
__global__ __launch_bounds__(256) void prep_kernel(
    const float* __restrict__ fc_w, const float* __restrict__ c1w,
    const float* __restrict__ c2w, const float* __restrict__ Wq,
    const float* __restrict__ Wk, const float* __restrict__ Wv,
    short* __restrict__ Bfc, uchar* __restrict__ Bc1,
    uchar* __restrict__ Bc2, short* __restrict__ Bqkv)
{
    int i = blockIdx.x*256 + threadIdx.x;
    const int NFC = 512*512, NCV = 512*1536, NQ = 3*64*64;
    if (i < NFC) { Bfc[i] = f2s(fc_w[i]); return; }
    i -= NFC;
    if (i < NCV) {
        int o = i/1536, r = i%1536, dk = r>>9, ci = r&511;
        Bc1[i] = f2q(c1w[(o*512+ci)*3+dk] * 16.f); return;
    }
    i -= NCV;
    if (i < NCV) {
        int o = i/1536, r = i%1536, dk = r>>9, ci = r&511;
        Bc2[i] = f2q(c2w[(o*512+ci)*3+dk] * 16.f); return;
    }
    i -= NCV;
    if (i < NQ) {
        int w = i >> 12, rest = i & 4095;
        const float* W = (w==0)?Wq:(w==1)?Wk:Wv;
        Bqkv[i] = f2s(W[((rest>>6)&63)*64 + (rest&63)]);
    }
}

// ---------------------------------------------------------------------------
// K1: QKV projection, bf16 MFMA. q/k out fp8, v out bf16.
// ---------------------------------------------------------------------------
__global__ __launch_bounds__(256) void qkv_mfma(
    const float* __restrict__ x, const short* __restrict__ Bqkv,
    uchar* __restrict__ qf, uchar* __restrict__ kf, short* __restrict__ vf)
{
    __shared__ short Xs[64*72];
    __shared__ short Ws[192*72];
    const int tid = threadIdx.x;
    const int m0 = blockIdx.x * 64;
    const int h = blockIdx.y;
    const int wave = tid >> 6, lane = tid & 63;
    const int lr = lane & 15, lq = lane >> 4;

    for (int i = tid; i < 1024; i += 256) {
        int r = i >> 4, cg = (i & 15)*4;
        float4 v = *(const float4*)(x + (size_t)(m0+r)*CC + h*64 + cg);
        Xs[r*72+cg+0] = f2s(v.x); Xs[r*72+cg+1] = f2s(v.y);
        Xs[r*72+cg+2] = f2s(v.z); Xs[r*72+cg+3] = f2s(v.w);
    }
    for (int i = tid; i < 3072; i += 256) {
        int r = i >> 4, cg = (i & 15)*4;
        *(short4*)(Ws + r*72 + cg) = *(const short4*)(Bqkv + (size_t)r*64 + cg);
    }
    __syncthreads();

    f32x4 acc[12];
    #pragma unroll
    for (int nt = 0; nt < 12; ++nt) acc[nt] = {0.f,0.f,0.f,0.f};
    #pragma unroll
    for (int ks = 0; ks < 2; ++ks) {
        int ko = ks*32 + lq*8;
        short8 a = *(const short8*)(Xs + (wave*16 + lr)*72 + ko);
        #pragma unroll
        for (int nt = 0; nt < 12; ++nt) {
            short8 b = *(const short8*)(Ws + (nt*16 + lr)*72 + ko);
            acc[nt] = MFMA16(a, b, acc[nt]);
        }
    }
    #pragma unroll
    for (int nt = 0; nt < 12; ++nt) {
        int ep = nt*16 + lr;
        int w = ep >> 6, e = ep & 63;
        #pragma unroll
        for (int reg = 0; reg < 4; ++reg) {
            int m = m0 + wave*16 + lq*4 + reg;
            int n = m >> 10, s = m & 1023;
            float v = acc[nt][reg];
            if (w == 0)      qf[((size_t)(n*HH+h)*SS + s)*DD + e] = f2q(v);
            else if (w == 1) kf[((size_t)(n*HH+h)*KT + s)*DD + e] = f2q(v);
            else             vf[((size_t)(n*HH+h)*KT + s)*DD + e] = f2s(v);
        }
    }
}

// ---------------------------------------------------------------------------
// K1b: persistent tokens -> kf(fp8)/vf(bf16) tails.
// ---------------------------------------------------------------------------
__global__ __launch_bounds__(256) void persist_kernel(
    const float* __restrict__ pk, const float* __restrict__ pv,
    uchar* __restrict__ kf, short* __restrict__ vf)
{
    int idx = blockIdx.x*256 + threadIdx.x;
    if (idx >= BN*HH*PP*DD) return;
    int d = idx & 63, p = (idx >> 6) & 15, h = (idx >> 10) & 7, n = idx >> 13;
    size_t dst = (((size_t)(n*HH+h))*KT + SS + p)*DD + d;
    size_t src = ((size_t)p*HH + h)*DD + d;
    kf[dst] = f2q(pk[src]);
    vf[dst] = f2s(pv[src]);
}

// ---------------------------------------------------------------------------
// K1c: V transpose + fp8 quant: vt[nh][d][k] (fp8) = vf[nh][k][d] (bf16).
// ---------------------------------------------------------------------------
__global__ __launch_bounds__(256) void vtrans_kernel(
    const short* __restrict__ vf, uchar* __restrict__ vt)
{
    __shared__ short Ts[64*65];
    const int tid = threadIdx.x;
    const int k0 = blockIdx.x * 64;
    const int nh = blockIdx.y;
    for (int i = tid; i < 1024; i += 256) {
        int kk = i >> 4, dg = (i & 15)*4;
        int k = k0 + kk;
        short4 v = {0,0,0,0};
        if (k < KT) v = *(const short4*)(vf + ((size_t)nh*KT + k)*DD + dg);
        Ts[(dg+0)*65 + kk] = v.x;
        Ts[(dg+1)*65 + kk] = v.y;
        Ts[(dg+2)*65 + kk] = v.z;
        Ts[(dg+3)*65 + kk] = v.w;
    }
    __syncthreads();
    for (int i = tid; i < 1024; i += 256) {
        int d = i >> 4, kg = (i & 15)*4;
        int k = k0 + kg;
        if (k < KT) {
            float f0 = s2f(Ts[d*65 + kg+0]), f1 = s2f(Ts[d*65 + kg+1]);
            float f2 = s2f(Ts[d*65 + kg+2]), f3 = s2f(Ts[d*65 + kg+3]);
            int p0 = __builtin_amdgcn_cvt_pk_fp8_f32(f0, f1, 0, false);
            int p1 = __builtin_amdgcn_cvt_pk_fp8_f32(f2, f3, 0, false);
            unsigned int w = (unsigned int)(p0 & 0xffff) | ((unsigned int)p1 << 16);
            *(unsigned int*)(vt + ((size_t)nh*DD + d)*KT + k) = w;
        }
    }
}

// ---------------------------------------------------------------------------
// K2: energy, fp8 MFMA NT, r11 block shape. grid (17, S/64, BN*HH).
// Raw fp8 scores E[(n,q),h,k].
// ---------------------------------------------------------------------------
__global__ __launch_bounds__(256) void energy_mfma8(
    const uchar* __restrict__ qf, const uchar* __restrict__ kf,
    uchar* __restrict__ E)
{
    __shared__ uchar Qs[64*72];
    __shared__ uchar Ks[64*72];
    const int tid = threadIdx.x;
    const int kt = blockIdx.x;
    const int mt = blockIdx.y;
    const int nh = blockIdx.z;
    const int wave = tid >> 6, lane = tid & 63;
    const int lr = lane & 15, lq = lane >> 4;

    #pragma unroll
    for (int j = 0; j < 2; ++j) {
        int i = tid + j*256;
        int r = i >> 3, c8 = (i & 7)*8;
        *(uint2*)(Qs + r*72 + c8) =
            *(const uint2*)(qf + ((size_t)nh*SS + mt*64 + r)*DD + c8);
        int kcol = kt*64 + r;
        uint2 kv = {0u, 0u};
        if (kcol < KT)
            kv = *(const uint2*)(kf + ((size_t)nh*KT + kcol)*DD + c8);
        *(uint2*)(Ks + r*72 + c8) = kv;
    }
    __syncthreads();

    f32x4 acc[4];
    #pragma unroll
    for (int nt = 0; nt < 4; ++nt) acc[nt] = {0.f,0.f,0.f,0.f};
    #pragma unroll
    for (int ks = 0; ks < 2; ++ks) {
        int ko = ks*32 + lq*8;
        long a = *(const long*)(Qs + (wave*16 + lr)*72 + ko);
        #pragma unroll
        for (int nt = 0; nt < 4; ++nt) {
            long b = *(const long*)(Ks + (nt*16 + lr)*72 + ko);
            acc[nt] = MFMAF8(a, b, acc[nt]);
        }
    }
    const int n = nh >> 3, h = nh & 7;
    #pragma unroll
    for (int nt = 0; nt < 4; ++nt) {
        int kcol = kt*64 + nt*16 + lr;
        if (kcol >= KT) continue;
        #pragma unroll
        for (int reg = 0; reg < 4; ++reg) {
            int q = mt*64 + wave*16 + lq*4 + reg;
            E[(((size_t)(n*SS + q))*HH + h)*KT + kcol] = f2q(acc[nt][reg]);
        }
    }
}

// ---------------------------------------------------------------------------
// K3: softmax (r11 version): no-max, fp8 in/out, premix+postmix in-kernel.
// ---------------------------------------------------------------------------
__global__ __launch_bounds__(256) void softmax_kernel(
    uchar* __restrict__ E, const int* __restrict__ mask,
    const float* __restrict__ th_pre, const float* __restrict__ th_post)
{
    __shared__ float thp[64], thq[64];
    __shared__ float wred[4][8];
    const int tid = threadIdx.x;
    const int wave = tid >> 6, lane = tid & 63;
    const int blk = blockIdx.x;              // n*SS + q
    const int n = blk >> 10, q = blk & 1023;
    const float invs = 0.044194173824159216f;   // 1/sqrt(512)
    const float l2e  = 1.4426950408889634f;
    if (tid < 64) { thp[tid] = th_pre[tid]*(invs*l2e); thq[tid] = th_post[tid]; }
    __syncthreads();
    uchar* Eb = E + (size_t)blk*HH*KT;

    const float sl[8] = {0.5f,0.25f,0.125f,0.0625f,
                         0.03125f,0.015625f,0.0078125f,0.00390625f};
    const int* mrow = mask + (size_t)n*SS*SS + (size_t)q*SS;

    f32x2 tp[2][8];
    float tl[8];
    float sm[8];
    #pragma unroll
    for (int g = 0; g < 8; ++g) { sm[g] = 0.f; tl[g] = 0.f; }

    #pragma unroll
    for (int jj = 0; jj < 2; ++jj) {
        const int k0 = (tid + jj*256)*2;          // adjacent pair
        const int2 mk = *(const int2*)(mrow + k0);
        const f32x2 dist = { fabsf((float)(q - k0)), fabsf((float)(q - k0 - 1)) };
        f32x2 a[8];
        #pragma unroll
        for (int g = 0; g < 8; ++g) {
            ushort u = *(const ushort*)(Eb + g*KT + k0);
            f32x2 raw = __builtin_amdgcn_cvt_pk_f32_fp8((int)u, false);
            a[g].x = raw.x - dist.x*sl[g];
            a[g].y = raw.y - dist.y*sl[g];
        }
        #pragma unroll
        for (int h = 0; h < 8; ++h) {
            f32x2 t = {0.f, 0.f};
            #pragma unroll
            for (int g = 0; g < 8; ++g) {
                float c = thp[h*8 + g];      // pre-scaled: exponent base-2
                t.x = fmaf(c, a[g].x, t.x);
                t.y = fmaf(c, a[g].y, t.y);
            }
            f32x2 e;
            e.x = (mk.x == 0) ? 0.f : exp2f(t.x);
            e.y = (mk.y == 0) ? 0.f : exp2f(t.y);
            tp[jj][h] = e;
            sm[h] += e.x + e.y;
        }
    }
    if (tid < 16) {                               // persistent keys
        const int k = 1024 + tid;
        float a[8];
        #pragma unroll
        for (int g = 0; g < 8; ++g) {
            f32x2 r = __builtin_amdgcn_cvt_pk_f32_fp8((int)Eb[g*KT + k], false);
            a[g] = r.x;
        }
        #pragma unroll
        for (int h = 0; h < 8; ++h) {
            float t = 0.f;
            #pragma unroll
            for (int g = 0; g < 8; ++g) t = fmaf(thp[h*8 + g], a[g], t);
            float e = exp2f(t);
            tl[h] = e;
            sm[h] += e;
        }
    }
    #pragma unroll
    for (int g = 0; g < 8; ++g) {
        #pragma unroll
        for (int off = 32; off > 0; off >>= 1)
            sm[g] += __shfl_xor(sm[g], off);
    }
    if (lane == 0) {
        #pragma unroll
        for (int g = 0; g < 8; ++g) wred[wave][g] = sm[g];
    }
    __syncthreads();
    float lred[8];
    #pragma unroll
    for (int g = 0; g < 8; ++g)
        lred[g] = 1.0f / (wred[0][g] + wred[1][g] + wred[2][g] + wred[3][g]);

    #pragma unroll
    for (int jj = 0; jj < 2; ++jj) {
        const int k0 = (tid + jj*256)*2;
        f32x2 e[8];
        #pragma unroll
        for (int g = 0; g < 8; ++g) {
            e[g].x = tp[jj][g].x * lred[g];
            e[g].y = tp[jj][g].y * lred[g];
        }
        #pragma unroll
        for (int h = 0; h < 8; ++h) {
            f32x2 t = {0.f, 0.f};
            #pragma unroll
            for (int g = 0; g < 8; ++g) {
                float c = thq[h*8 + g];
                t.x = fmaf(c, e[g].x, t.x);
                t.y = fmaf(c, e[g].y, t.y);
            }
            int p = __builtin_amdgcn_cvt_pk_fp8_f32(t.x, t.y, 0, false);
            *(ushort*)(Eb + h*KT + k0) = (ushort)p;
        }
    }
    if (tid < 16) {
        const int k = 1024 + tid;
        float e[8];
        #pragma unroll
        for (int g = 0; g < 8; ++g) e[g] = tl[g] * lred[g];
        #pragma unroll
        for (int h = 0; h < 8; ++h) {
            float t = 0.f;
            #pragma unroll
            for (int g = 0; g < 8; ++g) t = fmaf(thq[h*8 + g], e[g], t);
            Eb[h*KT + k] = f2q(t);
        }
    }
}

// ---------------------------------------------------------------------------
// K4: PV via fp8 MFMA (P' fp8 x V fp8), q-tile 32, register-prefetch dbuf.
// ---------------------------------------------------------------------------
__device__ __forceinline__ void pv_loadP(const uchar* __restrict__ E,
    int n, int h, int ql0, int kt, int tid, uint2* rp)
{
    int r = tid >> 3, cg = (tid & 7)*8;
    int k = kt*64 + cg;
    uint2 v = {0u, 0u};
    if (k < KT)
        v = *(const uint2*)(E + (((size_t)(n*SS + ql0 + r))*HH + h)*KT + k);
    rp[0] = v;
}
__device__ __forceinline__ void pv_loadV(const uchar* __restrict__ vt,
    int nh, int kt, int tid, uint2* rv)
{
    #pragma unroll
    for (int j = 0; j < 2; ++j) {
        int i = tid + j*256;
        int r = i >> 3, cg = (i & 7)*8;
        int k = kt*64 + cg;
        uint2 v = {0u, 0u};
        if (k < KT)
            v = *(const uint2*)(vt + ((size_t)nh*DD + r)*KT + k);
        rv[j] = v;
    }
}

__global__ __launch_bounds__(256) void pv_mfma(
    const uchar* __restrict__ E, const uchar* __restrict__ vt,
    short* __restrict__ AO)
{
    __shared__ uchar Ps[32*72];
    __shared__ uchar Vs[64*72];
    const int tid = threadIdx.x;
    const int ql0 = blockIdx.x * 32;
    const int nh = blockIdx.y;
    const int n = nh >> 3, h = nh & 7;
    const int wave = tid >> 6, lane = tid & 63;
    const int lr = lane & 15, lq = lane >> 4;
    const int mh = wave & 1, nb = (wave >> 1)*32;

    uint2 rp[1], rv[2];
    pv_loadP(E, n, h, ql0, 0, tid, rp);
    pv_loadV(vt, nh, 0, tid, rv);

    f32x4 acc[2];
    acc[0] = {0.f,0.f,0.f,0.f}; acc[1] = {0.f,0.f,0.f,0.f};

    for (int kt = 0; kt < 17; ++kt) {
        if (kt) __syncthreads();
        {
            int r = tid >> 3, cg = (tid & 7)*8;
            *(uint2*)(Ps + r*72 + cg) = rp[0];
        }
        #pragma unroll
        for (int j = 0; j < 2; ++j) {
            int i = tid + j*256;
            *(uint2*)(Vs + (i >> 3)*72 + (i & 7)*8) = rv[j];
        }
        __syncthreads();
        if (kt + 1 < 17) {
            pv_loadP(E, n, h, ql0, kt+1, tid, rp);
            pv_loadV(vt, nh, kt+1, tid, rv);
        }
        #pragma unroll
        for (int ks = 0; ks < 2; ++ks) {
            int ko = ks*32 + lq*8;
            long a = *(const long*)(Ps + (mh*16 + lr)*72 + ko);
            #pragma unroll
            for (int nt = 0; nt < 2; ++nt) {
                long b = *(const long*)(Vs + (nb + nt*16 + lr)*72 + ko);
                acc[nt] = MFMAF8(a, b, acc[nt]);
            }
        }
    }
    #pragma unroll
    for (int nt = 0; nt < 2; ++nt) {
        int d = nb + nt*16 + lr;
        #pragma unroll
        for (int reg = 0; reg < 4; ++reg) {
            int qg = ql0 + mh*16 + lq*4 + reg;
            AO[((size_t)(n*SS) + qg)*CC + h*64 + d] = f2s(acc[nt][reg]);
        }
    }
}

// ---------------------------------------------------------------------------
// K5: fc, bf16 MFMA, 64x64, XCD-swizzled, prefetch. Writes xres (bf16) AND
// xres8 (fp8 copy for conv1's A operand).
// ---------------------------------------------------------------------------
__device__ __forceinline__ void g_load4(const short* __restrict__ src,
    size_t rowstride, int row0, int col0, int tid, short4* r)
{
    #pragma unroll
    for (int j = 0; j < 4; ++j) {
        int i = tid + j*256;
        int rr = i >> 4, cg = (i & 15)*4;
        r[j] = *(const short4*)(src + (size_t)(row0 + rr)*rowstride + col0 + cg);
    }
}
__device__ __forceinline__ void lds_store4(short* __restrict__ dst,
    int tid, const short4* r)
{
    #pragma unroll
    for (int j = 0; j < 4; ++j) {
        int i = tid + j*256;
        *(short4*)(dst + (i >> 4)*72 + (i & 15)*4) = r[j];
    }
}

__global__ __launch_bounds__(256) void fc_mfma(
    const short* __restrict__ A, const short* __restrict__ Bt,
    const float* __restrict__ bias, const float* __restrict__ x,
    short* __restrict__ out, uchar* __restrict__ out8)
{
    __shared__ short As[64*72];
    __shared__ short Bs[64*72];
    const int tid = threadIdx.x;
    const int lin = blockIdx.x + 8*blockIdx.y;      // grid (8,128)
    const int xcd = lin & 7, slot = lin >> 3;
    const int m0 = (xcd*16 + (slot & 15))*64;
    const int n0 = (slot >> 4)*64;
    const int wave = tid >> 6, lane = tid & 63;
    const int lr = lane & 15, lq = lane >> 4;

    short4 ra[4], rb[4];
    g_load4(A, CC, m0, 0, tid, ra);
    g_load4(Bt, CC, n0, 0, tid, rb);

    f32x4 acc[4];
    #pragma unroll
    for (int nt = 0; nt < 4; ++nt) acc[nt] = {0.f,0.f,0.f,0.f};

    for (int kt = 0; kt < CC; kt += 64) {
        if (kt) __syncthreads();
        lds_store4(As, tid, ra);
        lds_store4(Bs, tid, rb);
        __syncthreads();
        if (kt + 64 < CC) {
            g_load4(A, CC, m0, kt+64, tid, ra);
            g_load4(Bt, CC, n0, kt+64, tid, rb);
        }
        #pragma unroll
        for (int ks = 0; ks < 2; ++ks) {
            int ko = ks*32 + lq*8;
            short8 a = *(const short8*)(As + (wave*16 + lr)*72 + ko);
            #pragma unroll
            for (int nt = 0; nt < 4; ++nt) {
                short8 b = *(const short8*)(Bs + (nt*16 + lr)*72 + ko);
                acc[nt] = MFMA16(a, b, acc[nt]);
            }
        }
    }
    #pragma unroll
    for (int nt = 0; nt < 4; ++nt) {
        int nn = n0 + nt*16 + lr;
        #pragma unroll
        for (int reg = 0; reg < 4; ++reg) {
            int m = m0 + wave*16 + lq*4 + reg;
            float v = acc[nt][reg] + bias[nn] + x[(size_t)m*CC + nn];
            out[(size_t)m*CC + nn]  = f2s(v);
            out8[(size_t)m*CC + nn] = f2q(v);
        }
    }
}

// ---------------------------------------------------------------------------
// K6: causal conv as fp8 NT GEMM K=1536, 64x64, XCD-swizzled, prefetch.
// Weights pre-scaled x16 -> acc descaled x(1/16). f8out: h1 fp8 / c2 bf16.
// ---------------------------------------------------------------------------
__device__ __forceinline__ void conv_loadA8(const uchar* __restrict__ A,
    int m0, int kt, int tid, uint2* ra)
{
    const int shift = (kt >> 9) - 2;
    const int ci0 = kt & 511;
    #pragma unroll
    for (int j = 0; j < 2; ++j) {
        int i = tid + j*256;
        int rr = i >> 3, c8 = (i & 7)*8;
        int m = m0 + rr;
        int s = m & (SS-1);
        uint2 v = {0u, 0u};
        if (s + shift >= 0)
            v = *(const uint2*)(A + (size_t)(m + shift)*CC + ci0 + c8);
        ra[j] = v;
    }
}
__device__ __forceinline__ void g_load8(const uchar* __restrict__ src,
    size_t rowstride, int row0, int col0, int tid, uint2* r)
{
    #pragma unroll
    for (int j = 0; j < 2; ++j) {
        int i = tid + j*256;
        int rr = i >> 3, c8 = (i & 7)*8;
        r[j] = *(const uint2*)(src + (size_t)(row0 + rr)*rowstride + col0 + c8);
    }
}
__device__ __forceinline__ void lds_store8(uchar* __restrict__ dst,
    int tid, const uint2* r)
{
    #pragma unroll
    for (int j = 0; j < 2; ++j) {
        int i = tid + j*256;
        *(uint2*)(dst + (i >> 3)*72 + (i & 7)*8) = r[j];
    }
}

__global__ __launch_bounds__(256) void conv_mfma8(
    const uchar* __restrict__ A, const uchar* __restrict__ Bt,
    const float* __restrict__ bias, uchar* __restrict__ out8,
    short* __restrict__ out16, int f8out)
{
    __shared__ uchar As[64*72];
    __shared__ uchar Bs[64*72];
    const int tid = threadIdx.x;
    const int lin = blockIdx.x + 8*blockIdx.y;      // grid (8,128)
    const int xcd = lin & 7, slot = lin >> 3;
    const int m0 = (xcd*16 + (slot & 15))*64;
    const int n0 = (slot >> 4)*64;
    const int wave = tid >> 6, lane = tid & 63;
    const int lr = lane & 15, lq = lane >> 4;

    uint2 ra[2], rb[2];
    conv_loadA8(A, m0, 0, tid, ra);
    g_load8(Bt, 1536, n0, 0, tid, rb);

    f32x4 acc[4];
    #pragma unroll
    for (int nt = 0; nt < 4; ++nt) acc[nt] = {0.f,0.f,0.f,0.f};

    for (int kt = 0; kt < 1536; kt += 64) {
        if (kt) __syncthreads();
        lds_store8(As, tid, ra);
        lds_store8(Bs, tid, rb);
        __syncthreads();
        if (kt + 64 < 1536) {
            conv_loadA8(A, m0, kt+64, tid, ra);
            g_load8(Bt, 1536, n0, kt+64, tid, rb);
        }
        #pragma unroll
        for (int ks = 0; ks < 2; ++ks) {
            int ko = ks*32 + lq*8;
            long a = *(const long*)(As + (wave*16 + lr)*72 + ko);
            #pragma unroll
            for (int nt = 0; nt < 4; ++nt) {
                long b = *(const long*)(Bs + (nt*16 + lr)*72 + ko);
                acc[nt] = MFMAF8(a, b, acc[nt]);
            }
        }
    }
    #pragma unroll
    for (int nt = 0; nt < 4; ++nt) {
        int nn = n0 + nt*16 + lr;
        #pragma unroll
        for (int reg = 0; reg < 4; ++reg) {
            int m = m0 + wave*16 + lq*4 + reg;
            float v = fmaxf(acc[nt][reg]*0.0625f + bias[nn], 0.f);
            if (f8out) out8[(size_t)m*CC + nn]  = f2q(v);
            else       out16[(size_t)m*CC + nn] = f2s(v);
        }
    }
}

// ---------------------------------------------------------------------------
// K7: out = LN(relu(c2 + xres) masked) * g + b.  short2 in / float2 out.
// ---------------------------------------------------------------------------
__global__ __launch_bounds__(256) void final_kernel(
    const short* __restrict__ c2, const short* __restrict__ xres,
    const int* __restrict__ mask, const float* __restrict__ g,
    const float* __restrict__ b, float* __restrict__ out)
{
    __shared__ float red[256];
    const int tid = threadIdx.x;
    const int m = blockIdx.x;
    const int n = m >> 10, s = m & 1023;
    const int mk = mask[(size_t)n*SS*SS + (size_t)s*SS];
    const int c0 = tid*2;

    short2 ca = *(const short2*)(c2 + (size_t)m*CC + c0);
    short2 xa = *(const short2*)(xres + (size_t)m*CC + c0);
    float v0 = fmaxf(s2f(ca.x) + s2f(xa.x), 0.f);
    float v1 = fmaxf(s2f(ca.y) + s2f(xa.y), 0.f);
    if (mk == 0) { v0 = 0.f; v1 = 0.f; }

    red[tid] = v0 + v1;
    __syncthreads();
    for (int off = 128; off > 0; off >>= 1) {
        if (tid < off) red[tid] += red[tid + off];
        __syncthreads();
    }
    float mu = red[0] * (1.0f/512.0f);
    __syncthreads();
    float d0 = v0 - mu, d1 = v1 - mu;
    red[tid] = d0*d0 + d1*d1;
    __syncthreads();
    for (int off = 128; off > 0; off >>= 1) {
        if (tid < off) red[tid] += red[tid + off];
        __syncthreads();
    }
    float rstd = rsqrtf(red[0] * (1.0f/512.0f) + 1e-5f);
    float2 gg = *(const float2*)(g + c0);
    float2 bb = *(const float2*)(b + c0);
    float2 o;
    o.x = d0*rstd*gg.x + bb.x;
    o.y = d1*rstd*gg.y + bb.y;
    *(float2*)(out + (size_t)m*CC + c0) = o;
}

// ---------------------------------------------------------------------------
extern "C" void kernel_launch(void* const* d_in, const int* in_sizes, int n_in,
                              void* d_out, int out_size, void* d_ws, size_t ws_size,
                              hipStream_t stream)
{
    const float* x      = (const float*)d_in[0];
    const int*   mask   = (const int*)  d_in[1];
    const float* Wq     = (const float*)d_in[2];
    const float* Wk     = (const float*)d_in[3];
    const float* Wv     = (const float*)d_in[4];
    const float* pk     = (const float*)d_in[5];
    const float* pv     = (const float*)d_in[6];
    const float* th_pre = (const float*)d_in[7];
    const float* th_post= (const float*)d_in[8];
    const float* fc_w   = (const float*)d_in[9];
    const float* fc_b   = (const float*)d_in[10];
    const float* c1w    = (const float*)d_in[11];
    const float* c1b    = (const float*)d_in[12];
    const float* c2w    = (const float*)d_in[13];
    const float* c2b    = (const float*)d_in[14];
    const float* lng    = (const float*)d_in[15];
    const float* lnb    = (const float*)d_in[16];
    float* out = (float*)d_out;
    (void)in_sizes; (void)n_in; (void)out_size; (void)ws_size;

    char* ws = (char*)d_ws;
    const size_t SZ_Q  = (size_t)BN*HH*SS*DD;      //  4.19 MB (fp8)
    const size_t SZ_K  = (size_t)BN*HH*KT*DD;      //  4.26 MB (fp8)
    const size_t SZ_V  = (size_t)BN*HH*KT*DD*2;    //  8.52 MB (bf16)
    const size_t SZ_VT = (size_t)BN*HH*DD*KT;      //  4.26 MB (fp8)
    const size_t SZ_E  = (size_t)BN*SS*HH*KT;      // 68.2 MB (fp8)
    const size_t SZ_A  = (size_t)BN*SS*CC*2;       //  8.39 MB (bf16)
    const size_t SZ_A8 = (size_t)BN*SS*CC;         //  4.19 MB (fp8)

    uchar* qf  = (uchar*)(ws);
    uchar* kf  = (uchar*)(ws + SZ_Q);
    short* vf  = (short*)(ws + SZ_Q + SZ_K);
    uchar* vt  = (uchar*)(ws + SZ_Q + SZ_K + SZ_V);
    uchar* E   = (uchar*)(ws + SZ_Q + SZ_K + SZ_V + SZ_VT);
    short* AO  = (short*)(ws + SZ_Q + SZ_K + SZ_V + SZ_VT + SZ_E);
    char*  wend = ws + SZ_Q + SZ_K + SZ_V + SZ_VT + SZ_E + SZ_A;
    short* Bfc = (short*)(wend);
    uchar* Bc1 = (uchar*)(wend + 512*512*2);
    uchar* Bc2 = (uchar*)(wend + 512*512*2 + 512*1536);
    short* Bqkv= (short*)(wend + 512*512*2 + 2*512*1536);
    uchar* xres8 = (uchar*)(wend + 512*512*2 + 2*512*1536 + 3*64*64*2);
    // Aliases (dead regions): xres(bf16) over qf+kf (8.45 >= 8.39, dead after
    // energy); h1(fp8) over E (dead after pv); c2(bf16) over vf (dead after
    // vtrans).
    short* xres = (short*)(ws);
    uchar* h18  = (uchar*)E;
    short* c2   = (short*)vf;
    // total ws ~= 106 MB (ws_size >= 256 MiB)

    {
        int total = 512*512 + 2*512*1536 + 3*64*64;
        prep_kernel<<<(total + 255)/256, 256, 0, stream>>>(
            fc_w, c1w, c2w, Wq, Wk, Wv, Bfc, Bc1, Bc2, Bqkv);
    }
    qkv_mfma<<<dim3(BN*SS/64, HH), 256, 0, stream>>>(x, Bqkv, qf, kf, vf);
    persist_kernel<<<(BN*HH*PP*DD + 255)/256, 256, 0, stream>>>(pk, pv, kf, vf);
    vtrans_kernel<<<dim3(17, BN*HH), 256, 0, stream>>>(vf, vt);

    energy_mfma8<<<dim3(17, SS/64, BN*HH), 256, 0, stream>>>(qf, kf, E);
    softmax_kernel<<<BN*SS, 256, 0, stream>>>(E, mask, th_pre, th_post);
    pv_mfma<<<dim3(SS/32, BN*HH), 256, 0, stream>>>(E, vt, AO);

    fc_mfma<<<dim3(8, 128), 256, 0, stream>>>(AO, Bfc, fc_b, x, xres, xres8);
    conv_mfma8<<<dim3(8, 128), 256, 0, stream>>>(xres8, Bc1, c1b, h18, (short*)nullptr, 1);
    conv_mfma8<<<dim3(8, 128), 256, 0, stream>>>(h18, Bc2, c2b, (uchar*)nullptr, c2, 0);
    final_kernel<<<BN*SS, 256, 0, stream>>>(c2, xres, mask, lng, lnb, out);
}

// Round 14
// 314.788 us; speedup vs baseline: 1.5948x; 1.0394x over previous
//
#include <hip/hip_runtime.h>
#include <hip/hip_bf16.h>

#define BN 8
#define SS 1024
#define CC 512
#define HH 8
#define DD 64
#define PP 16
#define KT 1040

typedef __hip_bfloat16 bf16;
typedef unsigned char uchar;
typedef unsigned short ushort;
typedef __attribute__((ext_vector_type(8))) short short8;
typedef __attribute__((ext_vector_type(4))) float f32x4;
typedef __attribute__((ext_vector_type(2))) float f32x2;

__device__ __forceinline__ short f2s(float v){ bf16 b = __float2bfloat16(v); return *(short*)&b; }
__device__ __forceinline__ float s2f(short s){ bf16 b; *(short*)&b = s; return __bfloat162float(b); }
__device__ __forceinline__ uchar f2q(float v){          // f32 -> fp8 e4m3 byte
    return (uchar)__builtin_amdgcn_cvt_pk_fp8_f32(v, v, 0, false);
}

#define MFMA16(a,b,c)  __builtin_amdgcn_mfma_f32_16x16x32_bf16(a,b,c,0,0,0)
#define MFMAF8(a,b,c)  __builtin_amdgcn_mfma_f32_16x16x32_fp8_fp8(a,b,c,0,0,0)

// ---------------------------------------------------------------------------
// P0: weight pre-conversion. fc -> bf16 with th_post FOLDED IN:
//   Bfc[c, g*64+d] = sum_h fc_w[c, h*64+d] * th_post[h,g]
// conv weights -> fp8 scaled x16; qkv -> bf16.
// ---------------------------------------------------------------------------
__global__ __launch_bounds__(256) void prep_kernel(
    const float* __restrict__ fc_w, const float* __restrict__ c1w,
    const float* __restrict__ c2w, const float* __restrict__ Wq,
    const float* __restrict__ Wk, const float* __restrict__ Wv,
    const float* __restrict__ th_post,
    short* __restrict__ Bfc, uchar* __restrict__ Bc1,
    uchar* __restrict__ Bc2, short* __restrict__ Bqkv)
{
    int i = blockIdx.x*256 + threadIdx.x;
    const int NFC = 512*512, NCV = 512*1536, NQ = 3*64*64;
    if (i < NFC) {
        int c = i >> 9, r = i & 511;
        int g = r >> 6, d = r & 63;
        float s = 0.f;
        #pragma unroll
        for (int h = 0; h < 8; ++h)
            s += fc_w[(size_t)c*512 + h*64 + d] * th_post[h*8 + g];
        Bfc[i] = f2s(s);
        return;
    }
    i -= NFC;
    if (i < NCV) {
        int o = i/1536, r = i%1536, dk = r>>9, ci = r&511;
        Bc1[i] = f2q(c1w[(o*512+ci)*3+dk] * 16.f); return;
    }
    i -= NCV;
    if (i < NCV) {
        int o = i/1536, r = i%1536, dk = r>>9, ci = r&511;
        Bc2[i] = f2q(c2w[(o*512+ci)*3+dk] * 16.f); return;
    }
    i -= NCV;
    if (i < NQ) {
        int w = i >> 12, rest = i & 4095;
        const float* W = (w==0)?Wq:(w==1)?Wk:Wv;
        Bqkv[i] = f2s(W[((rest>>6)&63)*64 + (rest&63)]);
    }
}

// ---------------------------------------------------------------------------
// K1: QKV projection, bf16 MFMA. q/k out fp8, v out bf16.
// ---------------------------------------------------------------------------
__global__ __launch_bounds__(256) void qkv_mfma(
    const float* __restrict__ x, const short* __restrict__ Bqkv,
    uchar* __restrict__ qf, uchar* __restrict__ kf, short* __restrict__ vf)
{
    __shared__ short Xs[64*72];
    __shared__ short Ws[192*72];
    const int tid = threadIdx.x;
    const int m0 = blockIdx.x * 64;
    const int h = blockIdx.y;
    const int wave = tid >> 6, lane = tid & 63;
    const int lr = lane & 15, lq = lane >> 4;

    for (int i = tid; i < 1024; i += 256) {
        int r = i >> 4, cg = (i & 15)*4;
        float4 v = *(const float4*)(x + (size_t)(m0+r)*CC + h*64 + cg);
        Xs[r*72+cg+0] = f2s(v.x); Xs[r*72+cg+1] = f2s(v.y);
        Xs[r*72+cg+2] = f2s(v.z); Xs[r*72+cg+3] = f2s(v.w);
    }
    for (int i = tid; i < 3072; i += 256) {
        int r = i >> 4, cg = (i & 15)*4;
        *(short4*)(Ws + r*72 + cg) = *(const short4*)(Bqkv + (size_t)r*64 + cg);
    }
    __syncthreads();

    f32x4 acc[12];
    #pragma unroll
    for (int nt = 0; nt < 12; ++nt) acc[nt] = {0.f,0.f,0.f,0.f};
    #pragma unroll
    for (int ks = 0; ks < 2; ++ks) {
        int ko = ks*32 + lq*8;
        short8 a = *(const short8*)(Xs + (wave*16 + lr)*72 + ko);
        #pragma unroll
        for (int nt = 0; nt < 12; ++nt) {
            short8 b = *(const short8*)(Ws + (nt*16 + lr)*72 + ko);
            acc[nt] = MFMA16(a, b, acc[nt]);
        }
    }
    #pragma unroll
    for (int nt = 0; nt < 12; ++nt) {
        int ep = nt*16 + lr;
        int w = ep >> 6, e = ep & 63;
        #pragma unroll
        for (int reg = 0; reg < 4; ++reg) {
            int m = m0 + wave*16 + lq*4 + reg;
            int n = m >> 10, s = m & 1023;
            float v = acc[nt][reg];
            if (w == 0)      qf[((size_t)(n*HH+h)*SS + s)*DD + e] = f2q(v);
            else if (w == 1) kf[((size_t)(n*HH+h)*KT + s)*DD + e] = f2q(v);
            else             vf[((size_t)(n*HH+h)*KT + s)*DD + e] = f2s(v);
        }
    }
}

// ---------------------------------------------------------------------------
// K1b: persistent tokens -> kf(fp8)/vf(bf16) tails.
// ---------------------------------------------------------------------------
__global__ __launch_bounds__(256) void persist_kernel(
    const float* __restrict__ pk, const float* __restrict__ pv,
    uchar* __restrict__ kf, short* __restrict__ vf)
{
    int idx = blockIdx.x*256 + threadIdx.x;
    if (idx >= BN*HH*PP*DD) return;
    int d = idx & 63, p = (idx >> 6) & 15, h = (idx >> 10) & 7, n = idx >> 13;
    size_t dst = (((size_t)(n*HH+h))*KT + SS + p)*DD + d;
    size_t src = ((size_t)p*HH + h)*DD + d;
    kf[dst] = f2q(pk[src]);
    vf[dst] = f2s(pv[src]);
}

// ---------------------------------------------------------------------------
// K1c: V transpose + fp8 quant: vt[nh][d][k] (fp8) = vf[nh][k][d] (bf16).
// ---------------------------------------------------------------------------
__global__ __launch_bounds__(256) void vtrans_kernel(
    const short* __restrict__ vf, uchar* __restrict__ vt)
{
    __shared__ short Ts[64*65];
    const int tid = threadIdx.x;
    const int k0 = blockIdx.x * 64;
    const int nh = blockIdx.y;
    for (int i = tid; i < 1024; i += 256) {
        int kk = i >> 4, dg = (i & 15)*4;
        int k = k0 + kk;
        short4 v = {0,0,0,0};
        if (k < KT) v = *(const short4*)(vf + ((size_t)nh*KT + k)*DD + dg);
        Ts[(dg+0)*65 + kk] = v.x;
        Ts[(dg+1)*65 + kk] = v.y;
        Ts[(dg+2)*65 + kk] = v.z;
        Ts[(dg+3)*65 + kk] = v.w;
    }
    __syncthreads();
    for (int i = tid; i < 1024; i += 256) {
        int d = i >> 4, kg = (i & 15)*4;
        int k = k0 + kg;
        if (k < KT) {
            float f0 = s2f(Ts[d*65 + kg+0]), f1 = s2f(Ts[d*65 + kg+1]);
            float f2 = s2f(Ts[d*65 + kg+2]), f3 = s2f(Ts[d*65 + kg+3]);
            int p0 = __builtin_amdgcn_cvt_pk_fp8_f32(f0, f1, 0, false);
            int p1 = __builtin_amdgcn_cvt_pk_fp8_f32(f2, f3, 0, false);
            unsigned int w = (unsigned int)(p0 & 0xffff) | ((unsigned int)p1 << 16);
            *(unsigned int*)(vt + ((size_t)nh*DD + d)*KT + k) = w;
        }
    }
}

// ---------------------------------------------------------------------------
// K2: energy, fp8 MFMA NT. grid (17, S/64, BN*HH). Raw fp8 scores.
// ---------------------------------------------------------------------------
__global__ __launch_bounds__(256) void energy_mfma8(
    const uchar* __restrict__ qf, const uchar* __restrict__ kf,
    uchar* __restrict__ E)
{
    __shared__ uchar Qs[64*72];
    __shared__ uchar Ks[64*72];
    const int tid = threadIdx.x;
    const int kt = blockIdx.x;
    const int mt = blockIdx.y;
    const int nh = blockIdx.z;
    const int wave = tid >> 6, lane = tid & 63;
    const int lr = lane & 15, lq = lane >> 4;

    #pragma unroll
    for (int j = 0; j < 2; ++j) {
        int i = tid + j*256;
        int r = i >> 3, c8 = (i & 7)*8;
        *(uint2*)(Qs + r*72 + c8) =
            *(const uint2*)(qf + ((size_t)nh*SS + mt*64 + r)*DD + c8);
        int kcol = kt*64 + r;
        uint2 kv = {0u, 0u};
        if (kcol < KT)
            kv = *(const uint2*)(kf + ((size_t)nh*KT + kcol)*DD + c8);
        *(uint2*)(Ks + r*72 + c8) = kv;
    }
    __syncthreads();

    f32x4 acc[4];
    #pragma unroll
    for (int nt = 0; nt < 4; ++nt) acc[nt] = {0.f,0.f,0.f,0.f};
    #pragma unroll
    for (int ks = 0; ks < 2; ++ks) {
        int ko = ks*32 + lq*8;
        long a = *(const long*)(Qs + (wave*16 + lr)*72 + ko);
        #pragma unroll
        for (int nt = 0; nt < 4; ++nt) {
            long b = *(const long*)(Ks + (nt*16 + lr)*72 + ko);
            acc[nt] = MFMAF8(a, b, acc[nt]);
        }
    }
    const int n = nh >> 3, h = nh & 7;
    #pragma unroll
    for (int nt = 0; nt < 4; ++nt) {
        int kcol = kt*64 + nt*16 + lr;
        if (kcol >= KT) continue;
        #pragma unroll
        for (int reg = 0; reg < 4; ++reg) {
            int q = mt*64 + wave*16 + lq*4 + reg;
            E[(((size_t)(n*SS + q))*HH + h)*KT + kcol] = f2q(acc[nt][reg]);
        }
    }
}

// ---------------------------------------------------------------------------
// K3: softmax: no-max, fp8 in/out, premix in-kernel, NO postmix (folded into
// fc weights). Stores normalized probs e*lred per head-row.
// ---------------------------------------------------------------------------
__global__ __launch_bounds__(256) void softmax_kernel(
    uchar* __restrict__ E, const int* __restrict__ mask,
    const float* __restrict__ th_pre)
{
    __shared__ float thp[64];
    __shared__ float wred[4][8];
    const int tid = threadIdx.x;
    const int wave = tid >> 6, lane = tid & 63;
    const int blk = blockIdx.x;              // n*SS + q
    const int n = blk >> 10, q = blk & 1023;
    const float invs = 0.044194173824159216f;   // 1/sqrt(512)
    const float l2e  = 1.4426950408889634f;
    if (tid < 64) thp[tid] = th_pre[tid]*(invs*l2e);
    __syncthreads();
    uchar* Eb = E + (size_t)blk*HH*KT;

    const float sl[8] = {0.5f,0.25f,0.125f,0.0625f,
                         0.03125f,0.015625f,0.0078125f,0.00390625f};
    const int* mrow = mask + (size_t)n*SS*SS + (size_t)q*SS;

    f32x2 tp[2][8];
    float tl[8];
    float sm[8];
    #pragma unroll
    for (int g = 0; g < 8; ++g) { sm[g] = 0.f; tl[g] = 0.f; }

    #pragma unroll
    for (int jj = 0; jj < 2; ++jj) {
        const int k0 = (tid + jj*256)*2;          // adjacent pair
        const int2 mk = *(const int2*)(mrow + k0);
        const f32x2 dist = { fabsf((float)(q - k0)), fabsf((float)(q - k0 - 1)) };
        f32x2 a[8];
        #pragma unroll
        for (int g = 0; g < 8; ++g) {
            ushort u = *(const ushort*)(Eb + g*KT + k0);
            f32x2 raw = __builtin_amdgcn_cvt_pk_f32_fp8((int)u, false);
            a[g].x = raw.x - dist.x*sl[g];
            a[g].y = raw.y - dist.y*sl[g];
        }
        #pragma unroll
        for (int h = 0; h < 8; ++h) {
            f32x2 t = {0.f, 0.f};
            #pragma unroll
            for (int g = 0; g < 8; ++g) {
                float c = thp[h*8 + g];      // pre-scaled: exponent base-2
                t.x = fmaf(c, a[g].x, t.x);
                t.y = fmaf(c, a[g].y, t.y);
            }
            f32x2 e;
            e.x = (mk.x == 0) ? 0.f : exp2f(t.x);
            e.y = (mk.y == 0) ? 0.f : exp2f(t.y);
            tp[jj][h] = e;
            sm[h] += e.x + e.y;
        }
    }
    if (tid < 16) {                               // persistent keys
        const int k = 1024 + tid;
        float a[8];
        #pragma unroll
        for (int g = 0; g < 8; ++g) {
            f32x2 r = __builtin_amdgcn_cvt_pk_f32_fp8((int)Eb[g*KT + k], false);
            a[g] = r.x;
        }
        #pragma unroll
        for (int h = 0; h < 8; ++h) {
            float t = 0.f;
            #pragma unroll
            for (int g = 0; g < 8; ++g) t = fmaf(thp[h*8 + g], a[g], t);
            float e = exp2f(t);
            tl[h] = e;
            sm[h] += e;
        }
    }
    #pragma unroll
    for (int g = 0; g < 8; ++g) {
        #pragma unroll
        for (int off = 32; off > 0; off >>= 1)
            sm[g] += __shfl_xor(sm[g], off);
    }
    if (lane == 0) {
        #pragma unroll
        for (int g = 0; g < 8; ++g) wred[wave][g] = sm[g];
    }
    __syncthreads();
    float lred[8];
    #pragma unroll
    for (int g = 0; g < 8; ++g)
        lred[g] = 1.0f / (wred[0][g] + wred[1][g] + wred[2][g] + wred[3][g]);

    // normalized probs out (postmix folded into fc weights)
    #pragma unroll
    for (int jj = 0; jj < 2; ++jj) {
        const int k0 = (tid + jj*256)*2;
        #pragma unroll
        for (int g = 0; g < 8; ++g) {
            int p = __builtin_amdgcn_cvt_pk_fp8_f32(
                tp[jj][g].x * lred[g], tp[jj][g].y * lred[g], 0, false);
            *(ushort*)(Eb + g*KT + k0) = (ushort)p;
        }
    }
    if (tid < 16) {
        const int k = 1024 + tid;
        #pragma unroll
        for (int g = 0; g < 8; ++g)
            Eb[g*KT + k] = f2q(tl[g] * lred[g]);
    }
}

// ---------------------------------------------------------------------------
// K4: PV via fp8 MFMA (P fp8 x V fp8), q-tile 32, register-prefetch dbuf.
// ---------------------------------------------------------------------------
__device__ __forceinline__ void pv_loadP(const uchar* __restrict__ E,
    int n, int h, int ql0, int kt, int tid, uint2* rp)
{
    int r = tid >> 3, cg = (tid & 7)*8;
    int k = kt*64 + cg;
    uint2 v = {0u, 0u};
    if (k < KT)
        v = *(const uint2*)(E + (((size_t)(n*SS + ql0 + r))*HH + h)*KT + k);
    rp[0] = v;
}
__device__ __forceinline__ void pv_loadV(const uchar* __restrict__ vt,
    int nh, int kt, int tid, uint2* rv)
{
    #pragma unroll
    for (int j = 0; j < 2; ++j) {
        int i = tid + j*256;
        int r = i >> 3, cg = (i & 7)*8;
        int k = kt*64 + cg;
        uint2 v = {0u, 0u};
        if (k < KT)
            v = *(const uint2*)(vt + ((size_t)nh*DD + r)*KT + k);
        rv[j] = v;
    }
}

__global__ __launch_bounds__(256) void pv_mfma(
    const uchar* __restrict__ E, const uchar* __restrict__ vt,
    short* __restrict__ AO)
{
    __shared__ uchar Ps[32*72];
    __shared__ uchar Vs[64*72];
    const int tid = threadIdx.x;
    const int ql0 = blockIdx.x * 32;
    const int nh = blockIdx.y;
    const int n = nh >> 3, h = nh & 7;
    const int wave = tid >> 6, lane = tid & 63;
    const int lr = lane & 15, lq = lane >> 4;
    const int mh = wave & 1, nb = (wave >> 1)*32;

    uint2 rp[1], rv[2];
    pv_loadP(E, n, h, ql0, 0, tid, rp);
    pv_loadV(vt, nh, 0, tid, rv);

    f32x4 acc[2];
    acc[0] = {0.f,0.f,0.f,0.f}; acc[1] = {0.f,0.f,0.f,0.f};

    for (int kt = 0; kt < 17; ++kt) {
        if (kt) __syncthreads();
        {
            int r = tid >> 3, cg = (tid & 7)*8;
            *(uint2*)(Ps + r*72 + cg) = rp[0];
        }
        #pragma unroll
        for (int j = 0; j < 2; ++j) {
            int i = tid + j*256;
            *(uint2*)(Vs + (i >> 3)*72 + (i & 7)*8) = rv[j];
        }
        __syncthreads();
        if (kt + 1 < 17) {
            pv_loadP(E, n, h, ql0, kt+1, tid, rp);
            pv_loadV(vt, nh, kt+1, tid, rv);
        }
        #pragma unroll
        for (int ks = 0; ks < 2; ++ks) {
            int ko = ks*32 + lq*8;
            long a = *(const long*)(Ps + (mh*16 + lr)*72 + ko);
            #pragma unroll
            for (int nt = 0; nt < 2; ++nt) {
                long b = *(const long*)(Vs + (nb + nt*16 + lr)*72 + ko);
                acc[nt] = MFMAF8(a, b, acc[nt]);
            }
        }
    }
    #pragma unroll
    for (int nt = 0; nt < 2; ++nt) {
        int d = nb + nt*16 + lr;
        #pragma unroll
        for (int reg = 0; reg < 4; ++reg) {
            int qg = ql0 + mh*16 + lq*4 + reg;
            AO[((size_t)(n*SS) + qg)*CC + h*64 + d] = f2s(acc[nt][reg]);
        }
    }
}

// ---------------------------------------------------------------------------
// K5: fc (with th_post folded into weights), bf16 MFMA, 64x64, XCD-swizzled.
// Writes xres (bf16) AND xres8 (fp8 copy for conv1's A operand).
// ---------------------------------------------------------------------------
__device__ __forceinline__ void g_load4(const short* __restrict__ src,
    size_t rowstride, int row0, int col0, int tid, short4* r)
{
    #pragma unroll
    for (int j = 0; j < 4; ++j) {
        int i = tid + j*256;
        int rr = i >> 4, cg = (i & 15)*4;
        r[j] = *(const short4*)(src + (size_t)(row0 + rr)*rowstride + col0 + cg);
    }
}
__device__ __forceinline__ void lds_store4(short* __restrict__ dst,
    int tid, const short4* r)
{
    #pragma unroll
    for (int j = 0; j < 4; ++j) {
        int i = tid + j*256;
        *(short4*)(dst + (i >> 4)*72 + (i & 15)*4) = r[j];
    }
}

__global__ __launch_bounds__(256) void fc_mfma(
    const short* __restrict__ A, const short* __restrict__ Bt,
    const float* __restrict__ bias, const float* __restrict__ x,
    short* __restrict__ out, uchar* __restrict__ out8)
{
    __shared__ short As[64*72];
    __shared__ short Bs[64*72];
    const int tid = threadIdx.x;
    const int lin = blockIdx.x + 8*blockIdx.y;      // grid (8,128)
    const int xcd = lin & 7, slot = lin >> 3;
    const int m0 = (xcd*16 + (slot & 15))*64;
    const int n0 = (slot >> 4)*64;
    const int wave = tid >> 6, lane = tid & 63;
    const int lr = lane & 15, lq = lane >> 4;

    short4 ra[4], rb[4];
    g_load4(A, CC, m0, 0, tid, ra);
    g_load4(Bt, CC, n0, 0, tid, rb);

    f32x4 acc[4];
    #pragma unroll
    for (int nt = 0; nt < 4; ++nt) acc[nt] = {0.f,0.f,0.f,0.f};

    for (int kt = 0; kt < CC; kt += 64) {
        if (kt) __syncthreads();
        lds_store4(As, tid, ra);
        lds_store4(Bs, tid, rb);
        __syncthreads();
        if (kt + 64 < CC) {
            g_load4(A, CC, m0, kt+64, tid, ra);
            g_load4(Bt, CC, n0, kt+64, tid, rb);
        }
        #pragma unroll
        for (int ks = 0; ks < 2; ++ks) {
            int ko = ks*32 + lq*8;
            short8 a = *(const short8*)(As + (wave*16 + lr)*72 + ko);
            #pragma unroll
            for (int nt = 0; nt < 4; ++nt) {
                short8 b = *(const short8*)(Bs + (nt*16 + lr)*72 + ko);
                acc[nt] = MFMA16(a, b, acc[nt]);
            }
        }
    }
    #pragma unroll
    for (int nt = 0; nt < 4; ++nt) {
        int nn = n0 + nt*16 + lr;
        #pragma unroll
        for (int reg = 0; reg < 4; ++reg) {
            int m = m0 + wave*16 + lq*4 + reg;
            float v = acc[nt][reg] + bias[nn] + x[(size_t)m*CC + nn];
            out[(size_t)m*CC + nn]  = f2s(v);
            out8[(size_t)m*CC + nn] = f2q(v);
        }
    }
}

// ---------------------------------------------------------------------------
// K6: causal conv as fp8 NT GEMM K=1536, 64x64, XCD-swizzled, prefetch.
// Weights pre-scaled x16 -> acc descaled x(1/16). f8out: h1 fp8 / c2 bf16.
// ---------------------------------------------------------------------------
__device__ __forceinline__ void conv_loadA8(const uchar* __restrict__ A,
    int m0, int kt, int tid, uint2* ra)
{
    const int shift = (kt >> 9) - 2;
    const int ci0 = kt & 511;
    #pragma unroll
    for (int j = 0; j < 2; ++j) {
        int i = tid + j*256;
        int rr = i >> 3, c8 = (i & 7)*8;
        int m = m0 + rr;
        int s = m & (SS-1);
        uint2 v = {0u, 0u};
        if (s + shift >= 0)
            v = *(const uint2*)(A + (size_t)(m + shift)*CC + ci0 + c8);
        ra[j] = v;
    }
}
__device__ __forceinline__ void g_load8(const uchar* __restrict__ src,
    size_t rowstride, int row0, int col0, int tid, uint2* r)
{
    #pragma unroll
    for (int j = 0; j < 2; ++j) {
        int i = tid + j*256;
        int rr = i >> 3, c8 = (i & 7)*8;
        r[j] = *(const uint2*)(src + (size_t)(row0 + rr)*rowstride + col0 + c8);
    }
}
__device__ __forceinline__ void lds_store8(uchar* __restrict__ dst,
    int tid, const uint2* r)
{
    #pragma unroll
    for (int j = 0; j < 2; ++j) {
        int i = tid + j*256;
        *(uint2*)(dst + (i >> 3)*72 + (i & 7)*8) = r[j];
    }
}

__global__ __launch_bounds__(256) void conv_mfma8(
    const uchar* __restrict__ A, const uchar* __restrict__ Bt,
    const float* __restrict__ bias, uchar* __restrict__ out8,
    short* __restrict__ out16, int f8out)
{
    __shared__ uchar As[64*72];
    __shared__ uchar Bs[64*72];
    const int tid = threadIdx.x;
    const int lin = blockIdx.x + 8*blockIdx.y;      // grid (8,128)
    const int xcd = lin & 7, slot = lin >> 3;
    const int m0 = (xcd*16 + (slot & 15))*64;
    const int n0 = (slot >> 4)*64;
    const int wave = tid >> 6, lane = tid & 63;
    const int lr = lane & 15, lq = lane >> 4;

    uint2 ra[2], rb[2];
    conv_loadA8(A, m0, 0, tid, ra);
    g_load8(Bt, 1536, n0, 0, tid, rb);

    f32x4 acc[4];
    #pragma unroll
    for (int nt = 0; nt < 4; ++nt) acc[nt] = {0.f,0.f,0.f,0.f};

    for (int kt = 0; kt < 1536; kt += 64) {
        if (kt) __syncthreads();
        lds_store8(As, tid, ra);
        lds_store8(Bs, tid, rb);
        __syncthreads();
        if (kt + 64 < 1536) {
            conv_loadA8(A, m0, kt+64, tid, ra);
            g_load8(Bt, 1536, n0, kt+64, tid, rb);
        }
        #pragma unroll
        for (int ks = 0; ks < 2; ++ks) {
            int ko = ks*32 + lq*8;
            long a = *(const long*)(As + (wave*16 + lr)*72 + ko);
            #pragma unroll
            for (int nt = 0; nt < 4; ++nt) {
                long b = *(const long*)(Bs + (nt*16 + lr)*72 + ko);
                acc[nt] = MFMAF8(a, b, acc[nt]);
            }
        }
    }
    #pragma unroll
    for (int nt = 0; nt < 4; ++nt) {
        int nn = n0 + nt*16 + lr;
        #pragma unroll
        for (int reg = 0; reg < 4; ++reg) {
            int m = m0 + wave*16 + lq*4 + reg;
            float v = fmaxf(acc[nt][reg]*0.0625f + bias[nn], 0.f);
            if (f8out) out8[(size_t)m*CC + nn]  = f2q(v);
            else       out16[(size_t)m*CC + nn] = f2s(v);
        }
    }
}

// ---------------------------------------------------------------------------
// K7: out = LN(relu(c2 + xres) masked) * g + b.  short2 in / float2 out.
// ---------------------------------------------------------------------------
__global__ __launch_bounds__(256) void final_kernel(
    const short* __restrict__ c2, const short* __restrict__ xres,
    const int* __restrict__ mask, const float* __restrict__ g,
    const float* __restrict__ b, float* __restrict__ out)
{
    __shared__ float red[256];
    const int tid = threadIdx.x;
    const int m = blockIdx.x;
    const int n = m >> 10, s = m & 1023;
    const int mk = mask[(size_t)n*SS*SS + (size_t)s*SS];
    const int c0 = tid*2;

    short2 ca = *(const short2*)(c2 + (size_t)m*CC + c0);
    short2 xa = *(const short2*)(xres + (size_t)m*CC + c0);
    float v0 = fmaxf(s2f(ca.x) + s2f(xa.x), 0.f);
    float v1 = fmaxf(s2f(ca.y) + s2f(xa.y), 0.f);
    if (mk == 0) { v0 = 0.f; v1 = 0.f; }

    red[tid] = v0 + v1;
    __syncthreads();
    for (int off = 128; off > 0; off >>= 1) {
        if (tid < off) red[tid] += red[tid + off];
        __syncthreads();
    }
    float mu = red[0] * (1.0f/512.0f);
    __syncthreads();
    float d0 = v0 - mu, d1 = v1 - mu;
    red[tid] = d0*d0 + d1*d1;
    __syncthreads();
    for (int off = 128; off > 0; off >>= 1) {
        if (tid < off) red[tid] += red[tid + off];
        __syncthreads();
    }
    float rstd = rsqrtf(red[0] * (1.0f/512.0f) + 1e-5f);
    float2 gg = *(const float2*)(g + c0);
    float2 bb = *(const float2*)(b + c0);
    float2 o;
    o.x = d0*rstd*gg.x + bb.x;
    o.y = d1*rstd*gg.y + bb.y;
    *(float2*)(out + (size_t)m*CC + c0) = o;
}

// ---------------------------------------------------------------------------
extern "C" void kernel_launch(void* const* d_in, const int* in_sizes, int n_in,
                              void* d_out, int out_size, void* d_ws, size_t ws_size,
                              hipStream_t stream)
{
    const float* x      = (const float*)d_in[0];
    const int*   mask   = (const int*)  d_in[1];
    const float* Wq     = (const float*)d_in[2];
    const float* Wk     = (const float*)d_in[3];
    const float* Wv     = (const float*)d_in[4];
    const float* pk     = (const float*)d_in[5];
    const float* pv     = (const float*)d_in[6];
    const float* th_pre = (const float*)d_in[7];
    const float* th_post= (const float*)d_in[8];
    const float* fc_w   = (const float*)d_in[9];
    const float* fc_b   = (const float*)d_in[10];
    const float* c1w    = (const float*)d_in[11];
    const float* c1b    = (const float*)d_in[12];
    const float* c2w    = (const float*)d_in[13];
    const float* c2b    = (const float*)d_in[14];
    const float* lng    = (const float*)d_in[15];
    const float* lnb    = (const float*)d_in[16];
    float* out = (float*)d_out;
    (void)in_sizes; (void)n_in; (void)out_size; (void)ws_size;

    char* ws = (char*)d_ws;
    const size_t SZ_Q  = (size_t)BN*HH*SS*DD;      //  4.19 MB (fp8)
    const size_t SZ_K  = (size_t)BN*HH*KT*DD;      //  4.26 MB (fp8)
    const size_t SZ_V  = (size_t)BN*HH*KT*DD*2;    //  8.52 MB (bf16)
    const size_t SZ_VT = (size_t)BN*HH*DD*KT;      //  4.26 MB (fp8)
    const size_t SZ_E  = (size_t)BN*SS*HH*KT;      // 68.2 MB (fp8)
    const size_t SZ_A  = (size_t)BN*SS*CC*2;       //  8.39 MB (bf16)

    uchar* qf  = (uchar*)(ws);
    uchar* kf  = (uchar*)(ws + SZ_Q);
    short* vf  = (short*)(ws + SZ_Q + SZ_K);
    uchar* vt  = (uchar*)(ws + SZ_Q + SZ_K + SZ_V);
    uchar* E   = (uchar*)(ws + SZ_Q + SZ_K + SZ_V + SZ_VT);
    short* AO  = (short*)(ws + SZ_Q + SZ_K + SZ_V + SZ_VT + SZ_E);
    char*  wend = ws + SZ_Q + SZ_K + SZ_V + SZ_VT + SZ_E + SZ_A;
    short* Bfc = (short*)(wend);
    uchar* Bc1 = (uchar*)(wend + 512*512*2);
    uchar* Bc2 = (uchar*)(wend + 512*512*2 + 512*1536);
    short* Bqkv= (short*)(wend + 512*512*2 + 2*512*1536);
    uchar* xres8 = (uchar*)(wend + 512*512*2 + 2*512*1536 + 3*64*64*2);
    // Aliases (dead regions): xres(bf16) over qf+kf (dead after energy);
    // h1(fp8) over E (dead after pv); c2(bf16) over vf (dead after vtrans).
    short* xres = (short*)(ws);
    uchar* h18  = (uchar*)E;
    short* c2   = (short*)vf;
    // total ws ~= 106 MB (ws_size >= 256 MiB)

    {
        int total = 512*512 + 2*512*1536 + 3*64*64;
        prep_kernel<<<(total + 255)/256, 256, 0, stream>>>(
            fc_w, c1w, c2w, Wq, Wk, Wv, th_post, Bfc, Bc1, Bc2, Bqkv);
    }
    qkv_mfma<<<dim3(BN*SS/64, HH), 256, 0, stream>>>(x, Bqkv, qf, kf, vf);
    persist_kernel<<<(BN*HH*PP*DD + 255)/256, 256, 0, stream>>>(pk, pv, kf, vf);
    vtrans_kernel<<<dim3(17, BN*HH), 256, 0, stream>>>(vf, vt);

    energy_mfma8<<<dim3(17, SS/64, BN*HH), 256, 0, stream>>>(qf, kf, E);
    softmax_kernel<<<BN*SS, 256, 0, stream>>>(E, mask, th_pre);
    pv_mfma<<<dim3(SS/32, BN*HH), 256, 0, stream>>>(E, vt, AO);

    fc_mfma<<<dim3(8, 128), 256, 0, stream>>>(AO, Bfc, fc_b, x, xres, xres8);
    conv_mfma8<<<dim3(8, 128), 256, 0, stream>>>(xres8, Bc1, c1b, h18, (short*)nullptr, 1);
    conv_mfma8<<<dim3(8, 128), 256, 0, stream>>>(h18, Bc2, c2b, (uchar*)nullptr, c2, 0);
    final_kernel<<<BN*SS, 256, 0, stream>>>(c2, xres, mask, lng, lnb, out);
}

// Round 15
// 309.135 us; speedup vs baseline: 1.6239x; 1.0183x over previous
//
#include <hip/hip_runtime.h>
#include <hip/hip_bf16.h>

#define BN 8
#define SS 1024
#define CC 512
#define HH 8
#define DD 64
#define PP 16
#define KT 1040

typedef __hip_bfloat16 bf16;
typedef unsigned char uchar;
typedef unsigned short ushort;
typedef unsigned int uint;
typedef __attribute__((ext_vector_type(8))) short short8;
typedef __attribute__((ext_vector_type(4))) float f32x4;
typedef __attribute__((ext_vector_type(2))) float f32x2;

__device__ __forceinline__ short f2s(float v){ bf16 b = __float2bfloat16(v); return *(short*)&b; }
__device__ __forceinline__ float s2f(short s){ bf16 b; *(short*)&b = s; return __bfloat162float(b); }
__device__ __forceinline__ uchar f2q(float v){          // f32 -> fp8 e4m3 byte
    return (uchar)__builtin_amdgcn_cvt_pk_fp8_f32(v, v, 0, false);
}

#define MFMA16(a,b,c)  __builtin_amdgcn_mfma_f32_16x16x32_bf16(a,b,c,0,0,0)
#define MFMAF8(a,b,c)  __builtin_amdgcn_mfma_f32_16x16x32_fp8_fp8(a,b,c,0,0,0)

// ---------------------------------------------------------------------------
// P0: weight pre-conversion. fc -> bf16 with th_post FOLDED IN:
//   Bfc[c, g*64+d] = sum_h fc_w[c, h*64+d] * th_post[h,g]
// conv weights -> fp8 scaled x16; qkv -> bf16.
// ---------------------------------------------------------------------------
__global__ __launch_bounds__(256) void prep_kernel(
    const float* __restrict__ fc_w, const float* __restrict__ c1w,
    const float* __restrict__ c2w, const float* __restrict__ Wq,
    const float* __restrict__ Wk, const float* __restrict__ Wv,
    const float* __restrict__ th_post,
    short* __restrict__ Bfc, uchar* __restrict__ Bc1,
    uchar* __restrict__ Bc2, short* __restrict__ Bqkv)
{
    int i = blockIdx.x*256 + threadIdx.x;
    const int NFC = 512*512, NCV = 512*1536, NQ = 3*64*64;
    if (i < NFC) {
        int c = i >> 9, r = i & 511;
        int g = r >> 6, d = r & 63;
        float s = 0.f;
        #pragma unroll
        for (int h = 0; h < 8; ++h)
            s += fc_w[(size_t)c*512 + h*64 + d] * th_post[h*8 + g];
        Bfc[i] = f2s(s);
        return;
    }
    i -= NFC;
    if (i < NCV) {
        int o = i/1536, r = i%1536, dk = r>>9, ci = r&511;
        Bc1[i] = f2q(c1w[(o*512+ci)*3+dk] * 16.f); return;
    }
    i -= NCV;
    if (i < NCV) {
        int o = i/1536, r = i%1536, dk = r>>9, ci = r&511;
        Bc2[i] = f2q(c2w[(o*512+ci)*3+dk] * 16.f); return;
    }
    i -= NCV;
    if (i < NQ) {
        int w = i >> 12, rest = i & 4095;
        const float* W = (w==0)?Wq:(w==1)?Wk:Wv;
        Bqkv[i] = f2s(W[((rest>>6)&63)*64 + (rest&63)]);
    }
}

// ---------------------------------------------------------------------------
// K1: QKV projection, bf16 MFMA. q/k out fp8 [s][d]; V written DIRECTLY into
// transposed fp8 vt[nh][d][k=s] (removes vtrans kernel + vf buffer).
// ---------------------------------------------------------------------------
__global__ __launch_bounds__(256) void qkv_mfma(
    const float* __restrict__ x, const short* __restrict__ Bqkv,
    uchar* __restrict__ qf, uchar* __restrict__ kf, uchar* __restrict__ vt)
{
    __shared__ short Xs[64*72];
    __shared__ short Ws[192*72];
    const int tid = threadIdx.x;
    const int m0 = blockIdx.x * 64;
    const int h = blockIdx.y;
    const int wave = tid >> 6, lane = tid & 63;
    const int lr = lane & 15, lq = lane >> 4;

    for (int i = tid; i < 1024; i += 256) {
        int r = i >> 4, cg = (i & 15)*4;
        float4 v = *(const float4*)(x + (size_t)(m0+r)*CC + h*64 + cg);
        Xs[r*72+cg+0] = f2s(v.x); Xs[r*72+cg+1] = f2s(v.y);
        Xs[r*72+cg+2] = f2s(v.z); Xs[r*72+cg+3] = f2s(v.w);
    }
    for (int i = tid; i < 3072; i += 256) {
        int r = i >> 4, cg = (i & 15)*4;
        *(short4*)(Ws + r*72 + cg) = *(const short4*)(Bqkv + (size_t)r*64 + cg);
    }
    __syncthreads();

    f32x4 acc[12];
    #pragma unroll
    for (int nt = 0; nt < 12; ++nt) acc[nt] = {0.f,0.f,0.f,0.f};
    #pragma unroll
    for (int ks = 0; ks < 2; ++ks) {
        int ko = ks*32 + lq*8;
        short8 a = *(const short8*)(Xs + (wave*16 + lr)*72 + ko);
        #pragma unroll
        for (int nt = 0; nt < 12; ++nt) {
            short8 b = *(const short8*)(Ws + (nt*16 + lr)*72 + ko);
            acc[nt] = MFMA16(a, b, acc[nt]);
        }
    }
    #pragma unroll
    for (int nt = 0; nt < 12; ++nt) {
        int ep = nt*16 + lr;
        int w = ep >> 6, e = ep & 63;
        #pragma unroll
        for (int reg = 0; reg < 4; ++reg) {
            int m = m0 + wave*16 + lq*4 + reg;
            int n = m >> 10, s = m & 1023;
            float v = acc[nt][reg];
            if (w == 0)      qf[((size_t)(n*HH+h)*SS + s)*DD + e] = f2q(v);
            else if (w == 1) kf[((size_t)(n*HH+h)*KT + s)*DD + e] = f2q(v);
            else             vt[(((size_t)(n*HH+h))*DD + e)*KT + s] = f2q(v);
        }
    }
}

// ---------------------------------------------------------------------------
// K1b: persistent tokens -> kf tail (fp8 [k][d]) and vt tail (fp8 [d][k]).
// ---------------------------------------------------------------------------
__global__ __launch_bounds__(256) void persist_kernel(
    const float* __restrict__ pk, const float* __restrict__ pv,
    uchar* __restrict__ kf, uchar* __restrict__ vt)
{
    int idx = blockIdx.x*256 + threadIdx.x;
    if (idx >= BN*HH*PP*DD) return;
    int d = idx & 63, p = (idx >> 6) & 15, h = (idx >> 10) & 7, n = idx >> 13;
    size_t src = ((size_t)p*HH + h)*DD + d;
    kf[(((size_t)(n*HH+h))*KT + SS + p)*DD + d] = f2q(pk[src]);
    vt[(((size_t)(n*HH+h))*DD + d)*KT + SS + p] = f2q(pv[src]);
}

// ---------------------------------------------------------------------------
// K2: energy, fp8 MFMA NT. grid (17, S/64, BN*HH). Raw fp8 scores.
// ---------------------------------------------------------------------------
__global__ __launch_bounds__(256) void energy_mfma8(
    const uchar* __restrict__ qf, const uchar* __restrict__ kf,
    uchar* __restrict__ E)
{
    __shared__ uchar Qs[64*72];
    __shared__ uchar Ks[64*72];
    const int tid = threadIdx.x;
    const int kt = blockIdx.x;
    const int mt = blockIdx.y;
    const int nh = blockIdx.z;
    const int wave = tid >> 6, lane = tid & 63;
    const int lr = lane & 15, lq = lane >> 4;

    #pragma unroll
    for (int j = 0; j < 2; ++j) {
        int i = tid + j*256;
        int r = i >> 3, c8 = (i & 7)*8;
        *(uint2*)(Qs + r*72 + c8) =
            *(const uint2*)(qf + ((size_t)nh*SS + mt*64 + r)*DD + c8);
        int kcol = kt*64 + r;
        uint2 kv = {0u, 0u};
        if (kcol < KT)
            kv = *(const uint2*)(kf + ((size_t)nh*KT + kcol)*DD + c8);
        *(uint2*)(Ks + r*72 + c8) = kv;
    }
    __syncthreads();

    f32x4 acc[4];
    #pragma unroll
    for (int nt = 0; nt < 4; ++nt) acc[nt] = {0.f,0.f,0.f,0.f};
    #pragma unroll
    for (int ks = 0; ks < 2; ++ks) {
        int ko = ks*32 + lq*8;
        long a = *(const long*)(Qs + (wave*16 + lr)*72 + ko);
        #pragma unroll
        for (int nt = 0; nt < 4; ++nt) {
            long b = *(const long*)(Ks + (nt*16 + lr)*72 + ko);
            acc[nt] = MFMAF8(a, b, acc[nt]);
        }
    }
    const int n = nh >> 3, h = nh & 7;
    #pragma unroll
    for (int nt = 0; nt < 4; ++nt) {
        int kcol = kt*64 + nt*16 + lr;
        if (kcol >= KT) continue;
        #pragma unroll
        for (int reg = 0; reg < 4; ++reg) {
            int q = mt*64 + wave*16 + lq*4 + reg;
            E[(((size_t)(n*SS + q))*HH + h)*KT + kcol] = f2q(acc[nt][reg]);
        }
    }
}

// ---------------------------------------------------------------------------
// K3: softmax: no-max, fp8 in/out, premix in-kernel, postmix folded into fc.
// Thread owns 4 ADJACENT cols (k0=tid*4): all E traffic is single-uint
// loads/stores (4x fewer mem instrs). Premix in f32x4 vector ops
// (v_pk_fma_f32 candidates). Stores normalized probs.
// ---------------------------------------------------------------------------
__global__ __launch_bounds__(256) void softmax_kernel(
    uchar* __restrict__ E, const int* __restrict__ mask,
    const float* __restrict__ th_pre)
{
    __shared__ float thp[64];
    __shared__ float wred[4][8];
    const int tid = threadIdx.x;
    const int wave = tid >> 6, lane = tid & 63;
    const int blk = blockIdx.x;              // n*SS + q
    const int n = blk >> 10, q = blk & 1023;
    const float invs = 0.044194173824159216f;   // 1/sqrt(512)
    const float l2e  = 1.4426950408889634f;
    if (tid < 64) thp[tid] = th_pre[tid]*(invs*l2e);
    __syncthreads();
    uchar* Eb = E + (size_t)blk*HH*KT;

    const float sl[8] = {0.5f,0.25f,0.125f,0.0625f,
                         0.03125f,0.015625f,0.0078125f,0.00390625f};
    const int* mrow = mask + (size_t)n*SS*SS + (size_t)q*SS;

    const int k0 = tid*4;                    // 4 adjacent columns
    const int4 mk = *(const int4*)(mrow + k0);
    f32x4 dist;
    dist.x = fabsf((float)(q - k0));
    dist.y = fabsf((float)(q - k0 - 1));
    dist.z = fabsf((float)(q - k0 - 2));
    dist.w = fabsf((float)(q - k0 - 3));

    f32x4 tp[8];
    float tl[8];
    float sm[8];
    #pragma unroll
    for (int g = 0; g < 8; ++g) { sm[g] = 0.f; tl[g] = 0.f; }

    {
        f32x4 a[8];
        #pragma unroll
        for (int g = 0; g < 8; ++g) {
            uint u = *(const uint*)(Eb + g*KT + k0);
            f32x2 lo = __builtin_amdgcn_cvt_pk_f32_fp8((int)u, false);
            f32x2 hi = __builtin_amdgcn_cvt_pk_f32_fp8((int)u, true);
            f32x4 r; r.x = lo.x; r.y = lo.y; r.z = hi.x; r.w = hi.y;
            a[g] = r - dist*sl[g];
        }
        #pragma unroll
        for (int h = 0; h < 8; ++h) {
            f32x4 t = {0.f,0.f,0.f,0.f};
            #pragma unroll
            for (int g = 0; g < 8; ++g)
                t += a[g] * thp[h*8 + g];    // packed-f32 FMA candidates
            f32x4 e;
            e.x = (mk.x == 0) ? 0.f : exp2f(t.x);
            e.y = (mk.y == 0) ? 0.f : exp2f(t.y);
            e.z = (mk.z == 0) ? 0.f : exp2f(t.z);
            e.w = (mk.w == 0) ? 0.f : exp2f(t.w);
            tp[h] = e;
            sm[h] += e.x + e.y + e.z + e.w;
        }
    }
    if (tid < 16) {                          // persistent keys
        const int k = 1024 + tid;
        float a[8];
        #pragma unroll
        for (int g = 0; g < 8; ++g) {
            f32x2 r = __builtin_amdgcn_cvt_pk_f32_fp8((int)Eb[g*KT + k], false);
            a[g] = r.x;
        }
        #pragma unroll
        for (int h = 0; h < 8; ++h) {
            float t = 0.f;
            #pragma unroll
            for (int g = 0; g < 8; ++g) t = fmaf(thp[h*8 + g], a[g], t);
            float e = exp2f(t);
            tl[h] = e;
            sm[h] += e;
        }
    }
    #pragma unroll
    for (int g = 0; g < 8; ++g) {
        #pragma unroll
        for (int off = 32; off > 0; off >>= 1)
            sm[g] += __shfl_xor(sm[g], off);
    }
    if (lane == 0) {
        #pragma unroll
        for (int g = 0; g < 8; ++g) wred[wave][g] = sm[g];
    }
    __syncthreads();
    float lred[8];
    #pragma unroll
    for (int g = 0; g < 8; ++g)
        lred[g] = 1.0f / (wred[0][g] + wred[1][g] + wred[2][g] + wred[3][g]);

    // normalized probs out: one uint store per head
    #pragma unroll
    for (int h = 0; h < 8; ++h) {
        f32x4 e = tp[h] * lred[h];
        int p = __builtin_amdgcn_cvt_pk_fp8_f32(e.x, e.y, 0, false);
        p = __builtin_amdgcn_cvt_pk_fp8_f32(e.z, e.w, p, true);
        *(uint*)(Eb + h*KT + k0) = (uint)p;
    }
    if (tid < 16) {
        const int k = 1024 + tid;
        #pragma unroll
        for (int g = 0; g < 8; ++g)
            Eb[g*KT + k] = f2q(tl[g] * lred[g]);
    }
}

// ---------------------------------------------------------------------------
// K4: PV via fp8 MFMA (P fp8 x V fp8), q-tile 32, register-prefetch dbuf.
// ---------------------------------------------------------------------------
__device__ __forceinline__ void pv_loadP(const uchar* __restrict__ E,
    int n, int h, int ql0, int kt, int tid, uint2* rp)
{
    int r = tid >> 3, cg = (tid & 7)*8;
    int k = kt*64 + cg;
    uint2 v = {0u, 0u};
    if (k < KT)
        v = *(const uint2*)(E + (((size_t)(n*SS + ql0 + r))*HH + h)*KT + k);
    rp[0] = v;
}
__device__ __forceinline__ void pv_loadV(const uchar* __restrict__ vt,
    int nh, int kt, int tid, uint2* rv)
{
    #pragma unroll
    for (int j = 0; j < 2; ++j) {
        int i = tid + j*256;
        int r = i >> 3, cg = (i & 7)*8;
        int k = kt*64 + cg;
        uint2 v = {0u, 0u};
        if (k < KT)
            v = *(const uint2*)(vt + ((size_t)nh*DD + r)*KT + k);
        rv[j] = v;
    }
}

__global__ __launch_bounds__(256) void pv_mfma(
    const uchar* __restrict__ E, const uchar* __restrict__ vt,
    short* __restrict__ AO)
{
    __shared__ uchar Ps[32*72];
    __shared__ uchar Vs[64*72];
    const int tid = threadIdx.x;
    const int ql0 = blockIdx.x * 32;
    const int nh = blockIdx.y;
    const int n = nh >> 3, h = nh & 7;
    const int wave = tid >> 6, lane = tid & 63;
    const int lr = lane & 15, lq = lane >> 4;
    const int mh = wave & 1, nb = (wave >> 1)*32;

    uint2 rp[1], rv[2];
    pv_loadP(E, n, h, ql0, 0, tid, rp);
    pv_loadV(vt, nh, 0, tid, rv);

    f32x4 acc[2];
    acc[0] = {0.f,0.f,0.f,0.f}; acc[1] = {0.f,0.f,0.f,0.f};

    for (int kt = 0; kt < 17; ++kt) {
        if (kt) __syncthreads();
        {
            int r = tid >> 3, cg = (tid & 7)*8;
            *(uint2*)(Ps + r*72 + cg) = rp[0];
        }
        #pragma unroll
        for (int j = 0; j < 2; ++j) {
            int i = tid + j*256;
            *(uint2*)(Vs + (i >> 3)*72 + (i & 7)*8) = rv[j];
        }
        __syncthreads();
        if (kt + 1 < 17) {
            pv_loadP(E, n, h, ql0, kt+1, tid, rp);
            pv_loadV(vt, nh, kt+1, tid, rv);
        }
        #pragma unroll
        for (int ks = 0; ks < 2; ++ks) {
            int ko = ks*32 + lq*8;
            long a = *(const long*)(Ps + (mh*16 + lr)*72 + ko);
            #pragma unroll
            for (int nt = 0; nt < 2; ++nt) {
                long b = *(const long*)(Vs + (nb + nt*16 + lr)*72 + ko);
                acc[nt] = MFMAF8(a, b, acc[nt]);
            }
        }
    }
    #pragma unroll
    for (int nt = 0; nt < 2; ++nt) {
        int d = nb + nt*16 + lr;
        #pragma unroll
        for (int reg = 0; reg < 4; ++reg) {
            int qg = ql0 + mh*16 + lq*4 + reg;
            AO[((size_t)(n*SS) + qg)*CC + h*64 + d] = f2s(acc[nt][reg]);
        }
    }
}

// ---------------------------------------------------------------------------
// K5: fc (th_post folded into weights), bf16 MFMA, 64x64, XCD-swizzled.
// Writes xres (bf16) AND xres8 (fp8 copy for conv1's A operand).
// ---------------------------------------------------------------------------
__device__ __forceinline__ void g_load4(const short* __restrict__ src,
    size_t rowstride, int row0, int col0, int tid, short4* r)
{
    #pragma unroll
    for (int j = 0; j < 4; ++j) {
        int i = tid + j*256;
        int rr = i >> 4, cg = (i & 15)*4;
        r[j] = *(const short4*)(src + (size_t)(row0 + rr)*rowstride + col0 + cg);
    }
}
__device__ __forceinline__ void lds_store4(short* __restrict__ dst,
    int tid, const short4* r)
{
    #pragma unroll
    for (int j = 0; j < 4; ++j) {
        int i = tid + j*256;
        *(short4*)(dst + (i >> 4)*72 + (i & 15)*4) = r[j];
    }
}

__global__ __launch_bounds__(256) void fc_mfma(
    const short* __restrict__ A, const short* __restrict__ Bt,
    const float* __restrict__ bias, const float* __restrict__ x,
    short* __restrict__ out, uchar* __restrict__ out8)
{
    __shared__ short As[64*72];
    __shared__ short Bs[64*72];
    const int tid = threadIdx.x;
    const int lin = blockIdx.x + 8*blockIdx.y;      // grid (8,128)
    const int xcd = lin & 7, slot = lin >> 3;
    const int m0 = (xcd*16 + (slot & 15))*64;
    const int n0 = (slot >> 4)*64;
    const int wave = tid >> 6, lane = tid & 63;
    const int lr = lane & 15, lq = lane >> 4;

    short4 ra[4], rb[4];
    g_load4(A, CC, m0, 0, tid, ra);
    g_load4(Bt, CC, n0, 0, tid, rb);

    f32x4 acc[4];
    #pragma unroll
    for (int nt = 0; nt < 4; ++nt) acc[nt] = {0.f,0.f,0.f,0.f};

    for (int kt = 0; kt < CC; kt += 64) {
        if (kt) __syncthreads();
        lds_store4(As, tid, ra);
        lds_store4(Bs, tid, rb);
        __syncthreads();
        if (kt + 64 < CC) {
            g_load4(A, CC, m0, kt+64, tid, ra);
            g_load4(Bt, CC, n0, kt+64, tid, rb);
        }
        #pragma unroll
        for (int ks = 0; ks < 2; ++ks) {
            int ko = ks*32 + lq*8;
            short8 a = *(const short8*)(As + (wave*16 + lr)*72 + ko);
            #pragma unroll
            for (int nt = 0; nt < 4; ++nt) {
                short8 b = *(const short8*)(Bs + (nt*16 + lr)*72 + ko);
                acc[nt] = MFMA16(a, b, acc[nt]);
            }
        }
    }
    #pragma unroll
    for (int nt = 0; nt < 4; ++nt) {
        int nn = n0 + nt*16 + lr;
        #pragma unroll
        for (int reg = 0; reg < 4; ++reg) {
            int m = m0 + wave*16 + lq*4 + reg;
            float v = acc[nt][reg] + bias[nn] + x[(size_t)m*CC + nn];
            out[(size_t)m*CC + nn]  = f2s(v);
            out8[(size_t)m*CC + nn] = f2q(v);
        }
    }
}

// ---------------------------------------------------------------------------
// K6: causal conv as fp8 NT GEMM K=1536, 64x64, XCD-swizzled, prefetch.
// Weights pre-scaled x16 -> acc descaled x(1/16). f8out: h1 fp8 / c2 bf16.
// ---------------------------------------------------------------------------
__device__ __forceinline__ void conv_loadA8(const uchar* __restrict__ A,
    int m0, int kt, int tid, uint2* ra)
{
    const int shift = (kt >> 9) - 2;
    const int ci0 = kt & 511;
    #pragma unroll
    for (int j = 0; j < 2; ++j) {
        int i = tid + j*256;
        int rr = i >> 3, c8 = (i & 7)*8;
        int m = m0 + rr;
        int s = m & (SS-1);
        uint2 v = {0u, 0u};
        if (s + shift >= 0)
            v = *(const uint2*)(A + (size_t)(m + shift)*CC + ci0 + c8);
        ra[j] = v;
    }
}
__device__ __forceinline__ void g_load8(const uchar* __restrict__ src,
    size_t rowstride, int row0, int col0, int tid, uint2* r)
{
    #pragma unroll
    for (int j = 0; j < 2; ++j) {
        int i = tid + j*256;
        int rr = i >> 3, c8 = (i & 7)*8;
        r[j] = *(const uint2*)(src + (size_t)(row0 + rr)*rowstride + col0 + c8);
    }
}
__device__ __forceinline__ void lds_store8(uchar* __restrict__ dst,
    int tid, const uint2* r)
{
    #pragma unroll
    for (int j = 0; j < 2; ++j) {
        int i = tid + j*256;
        *(uint2*)(dst + (i >> 3)*72 + (i & 7)*8) = r[j];
    }
}

__global__ __launch_bounds__(256) void conv_mfma8(
    const uchar* __restrict__ A, const uchar* __restrict__ Bt,
    const float* __restrict__ bias, uchar* __restrict__ out8,
    short* __restrict__ out16, int f8out)
{
    __shared__ uchar As[64*72];
    __shared__ uchar Bs[64*72];
    const int tid = threadIdx.x;
    const int lin = blockIdx.x + 8*blockIdx.y;      // grid (8,128)
    const int xcd = lin & 7, slot = lin >> 3;
    const int m0 = (xcd*16 + (slot & 15))*64;
    const int n0 = (slot >> 4)*64;
    const int wave = tid >> 6, lane = tid & 63;
    const int lr = lane & 15, lq = lane >> 4;

    uint2 ra[2], rb[2];
    conv_loadA8(A, m0, 0, tid, ra);
    g_load8(Bt, 1536, n0, 0, tid, rb);

    f32x4 acc[4];
    #pragma unroll
    for (int nt = 0; nt < 4; ++nt) acc[nt] = {0.f,0.f,0.f,0.f};

    for (int kt = 0; kt < 1536; kt += 64) {
        if (kt) __syncthreads();
        lds_store8(As, tid, ra);
        lds_store8(Bs, tid, rb);
        __syncthreads();
        if (kt + 64 < 1536) {
            conv_loadA8(A, m0, kt+64, tid, ra);
            g_load8(Bt, 1536, n0, kt+64, tid, rb);
        }
        #pragma unroll
        for (int ks = 0; ks < 2; ++ks) {
            int ko = ks*32 + lq*8;
            long a = *(const long*)(As + (wave*16 + lr)*72 + ko);
            #pragma unroll
            for (int nt = 0; nt < 4; ++nt) {
                long b = *(const long*)(Bs + (nt*16 + lr)*72 + ko);
                acc[nt] = MFMAF8(a, b, acc[nt]);
            }
        }
    }
    #pragma unroll
    for (int nt = 0; nt < 4; ++nt) {
        int nn = n0 + nt*16 + lr;
        #pragma unroll
        for (int reg = 0; reg < 4; ++reg) {
            int m = m0 + wave*16 + lq*4 + reg;
            float v = fmaxf(acc[nt][reg]*0.0625f + bias[nn], 0.f);
            if (f8out) out8[(size_t)m*CC + nn]  = f2q(v);
            else       out16[(size_t)m*CC + nn] = f2s(v);
        }
    }
}

// ---------------------------------------------------------------------------
// K7: out = LN(relu(c2 + xres) masked) * g + b.  short2 in / float2 out.
// ---------------------------------------------------------------------------
__global__ __launch_bounds__(256) void final_kernel(
    const short* __restrict__ c2, const short* __restrict__ xres,
    const int* __restrict__ mask, const float* __restrict__ g,
    const float* __restrict__ b, float* __restrict__ out)
{
    __shared__ float red[256];
    const int tid = threadIdx.x;
    const int m = blockIdx.x;
    const int n = m >> 10, s = m & 1023;
    const int mk = mask[(size_t)n*SS*SS + (size_t)s*SS];
    const int c0 = tid*2;

    short2 ca = *(const short2*)(c2 + (size_t)m*CC + c0);
    short2 xa = *(const short2*)(xres + (size_t)m*CC + c0);
    float v0 = fmaxf(s2f(ca.x) + s2f(xa.x), 0.f);
    float v1 = fmaxf(s2f(ca.y) + s2f(xa.y), 0.f);
    if (mk == 0) { v0 = 0.f; v1 = 0.f; }

    red[tid] = v0 + v1;
    __syncthreads();
    for (int off = 128; off > 0; off >>= 1) {
        if (tid < off) red[tid] += red[tid + off];
        __syncthreads();
    }
    float mu = red[0] * (1.0f/512.0f);
    __syncthreads();
    float d0 = v0 - mu, d1 = v1 - mu;
    red[tid] = d0*d0 + d1*d1;
    __syncthreads();
    for (int off = 128; off > 0; off >>= 1) {
        if (tid < off) red[tid] += red[tid + off];
        __syncthreads();
    }
    float rstd = rsqrtf(red[0] * (1.0f/512.0f) + 1e-5f);
    float2 gg = *(const float2*)(g + c0);
    float2 bb = *(const float2*)(b + c0);
    float2 o;
    o.x = d0*rstd*gg.x + bb.x;
    o.y = d1*rstd*gg.y + bb.y;
    *(float2*)(out + (size_t)m*CC + c0) = o;
}

// ---------------------------------------------------------------------------
extern "C" void kernel_launch(void* const* d_in, const int* in_sizes, int n_in,
                              void* d_out, int out_size, void* d_ws, size_t ws_size,
                              hipStream_t stream)
{
    const float* x      = (const float*)d_in[0];
    const int*   mask   = (const int*)  d_in[1];
    const float* Wq     = (const float*)d_in[2];
    const float* Wk     = (const float*)d_in[3];
    const float* Wv     = (const float*)d_in[4];
    const float* pk     = (const float*)d_in[5];
    const float* pv     = (const float*)d_in[6];
    const float* th_pre = (const float*)d_in[7];
    const float* th_post= (const float*)d_in[8];
    const float* fc_w   = (const float*)d_in[9];
    const float* fc_b   = (const float*)d_in[10];
    const float* c1w    = (const float*)d_in[11];
    const float* c1b    = (const float*)d_in[12];
    const float* c2w    = (const float*)d_in[13];
    const float* c2b    = (const float*)d_in[14];
    const float* lng    = (const float*)d_in[15];
    const float* lnb    = (const float*)d_in[16];
    float* out = (float*)d_out;
    (void)in_sizes; (void)n_in; (void)out_size; (void)ws_size;

    char* ws = (char*)d_ws;
    const size_t SZ_Q  = (size_t)BN*HH*SS*DD;      //  4.19 MB (fp8)
    const size_t SZ_K  = (size_t)BN*HH*KT*DD;      //  4.26 MB (fp8)
    const size_t SZ_VT = (size_t)BN*HH*DD*KT;      //  4.26 MB (fp8)
    const size_t SZ_E  = (size_t)BN*SS*HH*KT;      // 68.2 MB (fp8)
    const size_t SZ_A  = (size_t)BN*SS*CC*2;       //  8.39 MB (bf16)
    const size_t SZ_A8 = (size_t)BN*SS*CC;         //  4.19 MB (fp8)

    uchar* qf  = (uchar*)(ws);
    uchar* kf  = (uchar*)(ws + SZ_Q);
    uchar* vt  = (uchar*)(ws + SZ_Q + SZ_K);
    uchar* E   = (uchar*)(ws + SZ_Q + SZ_K + SZ_VT);
    short* AO  = (short*)(ws + SZ_Q + SZ_K + SZ_VT + SZ_E);
    char*  wend = ws + SZ_Q + SZ_K + SZ_VT + SZ_E + SZ_A;
    short* Bfc = (short*)(wend);
    uchar* Bc1 = (uchar*)(wend + 512*512*2);
    uchar* Bc2 = (uchar*)(wend + 512*512*2 + 512*1536);
    short* Bqkv= (short*)(wend + 512*512*2 + 2*512*1536);
    uchar* xres8 = (uchar*)(wend + 512*512*2 + 2*512*1536 + 3*64*64*2);
    short* c2buf = (short*)(wend + 512*512*2 + 2*512*1536 + 3*64*64*2 + SZ_A8);
    // Aliases (dead regions): xres(bf16) over qf+kf (8.45 >= 8.39, dead after
    // energy; fc runs after pv); h1(fp8) over E (dead after pv).
    short* xres = (short*)(ws);
    uchar* h18  = (uchar*)E;
    // total ws ~= 103 MB (ws_size >= 256 MiB)

    {
        int total = 512*512 + 2*512*1536 + 3*64*64;
        prep_kernel<<<(total + 255)/256, 256, 0, stream>>>(
            fc_w, c1w, c2w, Wq, Wk, Wv, th_post, Bfc, Bc1, Bc2, Bqkv);
    }
    qkv_mfma<<<dim3(BN*SS/64, HH), 256, 0, stream>>>(x, Bqkv, qf, kf, vt);
    persist_kernel<<<(BN*HH*PP*DD + 255)/256, 256, 0, stream>>>(pk, pv, kf, vt);

    energy_mfma8<<<dim3(17, SS/64, BN*HH), 256, 0, stream>>>(qf, kf, E);
    softmax_kernel<<<BN*SS, 256, 0, stream>>>(E, mask, th_pre);
    pv_mfma<<<dim3(SS/32, BN*HH), 256, 0, stream>>>(E, vt, AO);

    fc_mfma<<<dim3(8, 128), 256, 0, stream>>>(AO, Bfc, fc_b, x, xres, xres8);
    conv_mfma8<<<dim3(8, 128), 256, 0, stream>>>(xres8, Bc1, c1b, h18, (short*)nullptr, 1);
    conv_mfma8<<<dim3(8, 128), 256, 0, stream>>>(h18, Bc2, c2b, (uchar*)nullptr, c2buf, 0);
    final_kernel<<<BN*SS, 256, 0, stream>>>(c2buf, xres, mask, lng, lnb, out);
}

// Round 16
// 305.407 us; speedup vs baseline: 1.6438x; 1.0122x over previous
//
#include <hip/hip_runtime.h>
#include <hip/hip_bf16.h>

#define BN 8
#define SS 1024
#define CC 512
#define HH 8
#define DD 64
#define PP 16
#define KT 1040

typedef __hip_bfloat16 bf16;
typedef unsigned char uchar;
typedef unsigned short ushort;
typedef unsigned int uint;
typedef __attribute__((ext_vector_type(8))) short short8;
typedef __attribute__((ext_vector_type(4))) float f32x4;
typedef __attribute__((ext_vector_type(2))) float f32x2;

__device__ __forceinline__ short f2s(float v){ bf16 b = __float2bfloat16(v); return *(short*)&b; }
__device__ __forceinline__ float s2f(short s){ bf16 b; *(short*)&b = s; return __bfloat162float(b); }
__device__ __forceinline__ uchar f2q(float v){          // f32 -> fp8 e4m3 byte
    return (uchar)__builtin_amdgcn_cvt_pk_fp8_f32(v, v, 0, false);
}

#define MFMA16(a,b,c)  __builtin_amdgcn_mfma_f32_16x16x32_bf16(a,b,c,0,0,0)
#define MFMAF8(a,b,c)  __builtin_amdgcn_mfma_f32_16x16x32_fp8_fp8(a,b,c,0,0,0)

// ---------------------------------------------------------------------------
// P0: weight pre-conversion. fc -> bf16 with th_post FOLDED IN:
//   Bfc[c, g*64+d] = sum_h fc_w[c, h*64+d] * th_post[h,g]
// conv weights -> fp8 scaled x16; qkv -> bf16.
// ---------------------------------------------------------------------------
__global__ __launch_bounds__(256) void prep_kernel(
    const float* __restrict__ fc_w, const float* __restrict__ c1w,
    const float* __restrict__ c2w, const float* __restrict__ Wq,
    const float* __restrict__ Wk, const float* __restrict__ Wv,
    const float* __restrict__ th_post,
    short* __restrict__ Bfc, uchar* __restrict__ Bc1,
    uchar* __restrict__ Bc2, short* __restrict__ Bqkv)
{
    int i = blockIdx.x*256 + threadIdx.x;
    const int NFC = 512*512, NCV = 512*1536, NQ = 3*64*64;
    if (i < NFC) {
        int c = i >> 9, r = i & 511;
        int g = r >> 6, d = r & 63;
        float s = 0.f;
        #pragma unroll
        for (int h = 0; h < 8; ++h)
            s += fc_w[(size_t)c*512 + h*64 + d] * th_post[h*8 + g];
        Bfc[i] = f2s(s);
        return;
    }
    i -= NFC;
    if (i < NCV) {
        int o = i/1536, r = i%1536, dk = r>>9, ci = r&511;
        Bc1[i] = f2q(c1w[(o*512+ci)*3+dk] * 16.f); return;
    }
    i -= NCV;
    if (i < NCV) {
        int o = i/1536, r = i%1536, dk = r>>9, ci = r&511;
        Bc2[i] = f2q(c2w[(o*512+ci)*3+dk] * 16.f); return;
    }
    i -= NCV;
    if (i < NQ) {
        int w = i >> 12, rest = i & 4095;
        const float* W = (w==0)?Wq:(w==1)?Wk:Wv;
        Bqkv[i] = f2s(W[((rest>>6)&63)*64 + (rest&63)]);
    }
}

// ---------------------------------------------------------------------------
// K1: QKV projection, bf16 MFMA. q/k out fp8 [s][d]; V written DIRECTLY into
// transposed fp8 vt[nh][d][k=s].
// ---------------------------------------------------------------------------
__global__ __launch_bounds__(256) void qkv_mfma(
    const float* __restrict__ x, const short* __restrict__ Bqkv,
    uchar* __restrict__ qf, uchar* __restrict__ kf, uchar* __restrict__ vt)
{
    __shared__ short Xs[64*72];
    __shared__ short Ws[192*72];
    const int tid = threadIdx.x;
    const int m0 = blockIdx.x * 64;
    const int h = blockIdx.y;
    const int wave = tid >> 6, lane = tid & 63;
    const int lr = lane & 15, lq = lane >> 4;

    for (int i = tid; i < 1024; i += 256) {
        int r = i >> 4, cg = (i & 15)*4;
        float4 v = *(const float4*)(x + (size_t)(m0+r)*CC + h*64 + cg);
        Xs[r*72+cg+0] = f2s(v.x); Xs[r*72+cg+1] = f2s(v.y);
        Xs[r*72+cg+2] = f2s(v.z); Xs[r*72+cg+3] = f2s(v.w);
    }
    for (int i = tid; i < 3072; i += 256) {
        int r = i >> 4, cg = (i & 15)*4;
        *(short4*)(Ws + r*72 + cg) = *(const short4*)(Bqkv + (size_t)r*64 + cg);
    }
    __syncthreads();

    f32x4 acc[12];
    #pragma unroll
    for (int nt = 0; nt < 12; ++nt) acc[nt] = {0.f,0.f,0.f,0.f};
    #pragma unroll
    for (int ks = 0; ks < 2; ++ks) {
        int ko = ks*32 + lq*8;
        short8 a = *(const short8*)(Xs + (wave*16 + lr)*72 + ko);
        #pragma unroll
        for (int nt = 0; nt < 12; ++nt) {
            short8 b = *(const short8*)(Ws + (nt*16 + lr)*72 + ko);
            acc[nt] = MFMA16(a, b, acc[nt]);
        }
    }
    #pragma unroll
    for (int nt = 0; nt < 12; ++nt) {
        int ep = nt*16 + lr;
        int w = ep >> 6, e = ep & 63;
        #pragma unroll
        for (int reg = 0; reg < 4; ++reg) {
            int m = m0 + wave*16 + lq*4 + reg;
            int n = m >> 10, s = m & 1023;
            float v = acc[nt][reg];
            if (w == 0)      qf[((size_t)(n*HH+h)*SS + s)*DD + e] = f2q(v);
            else if (w == 1) kf[((size_t)(n*HH+h)*KT + s)*DD + e] = f2q(v);
            else             vt[(((size_t)(n*HH+h))*DD + e)*KT + s] = f2q(v);
        }
    }
}

// ---------------------------------------------------------------------------
// K1b: persistent tokens -> kf tail (fp8 [k][d]) and vt tail (fp8 [d][k]).
// ---------------------------------------------------------------------------
__global__ __launch_bounds__(256) void persist_kernel(
    const float* __restrict__ pk, const float* __restrict__ pv,
    uchar* __restrict__ kf, uchar* __restrict__ vt)
{
    int idx = blockIdx.x*256 + threadIdx.x;
    if (idx >= BN*HH*PP*DD) return;
    int d = idx & 63, p = (idx >> 6) & 15, h = (idx >> 10) & 7, n = idx >> 13;
    size_t src = ((size_t)p*HH + h)*DD + d;
    kf[(((size_t)(n*HH+h))*KT + SS + p)*DD + d] = f2q(pk[src]);
    vt[(((size_t)(n*HH+h))*DD + d)*KT + SS + p] = f2q(pv[src]);
}

// ---------------------------------------------------------------------------
// K2 v2: energy, fp8 MFMA NT. Block = (mt, nh), grid 1024. Q staged ONCE;
// loop over 17 k-tiles with register-prefetch dbuf (pv pattern). Removes
// 17x Q re-fetch of the old (kt,mt,nh) shape.
// ---------------------------------------------------------------------------
__device__ __forceinline__ void en_loadK(const uchar* __restrict__ kf,
    int nh, int kt, int tid, uint2* rk)
{
    #pragma unroll
    for (int j = 0; j < 2; ++j) {
        int i = tid + j*256;
        int r = i >> 3, c8 = (i & 7)*8;
        int kcol = kt*64 + r;
        uint2 v = {0u, 0u};
        if (kcol < KT)
            v = *(const uint2*)(kf + ((size_t)nh*KT + kcol)*DD + c8);
        rk[j] = v;
    }
}

__global__ __launch_bounds__(256) void energy_mfma8(
    const uchar* __restrict__ qf, const uchar* __restrict__ kf,
    uchar* __restrict__ E)
{
    __shared__ uchar Qs[64*72];
    __shared__ uchar Ks[64*72];
    const int tid = threadIdx.x;
    const int mt = blockIdx.x;
    const int nh = blockIdx.y;
    const int wave = tid >> 6, lane = tid & 63;
    const int lr = lane & 15, lq = lane >> 4;
    const int n = nh >> 3, h = nh & 7;

    #pragma unroll
    for (int j = 0; j < 2; ++j) {
        int i = tid + j*256;
        int r = i >> 3, c8 = (i & 7)*8;
        *(uint2*)(Qs + r*72 + c8) =
            *(const uint2*)(qf + ((size_t)nh*SS + mt*64 + r)*DD + c8);
    }

    uint2 rk[2];
    en_loadK(kf, nh, 0, tid, rk);

    for (int kt = 0; kt < 17; ++kt) {
        if (kt) __syncthreads();
        #pragma unroll
        for (int j = 0; j < 2; ++j) {
            int i = tid + j*256;
            *(uint2*)(Ks + (i >> 3)*72 + (i & 7)*8) = rk[j];
        }
        __syncthreads();
        if (kt + 1 < 17) en_loadK(kf, nh, kt+1, tid, rk);

        f32x4 acc[4];
        #pragma unroll
        for (int nt = 0; nt < 4; ++nt) acc[nt] = {0.f,0.f,0.f,0.f};
        #pragma unroll
        for (int ks = 0; ks < 2; ++ks) {
            int ko = ks*32 + lq*8;
            long a = *(const long*)(Qs + (wave*16 + lr)*72 + ko);
            #pragma unroll
            for (int nt = 0; nt < 4; ++nt) {
                long b = *(const long*)(Ks + (nt*16 + lr)*72 + ko);
                acc[nt] = MFMAF8(a, b, acc[nt]);
            }
        }
        #pragma unroll
        for (int nt = 0; nt < 4; ++nt) {
            int kcol = kt*64 + nt*16 + lr;
            if (kcol >= KT) continue;
            #pragma unroll
            for (int reg = 0; reg < 4; ++reg) {
                int q = mt*64 + wave*16 + lq*4 + reg;
                E[(((size_t)(n*SS + q))*HH + h)*KT + kcol] = f2q(acc[nt][reg]);
            }
        }
    }
}

// ---------------------------------------------------------------------------
// K3: softmax: no-max, fp8 in/out, premix with ALiBi folded into per-head
// constant ch[h]; postmix folded into fc weights. Thread owns 4 adjacent
// cols. Mask fast-path (cndmask only when a dead column exists).
// ---------------------------------------------------------------------------
__global__ __launch_bounds__(256) void softmax_kernel(
    uchar* __restrict__ E, const int* __restrict__ mask,
    const float* __restrict__ th_pre)
{
    __shared__ float thp[64];
    __shared__ float ch[8];
    __shared__ float wred[4][8];
    const int tid = threadIdx.x;
    const int wave = tid >> 6, lane = tid & 63;
    const int blk = blockIdx.x;              // n*SS + q
    const int n = blk >> 10, q = blk & 1023;
    const float invs = 0.044194173824159216f;   // 1/sqrt(512)
    const float l2e  = 1.4426950408889634f;
    if (tid < 64) thp[tid] = th_pre[tid]*(invs*l2e);
    if (tid < 8) {
        const float sl[8] = {0.5f,0.25f,0.125f,0.0625f,
                             0.03125f,0.015625f,0.0078125f,0.00390625f};
        float c = 0.f;
        #pragma unroll
        for (int g = 0; g < 8; ++g) c += th_pre[tid*8+g]*sl[g];
        ch[tid] = c * (invs*l2e);
    }
    __syncthreads();
    uchar* Eb = E + (size_t)blk*HH*KT;
    const int* mrow = mask + (size_t)n*SS*SS + (size_t)q*SS;

    const int k0 = tid*4;                    // 4 adjacent columns
    const int4 mk = *(const int4*)(mrow + k0);
    const bool anyDead = (mk.x == 0) || (mk.y == 0) || (mk.z == 0) || (mk.w == 0);
    f32x4 dist;
    dist.x = fabsf((float)(q - k0));
    dist.y = fabsf((float)(q - k0 - 1));
    dist.z = fabsf((float)(q - k0 - 2));
    dist.w = fabsf((float)(q - k0 - 3));

    f32x4 tp[8];
    float tl[8];
    float sm[8];
    #pragma unroll
    for (int g = 0; g < 8; ++g) { sm[g] = 0.f; tl[g] = 0.f; }

    {
        f32x4 a[8];
        #pragma unroll
        for (int g = 0; g < 8; ++g) {
            uint u = *(const uint*)(Eb + g*KT + k0);
            f32x2 lo = __builtin_amdgcn_cvt_pk_f32_fp8((int)u, false);
            f32x2 hi = __builtin_amdgcn_cvt_pk_f32_fp8((int)u, true);
            f32x4 r; r.x = lo.x; r.y = lo.y; r.z = hi.x; r.w = hi.y;
            a[g] = r;
        }
        #pragma unroll
        for (int h = 0; h < 8; ++h) {
            f32x4 t = {0.f,0.f,0.f,0.f};
            #pragma unroll
            for (int g = 0; g < 8; ++g)
                t += a[g] * thp[h*8 + g];    // packed-f32 FMA candidates
            t -= dist * ch[h];               // folded ALiBi premix
            f32x4 e;
            e.x = exp2f(t.x);
            e.y = exp2f(t.y);
            e.z = exp2f(t.z);
            e.w = exp2f(t.w);
            if (anyDead) {
                if (mk.x == 0) e.x = 0.f;
                if (mk.y == 0) e.y = 0.f;
                if (mk.z == 0) e.z = 0.f;
                if (mk.w == 0) e.w = 0.f;
            }
            tp[h] = e;
            sm[h] += e.x + e.y + e.z + e.w;
        }
    }
    if (tid < 16) {                          // persistent keys (dist = 0)
        const int k = 1024 + tid;
        float a[8];
        #pragma unroll
        for (int g = 0; g < 8; ++g) {
            f32x2 r = __builtin_amdgcn_cvt_pk_f32_fp8((int)Eb[g*KT + k], false);
            a[g] = r.x;
        }
        #pragma unroll
        for (int h = 0; h < 8; ++h) {
            float t = 0.f;
            #pragma unroll
            for (int g = 0; g < 8; ++g) t = fmaf(thp[h*8 + g], a[g], t);
            float e = exp2f(t);
            tl[h] = e;
            sm[h] += e;
        }
    }
    #pragma unroll
    for (int g = 0; g < 8; ++g) {
        #pragma unroll
        for (int off = 32; off > 0; off >>= 1)
            sm[g] += __shfl_xor(sm[g], off);
    }
    if (lane == 0) {
        #pragma unroll
        for (int g = 0; g < 8; ++g) wred[wave][g] = sm[g];
    }
    __syncthreads();
    float lred[8];
    #pragma unroll
    for (int g = 0; g < 8; ++g)
        lred[g] = 1.0f / (wred[0][g] + wred[1][g] + wred[2][g] + wred[3][g]);

    // normalized probs out: one uint store per head
    #pragma unroll
    for (int h = 0; h < 8; ++h) {
        f32x4 e = tp[h] * lred[h];
        int p = __builtin_amdgcn_cvt_pk_fp8_f32(e.x, e.y, 0, false);
        p = __builtin_amdgcn_cvt_pk_fp8_f32(e.z, e.w, p, true);
        *(uint*)(Eb + h*KT + k0) = (uint)p;
    }
    if (tid < 16) {
        const int k = 1024 + tid;
        #pragma unroll
        for (int g = 0; g < 8; ++g)
            Eb[g*KT + k] = f2q(tl[g] * lred[g]);
    }
}

// ---------------------------------------------------------------------------
// K4: PV via fp8 MFMA (P fp8 x V fp8), q-tile 32, register-prefetch dbuf.
// ---------------------------------------------------------------------------
__device__ __forceinline__ void pv_loadP(const uchar* __restrict__ E,
    int n, int h, int ql0, int kt, int tid, uint2* rp)
{
    int r = tid >> 3, cg = (tid & 7)*8;
    int k = kt*64 + cg;
    uint2 v = {0u, 0u};
    if (k < KT)
        v = *(const uint2*)(E + (((size_t)(n*SS + ql0 + r))*HH + h)*KT + k);
    rp[0] = v;
}
__device__ __forceinline__ void pv_loadV(const uchar* __restrict__ vt,
    int nh, int kt, int tid, uint2* rv)
{
    #pragma unroll
    for (int j = 0; j < 2; ++j) {
        int i = tid + j*256;
        int r = i >> 3, cg = (i & 7)*8;
        int k = kt*64 + cg;
        uint2 v = {0u, 0u};
        if (k < KT)
            v = *(const uint2*)(vt + ((size_t)nh*DD + r)*KT + k);
        rv[j] = v;
    }
}

__global__ __launch_bounds__(256) void pv_mfma(
    const uchar* __restrict__ E, const uchar* __restrict__ vt,
    short* __restrict__ AO)
{
    __shared__ uchar Ps[32*72];
    __shared__ uchar Vs[64*72];
    const int tid = threadIdx.x;
    const int ql0 = blockIdx.x * 32;
    const int nh = blockIdx.y;
    const int n = nh >> 3, h = nh & 7;
    const int wave = tid >> 6, lane = tid & 63;
    const int lr = lane & 15, lq = lane >> 4;
    const int mh = wave & 1, nb = (wave >> 1)*32;

    uint2 rp[1], rv[2];
    pv_loadP(E, n, h, ql0, 0, tid, rp);
    pv_loadV(vt, nh, 0, tid, rv);

    f32x4 acc[2];
    acc[0] = {0.f,0.f,0.f,0.f}; acc[1] = {0.f,0.f,0.f,0.f};

    for (int kt = 0; kt < 17; ++kt) {
        if (kt) __syncthreads();
        {
            int r = tid >> 3, cg = (tid & 7)*8;
            *(uint2*)(Ps + r*72 + cg) = rp[0];
        }
        #pragma unroll
        for (int j = 0; j < 2; ++j) {
            int i = tid + j*256;
            *(uint2*)(Vs + (i >> 3)*72 + (i & 7)*8) = rv[j];
        }
        __syncthreads();
        if (kt + 1 < 17) {
            pv_loadP(E, n, h, ql0, kt+1, tid, rp);
            pv_loadV(vt, nh, kt+1, tid, rv);
        }
        #pragma unroll
        for (int ks = 0; ks < 2; ++ks) {
            int ko = ks*32 + lq*8;
            long a = *(const long*)(Ps + (mh*16 + lr)*72 + ko);
            #pragma unroll
            for (int nt = 0; nt < 2; ++nt) {
                long b = *(const long*)(Vs + (nb + nt*16 + lr)*72 + ko);
                acc[nt] = MFMAF8(a, b, acc[nt]);
            }
        }
    }
    #pragma unroll
    for (int nt = 0; nt < 2; ++nt) {
        int d = nb + nt*16 + lr;
        #pragma unroll
        for (int reg = 0; reg < 4; ++reg) {
            int qg = ql0 + mh*16 + lq*4 + reg;
            AO[((size_t)(n*SS) + qg)*CC + h*64 + d] = f2s(acc[nt][reg]);
        }
    }
}

// ---------------------------------------------------------------------------
// K5: fc (th_post folded into weights), bf16 MFMA, 64x64, XCD-swizzled.
// Writes xres (bf16) AND xres8 (fp8 copy for conv1's A operand).
// ---------------------------------------------------------------------------
__device__ __forceinline__ void g_load4(const short* __restrict__ src,
    size_t rowstride, int row0, int col0, int tid, short4* r)
{
    #pragma unroll
    for (int j = 0; j < 4; ++j) {
        int i = tid + j*256;
        int rr = i >> 4, cg = (i & 15)*4;
        r[j] = *(const short4*)(src + (size_t)(row0 + rr)*rowstride + col0 + cg);
    }
}
__device__ __forceinline__ void lds_store4(short* __restrict__ dst,
    int tid, const short4* r)
{
    #pragma unroll
    for (int j = 0; j < 4; ++j) {
        int i = tid + j*256;
        *(short4*)(dst + (i >> 4)*72 + (i & 15)*4) = r[j];
    }
}

__global__ __launch_bounds__(256) void fc_mfma(
    const short* __restrict__ A, const short* __restrict__ Bt,
    const float* __restrict__ bias, const float* __restrict__ x,
    short* __restrict__ out, uchar* __restrict__ out8)
{
    __shared__ short As[64*72];
    __shared__ short Bs[64*72];
    const int tid = threadIdx.x;
    const int lin = blockIdx.x + 8*blockIdx.y;      // grid (8,128)
    const int xcd = lin & 7, slot = lin >> 3;
    const int m0 = (xcd*16 + (slot & 15))*64;
    const int n0 = (slot >> 4)*64;
    const int wave = tid >> 6, lane = tid & 63;
    const int lr = lane & 15, lq = lane >> 4;

    short4 ra[4], rb[4];
    g_load4(A, CC, m0, 0, tid, ra);
    g_load4(Bt, CC, n0, 0, tid, rb);

    f32x4 acc[4];
    #pragma unroll
    for (int nt = 0; nt < 4; ++nt) acc[nt] = {0.f,0.f,0.f,0.f};

    for (int kt = 0; kt < CC; kt += 64) {
        if (kt) __syncthreads();
        lds_store4(As, tid, ra);
        lds_store4(Bs, tid, rb);
        __syncthreads();
        if (kt + 64 < CC) {
            g_load4(A, CC, m0, kt+64, tid, ra);
            g_load4(Bt, CC, n0, kt+64, tid, rb);
        }
        #pragma unroll
        for (int ks = 0; ks < 2; ++ks) {
            int ko = ks*32 + lq*8;
            short8 a = *(const short8*)(As + (wave*16 + lr)*72 + ko);
            #pragma unroll
            for (int nt = 0; nt < 4; ++nt) {
                short8 b = *(const short8*)(Bs + (nt*16 + lr)*72 + ko);
                acc[nt] = MFMA16(a, b, acc[nt]);
            }
        }
    }
    #pragma unroll
    for (int nt = 0; nt < 4; ++nt) {
        int nn = n0 + nt*16 + lr;
        #pragma unroll
        for (int reg = 0; reg < 4; ++reg) {
            int m = m0 + wave*16 + lq*4 + reg;
            float v = acc[nt][reg] + bias[nn] + x[(size_t)m*CC + nn];
            out[(size_t)m*CC + nn]  = f2s(v);
            out8[(size_t)m*CC + nn] = f2q(v);
        }
    }
}

// ---------------------------------------------------------------------------
// K6: causal conv as fp8 NT GEMM K=1536, 64x64, XCD-swizzled, prefetch.
// Weights pre-scaled x16 -> acc descaled x(1/16). f8out: h1 fp8 / c2 bf16.
// ---------------------------------------------------------------------------
__device__ __forceinline__ void conv_loadA8(const uchar* __restrict__ A,
    int m0, int kt, int tid, uint2* ra)
{
    const int shift = (kt >> 9) - 2;
    const int ci0 = kt & 511;
    #pragma unroll
    for (int j = 0; j < 2; ++j) {
        int i = tid + j*256;
        int rr = i >> 3, c8 = (i & 7)*8;
        int m = m0 + rr;
        int s = m & (SS-1);
        uint2 v = {0u, 0u};
        if (s + shift >= 0)
            v = *(const uint2*)(A + (size_t)(m + shift)*CC + ci0 + c8);
        ra[j] = v;
    }
}
__device__ __forceinline__ void g_load8(const uchar* __restrict__ src,
    size_t rowstride, int row0, int col0, int tid, uint2* r)
{
    #pragma unroll
    for (int j = 0; j < 2; ++j) {
        int i = tid + j*256;
        int rr = i >> 3, c8 = (i & 7)*8;
        r[j] = *(const uint2*)(src + (size_t)(row0 + rr)*rowstride + col0 + c8);
    }
}
__device__ __forceinline__ void lds_store8(uchar* __restrict__ dst,
    int tid, const uint2* r)
{
    #pragma unroll
    for (int j = 0; j < 2; ++j) {
        int i = tid + j*256;
        *(uint2*)(dst + (i >> 3)*72 + (i & 7)*8) = r[j];
    }
}

__global__ __launch_bounds__(256) void conv_mfma8(
    const uchar* __restrict__ A, const uchar* __restrict__ Bt,
    const float* __restrict__ bias, uchar* __restrict__ out8,
    short* __restrict__ out16, int f8out)
{
    __shared__ uchar As[64*72];
    __shared__ uchar Bs[64*72];
    const int tid = threadIdx.x;
    const int lin = blockIdx.x + 8*blockIdx.y;      // grid (8,128)
    const int xcd = lin & 7, slot = lin >> 3;
    const int m0 = (xcd*16 + (slot & 15))*64;
    const int n0 = (slot >> 4)*64;
    const int wave = tid >> 6, lane = tid & 63;
    const int lr = lane & 15, lq = lane >> 4;

    uint2 ra[2], rb[2];
    conv_loadA8(A, m0, 0, tid, ra);
    g_load8(Bt, 1536, n0, 0, tid, rb);

    f32x4 acc[4];
    #pragma unroll
    for (int nt = 0; nt < 4; ++nt) acc[nt] = {0.f,0.f,0.f,0.f};

    for (int kt = 0; kt < 1536; kt += 64) {
        if (kt) __syncthreads();
        lds_store8(As, tid, ra);
        lds_store8(Bs, tid, rb);
        __syncthreads();
        if (kt + 64 < 1536) {
            conv_loadA8(A, m0, kt+64, tid, ra);
            g_load8(Bt, 1536, n0, kt+64, tid, rb);
        }
        #pragma unroll
        for (int ks = 0; ks < 2; ++ks) {
            int ko = ks*32 + lq*8;
            long a = *(const long*)(As + (wave*16 + lr)*72 + ko);
            #pragma unroll
            for (int nt = 0; nt < 4; ++nt) {
                long b = *(const long*)(Bs + (nt*16 + lr)*72 + ko);
                acc[nt] = MFMAF8(a, b, acc[nt]);
            }
        }
    }
    #pragma unroll
    for (int nt = 0; nt < 4; ++nt) {
        int nn = n0 + nt*16 + lr;
        #pragma unroll
        for (int reg = 0; reg < 4; ++reg) {
            int m = m0 + wave*16 + lq*4 + reg;
            float v = fmaxf(acc[nt][reg]*0.0625f + bias[nn], 0.f);
            if (f8out) out8[(size_t)m*CC + nn]  = f2q(v);
            else       out16[(size_t)m*CC + nn] = f2s(v);
        }
    }
}

// ---------------------------------------------------------------------------
// K7: out = LN(relu(c2 + xres) masked) * g + b.  short2 in / float2 out.
// ---------------------------------------------------------------------------
__global__ __launch_bounds__(256) void final_kernel(
    const short* __restrict__ c2, const short* __restrict__ xres,
    const int* __restrict__ mask, const float* __restrict__ g,
    const float* __restrict__ b, float* __restrict__ out)
{
    __shared__ float red[256];
    const int tid = threadIdx.x;
    const int m = blockIdx.x;
    const int n = m >> 10, s = m & 1023;
    const int mk = mask[(size_t)n*SS*SS + (size_t)s*SS];
    const int c0 = tid*2;

    short2 ca = *(const short2*)(c2 + (size_t)m*CC + c0);
    short2 xa = *(const short2*)(xres + (size_t)m*CC + c0);
    float v0 = fmaxf(s2f(ca.x) + s2f(xa.x), 0.f);
    float v1 = fmaxf(s2f(ca.y) + s2f(xa.y), 0.f);
    if (mk == 0) { v0 = 0.f; v1 = 0.f; }

    red[tid] = v0 + v1;
    __syncthreads();
    for (int off = 128; off > 0; off >>= 1) {
        if (tid < off) red[tid] += red[tid + off];
        __syncthreads();
    }
    float mu = red[0] * (1.0f/512.0f);
    __syncthreads();
    float d0 = v0 - mu, d1 = v1 - mu;
    red[tid] = d0*d0 + d1*d1;
    __syncthreads();
    for (int off = 128; off > 0; off >>= 1) {
        if (tid < off) red[tid] += red[tid + off];
        __syncthreads();
    }
    float rstd = rsqrtf(red[0] * (1.0f/512.0f) + 1e-5f);
    float2 gg = *(const float2*)(g + c0);
    float2 bb = *(const float2*)(b + c0);
    float2 o;
    o.x = d0*rstd*gg.x + bb.x;
    o.y = d1*rstd*gg.y + bb.y;
    *(float2*)(out + (size_t)m*CC + c0) = o;
}

// ---------------------------------------------------------------------------
extern "C" void kernel_launch(void* const* d_in, const int* in_sizes, int n_in,
                              void* d_out, int out_size, void* d_ws, size_t ws_size,
                              hipStream_t stream)
{
    const float* x      = (const float*)d_in[0];
    const int*   mask   = (const int*)  d_in[1];
    const float* Wq     = (const float*)d_in[2];
    const float* Wk     = (const float*)d_in[3];
    const float* Wv     = (const float*)d_in[4];
    const float* pk     = (const float*)d_in[5];
    const float* pv     = (const float*)d_in[6];
    const float* th_pre = (const float*)d_in[7];
    const float* th_post= (const float*)d_in[8];
    const float* fc_w   = (const float*)d_in[9];
    const float* fc_b   = (const float*)d_in[10];
    const float* c1w    = (const float*)d_in[11];
    const float* c1b    = (const float*)d_in[12];
    const float* c2w    = (const float*)d_in[13];
    const float* c2b    = (const float*)d_in[14];
    const float* lng    = (const float*)d_in[15];
    const float* lnb    = (const float*)d_in[16];
    float* out = (float*)d_out;
    (void)in_sizes; (void)n_in; (void)out_size; (void)ws_size;

    char* ws = (char*)d_ws;
    const size_t SZ_Q  = (size_t)BN*HH*SS*DD;      //  4.19 MB (fp8)
    const size_t SZ_K  = (size_t)BN*HH*KT*DD;      //  4.26 MB (fp8)
    const size_t SZ_VT = (size_t)BN*HH*DD*KT;      //  4.26 MB (fp8)
    const size_t SZ_E  = (size_t)BN*SS*HH*KT;      // 68.2 MB (fp8)
    const size_t SZ_A  = (size_t)BN*SS*CC*2;       //  8.39 MB (bf16)
    const size_t SZ_A8 = (size_t)BN*SS*CC;         //  4.19 MB (fp8)

    uchar* qf  = (uchar*)(ws);
    uchar* kf  = (uchar*)(ws + SZ_Q);
    uchar* vt  = (uchar*)(ws + SZ_Q + SZ_K);
    uchar* E   = (uchar*)(ws + SZ_Q + SZ_K + SZ_VT);
    short* AO  = (short*)(ws + SZ_Q + SZ_K + SZ_VT + SZ_E);
    char*  wend = ws + SZ_Q + SZ_K + SZ_VT + SZ_E + SZ_A;
    short* Bfc = (short*)(wend);
    uchar* Bc1 = (uchar*)(wend + 512*512*2);
    uchar* Bc2 = (uchar*)(wend + 512*512*2 + 512*1536);
    short* Bqkv= (short*)(wend + 512*512*2 + 2*512*1536);
    uchar* xres8 = (uchar*)(wend + 512*512*2 + 2*512*1536 + 3*64*64*2);
    short* c2buf = (short*)(wend + 512*512*2 + 2*512*1536 + 3*64*64*2 + SZ_A8);
    // Aliases (dead regions): xres(bf16) over qf+kf (dead after energy);
    // h1(fp8) over E (dead after pv).
    short* xres = (short*)(ws);
    uchar* h18  = (uchar*)E;
    // total ws ~= 103 MB (ws_size >= 256 MiB)

    {
        int total = 512*512 + 2*512*1536 + 3*64*64;
        prep_kernel<<<(total + 255)/256, 256, 0, stream>>>(
            fc_w, c1w, c2w, Wq, Wk, Wv, th_post, Bfc, Bc1, Bc2, Bqkv);
    }
    qkv_mfma<<<dim3(BN*SS/64, HH), 256, 0, stream>>>(x, Bqkv, qf, kf, vt);
    persist_kernel<<<(BN*HH*PP*DD + 255)/256, 256, 0, stream>>>(pk, pv, kf, vt);

    energy_mfma8<<<dim3(SS/64, BN*HH), 256, 0, stream>>>(qf, kf, E);
    softmax_kernel<<<BN*SS, 256, 0, stream>>>(E, mask, th_pre);
    pv_mfma<<<dim3(SS/32, BN*HH), 256, 0, stream>>>(E, vt, AO);

    fc_mfma<<<dim3(8, 128), 256, 0, stream>>>(AO, Bfc, fc_b, x, xres, xres8);
    conv_mfma8<<<dim3(8, 128), 256, 0, stream>>>(xres8, Bc1, c1b, h18, (short*)nullptr, 1);
    conv_mfma8<<<dim3(8, 128), 256, 0, stream>>>(h18, Bc2, c2b, (uchar*)nullptr, c2buf, 0);
    final_kernel<<<BN*SS, 256, 0, stream>>>(c2buf, xres, mask, lng, lnb, out);
}

// Round 17
// 298.634 us; speedup vs baseline: 1.6810x; 1.0227x over previous
//
#include <hip/hip_runtime.h>
#include <hip/hip_bf16.h>

#define BN 8
#define SS 1024
#define CC 512
#define HH 8
#define DD 64
#define PP 16
#define KT 1040

typedef __hip_bfloat16 bf16;
typedef unsigned char uchar;
typedef unsigned short ushort;
typedef unsigned int uint;
typedef __attribute__((ext_vector_type(8))) short short8;
typedef __attribute__((ext_vector_type(4))) float f32x4;
typedef __attribute__((ext_vector_type(2))) float f32x2;

__device__ __forceinline__ short f2s(float v){ bf16 b = __float2bfloat16(v); return *(short*)&b; }
__device__ __forceinline__ float s2f(short s){ bf16 b; *(short*)&b = s; return __bfloat162float(b); }
__device__ __forceinline__ uchar f2q(float v){          // f32 -> fp8 e4m3 byte
    return (uchar)__builtin_amdgcn_cvt_pk_fp8_f32(v, v, 0, false);
}

#define MFMA16(a,b,c)  __builtin_amdgcn_mfma_f32_16x16x32_bf16(a,b,c,0,0,0)
#define MFMAF8(a,b,c)  __builtin_amdgcn_mfma_f32_16x16x32_fp8_fp8(a,b,c,0,0,0)

// ---------------------------------------------------------------------------
// P0: weight pre-conversion. fc -> bf16 with th_post FOLDED IN:
//   Bfc[c, g*64+d] = sum_h fc_w[c, h*64+d] * th_post[h,g]
// conv weights -> fp8 scaled x16; qkv -> bf16.
// ---------------------------------------------------------------------------
__global__ __launch_bounds__(256) void prep_kernel(
    const float* __restrict__ fc_w, const float* __restrict__ c1w,
    const float* __restrict__ c2w, const float* __restrict__ Wq,
    const float* __restrict__ Wk, const float* __restrict__ Wv,
    const float* __restrict__ th_post,
    short* __restrict__ Bfc, uchar* __restrict__ Bc1,
    uchar* __restrict__ Bc2, short* __restrict__ Bqkv)
{
    int i = blockIdx.x*256 + threadIdx.x;
    const int NFC = 512*512, NCV = 512*1536, NQ = 3*64*64;
    if (i < NFC) {
        int c = i >> 9, r = i & 511;
        int g = r >> 6, d = r & 63;
        float s = 0.f;
        #pragma unroll
        for (int h = 0; h < 8; ++h)
            s += fc_w[(size_t)c*512 + h*64 + d] * th_post[h*8 + g];
        Bfc[i] = f2s(s);
        return;
    }
    i -= NFC;
    if (i < NCV) {
        int o = i/1536, r = i%1536, dk = r>>9, ci = r&511;
        Bc1[i] = f2q(c1w[(o*512+ci)*3+dk] * 16.f); return;
    }
    i -= NCV;
    if (i < NCV) {
        int o = i/1536, r = i%1536, dk = r>>9, ci = r&511;
        Bc2[i] = f2q(c2w[(o*512+ci)*3+dk] * 16.f); return;
    }
    i -= NCV;
    if (i < NQ) {
        int w = i >> 12, rest = i & 4095;
        const float* W = (w==0)?Wq:(w==1)?Wk:Wv;
        Bqkv[i] = f2s(W[((rest>>6)&63)*64 + (rest&63)]);
    }
}

// ---------------------------------------------------------------------------
// K1: QKV projection, bf16 MFMA. q/k out fp8 [s][d]; V written DIRECTLY into
// transposed fp8 vt[nh][d][k=s].
// ---------------------------------------------------------------------------
__global__ __launch_bounds__(256) void qkv_mfma(
    const float* __restrict__ x, const short* __restrict__ Bqkv,
    uchar* __restrict__ qf, uchar* __restrict__ kf, uchar* __restrict__ vt)
{
    __shared__ short Xs[64*72];
    __shared__ short Ws[192*72];
    const int tid = threadIdx.x;
    const int m0 = blockIdx.x * 64;
    const int h = blockIdx.y;
    const int wave = tid >> 6, lane = tid & 63;
    const int lr = lane & 15, lq = lane >> 4;

    for (int i = tid; i < 1024; i += 256) {
        int r = i >> 4, cg = (i & 15)*4;
        float4 v = *(const float4*)(x + (size_t)(m0+r)*CC + h*64 + cg);
        Xs[r*72+cg+0] = f2s(v.x); Xs[r*72+cg+1] = f2s(v.y);
        Xs[r*72+cg+2] = f2s(v.z); Xs[r*72+cg+3] = f2s(v.w);
    }
    for (int i = tid; i < 3072; i += 256) {
        int r = i >> 4, cg = (i & 15)*4;
        *(short4*)(Ws + r*72 + cg) = *(const short4*)(Bqkv + (size_t)r*64 + cg);
    }
    __syncthreads();

    f32x4 acc[12];
    #pragma unroll
    for (int nt = 0; nt < 12; ++nt) acc[nt] = {0.f,0.f,0.f,0.f};
    #pragma unroll
    for (int ks = 0; ks < 2; ++ks) {
        int ko = ks*32 + lq*8;
        short8 a = *(const short8*)(Xs + (wave*16 + lr)*72 + ko);
        #pragma unroll
        for (int nt = 0; nt < 12; ++nt) {
            short8 b = *(const short8*)(Ws + (nt*16 + lr)*72 + ko);
            acc[nt] = MFMA16(a, b, acc[nt]);
        }
    }
    #pragma unroll
    for (int nt = 0; nt < 12; ++nt) {
        int ep = nt*16 + lr;
        int w = ep >> 6, e = ep & 63;
        #pragma unroll
        for (int reg = 0; reg < 4; ++reg) {
            int m = m0 + wave*16 + lq*4 + reg;
            int n = m >> 10, s = m & 1023;
            float v = acc[nt][reg];
            if (w == 0)      qf[((size_t)(n*HH+h)*SS + s)*DD + e] = f2q(v);
            else if (w == 1) kf[((size_t)(n*HH+h)*KT + s)*DD + e] = f2q(v);
            else             vt[(((size_t)(n*HH+h))*DD + e)*KT + s] = f2q(v);
        }
    }
}

// ---------------------------------------------------------------------------
// K1b: persistent tokens -> kf tail (fp8 [k][d]) and vt tail (fp8 [d][k]).
// ---------------------------------------------------------------------------
__global__ __launch_bounds__(256) void persist_kernel(
    const float* __restrict__ pk, const float* __restrict__ pv,
    uchar* __restrict__ kf, uchar* __restrict__ vt)
{
    int idx = blockIdx.x*256 + threadIdx.x;
    if (idx >= BN*HH*PP*DD) return;
    int d = idx & 63, p = (idx >> 6) & 15, h = (idx >> 10) & 7, n = idx >> 13;
    size_t src = ((size_t)p*HH + h)*DD + d;
    kf[(((size_t)(n*HH+h))*KT + SS + p)*DD + d] = f2q(pk[src]);
    vt[(((size_t)(n*HH+h))*DD + d)*KT + SS + p] = f2q(pv[src]);
}

// ---------------------------------------------------------------------------
// K2 v2: energy, fp8 MFMA NT. Block = (mt, nh), grid 1024. Q staged ONCE;
// loop over 17 k-tiles with register-prefetch dbuf (pv pattern).
// ---------------------------------------------------------------------------
__device__ __forceinline__ void en_loadK(const uchar* __restrict__ kf,
    int nh, int kt, int tid, uint2* rk)
{
    #pragma unroll
    for (int j = 0; j < 2; ++j) {
        int i = tid + j*256;
        int r = i >> 3, c8 = (i & 7)*8;
        int kcol = kt*64 + r;
        uint2 v = {0u, 0u};
        if (kcol < KT)
            v = *(const uint2*)(kf + ((size_t)nh*KT + kcol)*DD + c8);
        rk[j] = v;
    }
}

__global__ __launch_bounds__(256) void energy_mfma8(
    const uchar* __restrict__ qf, const uchar* __restrict__ kf,
    uchar* __restrict__ E)
{
    __shared__ uchar Qs[64*72];
    __shared__ uchar Ks[64*72];
    const int tid = threadIdx.x;
    const int mt = blockIdx.x;
    const int nh = blockIdx.y;
    const int wave = tid >> 6, lane = tid & 63;
    const int lr = lane & 15, lq = lane >> 4;
    const int n = nh >> 3, h = nh & 7;

    #pragma unroll
    for (int j = 0; j < 2; ++j) {
        int i = tid + j*256;
        int r = i >> 3, c8 = (i & 7)*8;
        *(uint2*)(Qs + r*72 + c8) =
            *(const uint2*)(qf + ((size_t)nh*SS + mt*64 + r)*DD + c8);
    }

    uint2 rk[2];
    en_loadK(kf, nh, 0, tid, rk);

    for (int kt = 0; kt < 17; ++kt) {
        if (kt) __syncthreads();
        #pragma unroll
        for (int j = 0; j < 2; ++j) {
            int i = tid + j*256;
            *(uint2*)(Ks + (i >> 3)*72 + (i & 7)*8) = rk[j];
        }
        __syncthreads();
        if (kt + 1 < 17) en_loadK(kf, nh, kt+1, tid, rk);

        f32x4 acc[4];
        #pragma unroll
        for (int nt = 0; nt < 4; ++nt) acc[nt] = {0.f,0.f,0.f,0.f};
        #pragma unroll
        for (int ks = 0; ks < 2; ++ks) {
            int ko = ks*32 + lq*8;
            long a = *(const long*)(Qs + (wave*16 + lr)*72 + ko);
            #pragma unroll
            for (int nt = 0; nt < 4; ++nt) {
                long b = *(const long*)(Ks + (nt*16 + lr)*72 + ko);
                acc[nt] = MFMAF8(a, b, acc[nt]);
            }
        }
        #pragma unroll
        for (int nt = 0; nt < 4; ++nt) {
            int kcol = kt*64 + nt*16 + lr;
            if (kcol >= KT) continue;
            #pragma unroll
            for (int reg = 0; reg < 4; ++reg) {
                int q = mt*64 + wave*16 + lq*4 + reg;
                E[(((size_t)(n*SS + q))*HH + h)*KT + kcol] = f2q(acc[nt][reg]);
            }
        }
    }
}

// ---------------------------------------------------------------------------
// K3: softmax (r15 version — 52 VGPR sweet spot): no-max, fp8 in/out,
// premix in-kernel (ALiBi fused into per-g load), postmix folded into fc.
// Thread owns 4 adjacent cols; single-uint loads/stores per head.
// ---------------------------------------------------------------------------
__global__ __launch_bounds__(256) void softmax_kernel(
    uchar* __restrict__ E, const int* __restrict__ mask,
    const float* __restrict__ th_pre)
{
    __shared__ float thp[64];
    __shared__ float wred[4][8];
    const int tid = threadIdx.x;
    const int wave = tid >> 6, lane = tid & 63;
    const int blk = blockIdx.x;              // n*SS + q
    const int n = blk >> 10, q = blk & 1023;
    const float invs = 0.044194173824159216f;   // 1/sqrt(512)
    const float l2e  = 1.4426950408889634f;
    if (tid < 64) thp[tid] = th_pre[tid]*(invs*l2e);
    __syncthreads();
    uchar* Eb = E + (size_t)blk*HH*KT;

    const float sl[8] = {0.5f,0.25f,0.125f,0.0625f,
                         0.03125f,0.015625f,0.0078125f,0.00390625f};
    const int* mrow = mask + (size_t)n*SS*SS + (size_t)q*SS;

    const int k0 = tid*4;                    // 4 adjacent columns
    const int4 mk = *(const int4*)(mrow + k0);
    f32x4 dist;
    dist.x = fabsf((float)(q - k0));
    dist.y = fabsf((float)(q - k0 - 1));
    dist.z = fabsf((float)(q - k0 - 2));
    dist.w = fabsf((float)(q - k0 - 3));

    f32x4 tp[8];
    float tl[8];
    float sm[8];
    #pragma unroll
    for (int g = 0; g < 8; ++g) { sm[g] = 0.f; tl[g] = 0.f; }

    {
        f32x4 a[8];
        #pragma unroll
        for (int g = 0; g < 8; ++g) {
            uint u = *(const uint*)(Eb + g*KT + k0);
            f32x2 lo = __builtin_amdgcn_cvt_pk_f32_fp8((int)u, false);
            f32x2 hi = __builtin_amdgcn_cvt_pk_f32_fp8((int)u, true);
            f32x4 r; r.x = lo.x; r.y = lo.y; r.z = hi.x; r.w = hi.y;
            a[g] = r - dist*sl[g];
        }
        #pragma unroll
        for (int h = 0; h < 8; ++h) {
            f32x4 t = {0.f,0.f,0.f,0.f};
            #pragma unroll
            for (int g = 0; g < 8; ++g)
                t += a[g] * thp[h*8 + g];    // packed-f32 FMA candidates
            f32x4 e;
            e.x = (mk.x == 0) ? 0.f : exp2f(t.x);
            e.y = (mk.y == 0) ? 0.f : exp2f(t.y);
            e.z = (mk.z == 0) ? 0.f : exp2f(t.z);
            e.w = (mk.w == 0) ? 0.f : exp2f(t.w);
            tp[h] = e;
            sm[h] += e.x + e.y + e.z + e.w;
        }
    }
    if (tid < 16) {                          // persistent keys
        const int k = 1024 + tid;
        float a[8];
        #pragma unroll
        for (int g = 0; g < 8; ++g) {
            f32x2 r = __builtin_amdgcn_cvt_pk_f32_fp8((int)Eb[g*KT + k], false);
            a[g] = r.x;
        }
        #pragma unroll
        for (int h = 0; h < 8; ++h) {
            float t = 0.f;
            #pragma unroll
            for (int g = 0; g < 8; ++g) t = fmaf(thp[h*8 + g], a[g], t);
            float e = exp2f(t);
            tl[h] = e;
            sm[h] += e;
        }
    }
    #pragma unroll
    for (int g = 0; g < 8; ++g) {
        #pragma unroll
        for (int off = 32; off > 0; off >>= 1)
            sm[g] += __shfl_xor(sm[g], off);
    }
    if (lane == 0) {
        #pragma unroll
        for (int g = 0; g < 8; ++g) wred[wave][g] = sm[g];
    }
    __syncthreads();
    float lred[8];
    #pragma unroll
    for (int g = 0; g < 8; ++g)
        lred[g] = 1.0f / (wred[0][g] + wred[1][g] + wred[2][g] + wred[3][g]);

    // normalized probs out: one uint store per head
    #pragma unroll
    for (int h = 0; h < 8; ++h) {
        f32x4 e = tp[h] * lred[h];
        int p = __builtin_amdgcn_cvt_pk_fp8_f32(e.x, e.y, 0, false);
        p = __builtin_amdgcn_cvt_pk_fp8_f32(e.z, e.w, p, true);
        *(uint*)(Eb + h*KT + k0) = (uint)p;
    }
    if (tid < 16) {
        const int k = 1024 + tid;
        #pragma unroll
        for (int g = 0; g < 8; ++g)
            Eb[g*KT + k] = f2q(tl[g] * lred[g]);
    }
}

// ---------------------------------------------------------------------------
// K4: PV via fp8 MFMA (P fp8 x V fp8), q-tile 32, register-prefetch dbuf.
// ---------------------------------------------------------------------------
__device__ __forceinline__ void pv_loadP(const uchar* __restrict__ E,
    int n, int h, int ql0, int kt, int tid, uint2* rp)
{
    int r = tid >> 3, cg = (tid & 7)*8;
    int k = kt*64 + cg;
    uint2 v = {0u, 0u};
    if (k < KT)
        v = *(const uint2*)(E + (((size_t)(n*SS + ql0 + r))*HH + h)*KT + k);
    rp[0] = v;
}
__device__ __forceinline__ void pv_loadV(const uchar* __restrict__ vt,
    int nh, int kt, int tid, uint2* rv)
{
    #pragma unroll
    for (int j = 0; j < 2; ++j) {
        int i = tid + j*256;
        int r = i >> 3, cg = (i & 7)*8;
        int k = kt*64 + cg;
        uint2 v = {0u, 0u};
        if (k < KT)
            v = *(const uint2*)(vt + ((size_t)nh*DD + r)*KT + k);
        rv[j] = v;
    }
}

__global__ __launch_bounds__(256) void pv_mfma(
    const uchar* __restrict__ E, const uchar* __restrict__ vt,
    short* __restrict__ AO)
{
    __shared__ uchar Ps[32*72];
    __shared__ uchar Vs[64*72];
    const int tid = threadIdx.x;
    const int ql0 = blockIdx.x * 32;
    const int nh = blockIdx.y;
    const int n = nh >> 3, h = nh & 7;
    const int wave = tid >> 6, lane = tid & 63;
    const int lr = lane & 15, lq = lane >> 4;
    const int mh = wave & 1, nb = (wave >> 1)*32;

    uint2 rp[1], rv[2];
    pv_loadP(E, n, h, ql0, 0, tid, rp);
    pv_loadV(vt, nh, 0, tid, rv);

    f32x4 acc[2];
    acc[0] = {0.f,0.f,0.f,0.f}; acc[1] = {0.f,0.f,0.f,0.f};

    for (int kt = 0; kt < 17; ++kt) {
        if (kt) __syncthreads();
        {
            int r = tid >> 3, cg = (tid & 7)*8;
            *(uint2*)(Ps + r*72 + cg) = rp[0];
        }
        #pragma unroll
        for (int j = 0; j < 2; ++j) {
            int i = tid + j*256;
            *(uint2*)(Vs + (i >> 3)*72 + (i & 7)*8) = rv[j];
        }
        __syncthreads();
        if (kt + 1 < 17) {
            pv_loadP(E, n, h, ql0, kt+1, tid, rp);
            pv_loadV(vt, nh, kt+1, tid, rv);
        }
        #pragma unroll
        for (int ks = 0; ks < 2; ++ks) {
            int ko = ks*32 + lq*8;
            long a = *(const long*)(Ps + (mh*16 + lr)*72 + ko);
            #pragma unroll
            for (int nt = 0; nt < 2; ++nt) {
                long b = *(const long*)(Vs + (nb + nt*16 + lr)*72 + ko);
                acc[nt] = MFMAF8(a, b, acc[nt]);
            }
        }
    }
    #pragma unroll
    for (int nt = 0; nt < 2; ++nt) {
        int d = nb + nt*16 + lr;
        #pragma unroll
        for (int reg = 0; reg < 4; ++reg) {
            int qg = ql0 + mh*16 + lq*4 + reg;
            AO[((size_t)(n*SS) + qg)*CC + h*64 + d] = f2s(acc[nt][reg]);
        }
    }
}

// ---------------------------------------------------------------------------
// K5: fc (th_post folded into weights), bf16 MFMA, 64x64, XCD-swizzled.
// Writes xres (bf16) AND xres8 (fp8 copy for conv1's A operand).
// ---------------------------------------------------------------------------
__device__ __forceinline__ void g_load4(const short* __restrict__ src,
    size_t rowstride, int row0, int col0, int tid, short4* r)
{
    #pragma unroll
    for (int j = 0; j < 4; ++j) {
        int i = tid + j*256;
        int rr = i >> 4, cg = (i & 15)*4;
        r[j] = *(const short4*)(src + (size_t)(row0 + rr)*rowstride + col0 + cg);
    }
}
__device__ __forceinline__ void lds_store4(short* __restrict__ dst,
    int tid, const short4* r)
{
    #pragma unroll
    for (int j = 0; j < 4; ++j) {
        int i = tid + j*256;
        *(short4*)(dst + (i >> 4)*72 + (i & 15)*4) = r[j];
    }
}

__global__ __launch_bounds__(256) void fc_mfma(
    const short* __restrict__ A, const short* __restrict__ Bt,
    const float* __restrict__ bias, const float* __restrict__ x,
    short* __restrict__ out, uchar* __restrict__ out8)
{
    __shared__ short As[64*72];
    __shared__ short Bs[64*72];
    const int tid = threadIdx.x;
    const int lin = blockIdx.x + 8*blockIdx.y;      // grid (8,128)
    const int xcd = lin & 7, slot = lin >> 3;
    const int m0 = (xcd*16 + (slot & 15))*64;
    const int n0 = (slot >> 4)*64;
    const int wave = tid >> 6, lane = tid & 63;
    const int lr = lane & 15, lq = lane >> 4;

    short4 ra[4], rb[4];
    g_load4(A, CC, m0, 0, tid, ra);
    g_load4(Bt, CC, n0, 0, tid, rb);

    f32x4 acc[4];
    #pragma unroll
    for (int nt = 0; nt < 4; ++nt) acc[nt] = {0.f,0.f,0.f,0.f};

    for (int kt = 0; kt < CC; kt += 64) {
        if (kt) __syncthreads();
        lds_store4(As, tid, ra);
        lds_store4(Bs, tid, rb);
        __syncthreads();
        if (kt + 64 < CC) {
            g_load4(A, CC, m0, kt+64, tid, ra);
            g_load4(Bt, CC, n0, kt+64, tid, rb);
        }
        #pragma unroll
        for (int ks = 0; ks < 2; ++ks) {
            int ko = ks*32 + lq*8;
            short8 a = *(const short8*)(As + (wave*16 + lr)*72 + ko);
            #pragma unroll
            for (int nt = 0; nt < 4; ++nt) {
                short8 b = *(const short8*)(Bs + (nt*16 + lr)*72 + ko);
                acc[nt] = MFMA16(a, b, acc[nt]);
            }
        }
    }
    #pragma unroll
    for (int nt = 0; nt < 4; ++nt) {
        int nn = n0 + nt*16 + lr;
        #pragma unroll
        for (int reg = 0; reg < 4; ++reg) {
            int m = m0 + wave*16 + lq*4 + reg;
            float v = acc[nt][reg] + bias[nn] + x[(size_t)m*CC + nn];
            out[(size_t)m*CC + nn]  = f2s(v);
            out8[(size_t)m*CC + nn] = f2q(v);
        }
    }
}

// ---------------------------------------------------------------------------
// K6: causal conv as fp8 NT GEMM K=1536, 64x64, XCD-swizzled, prefetch.
// Weights pre-scaled x16 -> acc descaled x(1/16). f8out: h1 fp8 / c2 bf16.
// ---------------------------------------------------------------------------
__device__ __forceinline__ void conv_loadA8(const uchar* __restrict__ A,
    int m0, int kt, int tid, uint2* ra)
{
    const int shift = (kt >> 9) - 2;
    const int ci0 = kt & 511;
    #pragma unroll
    for (int j = 0; j < 2; ++j) {
        int i = tid + j*256;
        int rr = i >> 3, c8 = (i & 7)*8;
        int m = m0 + rr;
        int s = m & (SS-1);
        uint2 v = {0u, 0u};
        if (s + shift >= 0)
            v = *(const uint2*)(A + (size_t)(m + shift)*CC + ci0 + c8);
        ra[j] = v;
    }
}
__device__ __forceinline__ void g_load8(const uchar* __restrict__ src,
    size_t rowstride, int row0, int col0, int tid, uint2* r)
{
    #pragma unroll
    for (int j = 0; j < 2; ++j) {
        int i = tid + j*256;
        int rr = i >> 3, c8 = (i & 7)*8;
        r[j] = *(const uint2*)(src + (size_t)(row0 + rr)*rowstride + col0 + c8);
    }
}
__device__ __forceinline__ void lds_store8(uchar* __restrict__ dst,
    int tid, const uint2* r)
{
    #pragma unroll
    for (int j = 0; j < 2; ++j) {
        int i = tid + j*256;
        *(uint2*)(dst + (i >> 3)*72 + (i & 7)*8) = r[j];
    }
}

__global__ __launch_bounds__(256) void conv_mfma8(
    const uchar* __restrict__ A, const uchar* __restrict__ Bt,
    const float* __restrict__ bias, uchar* __restrict__ out8,
    short* __restrict__ out16, int f8out)
{
    __shared__ uchar As[64*72];
    __shared__ uchar Bs[64*72];
    const int tid = threadIdx.x;
    const int lin = blockIdx.x + 8*blockIdx.y;      // grid (8,128)
    const int xcd = lin & 7, slot = lin >> 3;
    const int m0 = (xcd*16 + (slot & 15))*64;
    const int n0 = (slot >> 4)*64;
    const int wave = tid >> 6, lane = tid & 63;
    const int lr = lane & 15, lq = lane >> 4;

    uint2 ra[2], rb[2];
    conv_loadA8(A, m0, 0, tid, ra);
    g_load8(Bt, 1536, n0, 0, tid, rb);

    f32x4 acc[4];
    #pragma unroll
    for (int nt = 0; nt < 4; ++nt) acc[nt] = {0.f,0.f,0.f,0.f};

    for (int kt = 0; kt < 1536; kt += 64) {
        if (kt) __syncthreads();
        lds_store8(As, tid, ra);
        lds_store8(Bs, tid, rb);
        __syncthreads();
        if (kt + 64 < 1536) {
            conv_loadA8(A, m0, kt+64, tid, ra);
            g_load8(Bt, 1536, n0, kt+64, tid, rb);
        }
        #pragma unroll
        for (int ks = 0; ks < 2; ++ks) {
            int ko = ks*32 + lq*8;
            long a = *(const long*)(As + (wave*16 + lr)*72 + ko);
            #pragma unroll
            for (int nt = 0; nt < 4; ++nt) {
                long b = *(const long*)(Bs + (nt*16 + lr)*72 + ko);
                acc[nt] = MFMAF8(a, b, acc[nt]);
            }
        }
    }
    #pragma unroll
    for (int nt = 0; nt < 4; ++nt) {
        int nn = n0 + nt*16 + lr;
        #pragma unroll
        for (int reg = 0; reg < 4; ++reg) {
            int m = m0 + wave*16 + lq*4 + reg;
            float v = fmaxf(acc[nt][reg]*0.0625f + bias[nn], 0.f);
            if (f8out) out8[(size_t)m*CC + nn]  = f2q(v);
            else       out16[(size_t)m*CC + nn] = f2s(v);
        }
    }
}

// ---------------------------------------------------------------------------
// K7: out = LN(relu(c2 + xres) masked) * g + b.  short2 in / float2 out.
// ---------------------------------------------------------------------------
__global__ __launch_bounds__(256) void final_kernel(
    const short* __restrict__ c2, const short* __restrict__ xres,
    const int* __restrict__ mask, const float* __restrict__ g,
    const float* __restrict__ b, float* __restrict__ out)
{
    __shared__ float red[256];
    const int tid = threadIdx.x;
    const int m = blockIdx.x;
    const int n = m >> 10, s = m & 1023;
    const int mk = mask[(size_t)n*SS*SS + (size_t)s*SS];
    const int c0 = tid*2;

    short2 ca = *(const short2*)(c2 + (size_t)m*CC + c0);
    short2 xa = *(const short2*)(xres + (size_t)m*CC + c0);
    float v0 = fmaxf(s2f(ca.x) + s2f(xa.x), 0.f);
    float v1 = fmaxf(s2f(ca.y) + s2f(xa.y), 0.f);
    if (mk == 0) { v0 = 0.f; v1 = 0.f; }

    red[tid] = v0 + v1;
    __syncthreads();
    for (int off = 128; off > 0; off >>= 1) {
        if (tid < off) red[tid] += red[tid + off];
        __syncthreads();
    }
    float mu = red[0] * (1.0f/512.0f);
    __syncthreads();
    float d0 = v0 - mu, d1 = v1 - mu;
    red[tid] = d0*d0 + d1*d1;
    __syncthreads();
    for (int off = 128; off > 0; off >>= 1) {
        if (tid < off) red[tid] += red[tid + off];
        __syncthreads();
    }
    float rstd = rsqrtf(red[0] * (1.0f/512.0f) + 1e-5f);
    float2 gg = *(const float2*)(g + c0);
    float2 bb = *(const float2*)(b + c0);
    float2 o;
    o.x = d0*rstd*gg.x + bb.x;
    o.y = d1*rstd*gg.y + bb.y;
    *(float2*)(out + (size_t)m*CC + c0) = o;
}

// ---------------------------------------------------------------------------
extern "C" void kernel_launch(void* const* d_in, const int* in_sizes, int n_in,
                              void* d_out, int out_size, void* d_ws, size_t ws_size,
                              hipStream_t stream)
{
    const float* x      = (const float*)d_in[0];
    const int*   mask   = (const int*)  d_in[1];
    const float* Wq     = (const float*)d_in[2];
    const float* Wk     = (const float*)d_in[3];
    const float* Wv     = (const float*)d_in[4];
    const float* pk     = (const float*)d_in[5];
    const float* pv     = (const float*)d_in[6];
    const float* th_pre = (const float*)d_in[7];
    const float* th_post= (const float*)d_in[8];
    const float* fc_w   = (const float*)d_in[9];
    const float* fc_b   = (const float*)d_in[10];
    const float* c1w    = (const float*)d_in[11];
    const float* c1b    = (const float*)d_in[12];
    const float* c2w    = (const float*)d_in[13];
    const float* c2b    = (const float*)d_in[14];
    const float* lng    = (const float*)d_in[15];
    const float* lnb    = (const float*)d_in[16];
    float* out = (float*)d_out;
    (void)in_sizes; (void)n_in; (void)out_size; (void)ws_size;

    char* ws = (char*)d_ws;
    const size_t SZ_Q  = (size_t)BN*HH*SS*DD;      //  4.19 MB (fp8)
    const size_t SZ_K  = (size_t)BN*HH*KT*DD;      //  4.26 MB (fp8)
    const size_t SZ_VT = (size_t)BN*HH*DD*KT;      //  4.26 MB (fp8)
    const size_t SZ_E  = (size_t)BN*SS*HH*KT;      // 68.2 MB (fp8)
    const size_t SZ_A  = (size_t)BN*SS*CC*2;       //  8.39 MB (bf16)
    const size_t SZ_A8 = (size_t)BN*SS*CC;         //  4.19 MB (fp8)

    uchar* qf  = (uchar*)(ws);
    uchar* kf  = (uchar*)(ws + SZ_Q);
    uchar* vt  = (uchar*)(ws + SZ_Q + SZ_K);
    uchar* E   = (uchar*)(ws + SZ_Q + SZ_K + SZ_VT);
    short* AO  = (short*)(ws + SZ_Q + SZ_K + SZ_VT + SZ_E);
    char*  wend = ws + SZ_Q + SZ_K + SZ_VT + SZ_E + SZ_A;
    short* Bfc = (short*)(wend);
    uchar* Bc1 = (uchar*)(wend + 512*512*2);
    uchar* Bc2 = (uchar*)(wend + 512*512*2 + 512*1536);
    short* Bqkv= (short*)(wend + 512*512*2 + 2*512*1536);
    uchar* xres8 = (uchar*)(wend + 512*512*2 + 2*512*1536 + 3*64*64*2);
    short* c2buf = (short*)(wend + 512*512*2 + 2*512*1536 + 3*64*64*2 + SZ_A8);
    // Aliases (dead regions): xres(bf16) over qf+kf (dead after energy);
    // h1(fp8) over E (dead after pv).
    short* xres = (short*)(ws);
    uchar* h18  = (uchar*)E;
    // total ws ~= 103 MB (ws_size >= 256 MiB)

    {
        int total = 512*512 + 2*512*1536 + 3*64*64;
        prep_kernel<<<(total + 255)/256, 256, 0, stream>>>(
            fc_w, c1w, c2w, Wq, Wk, Wv, th_post, Bfc, Bc1, Bc2, Bqkv);
    }
    qkv_mfma<<<dim3(BN*SS/64, HH), 256, 0, stream>>>(x, Bqkv, qf, kf, vt);
    persist_kernel<<<(BN*HH*PP*DD + 255)/256, 256, 0, stream>>>(pk, pv, kf, vt);

    energy_mfma8<<<dim3(SS/64, BN*HH), 256, 0, stream>>>(qf, kf, E);
    softmax_kernel<<<BN*SS, 256, 0, stream>>>(E, mask, th_pre);
    pv_mfma<<<dim3(SS/32, BN*HH), 256, 0, stream>>>(E, vt, AO);

    fc_mfma<<<dim3(8, 128), 256, 0, stream>>>(AO, Bfc, fc_b, x, xres, xres8);
    conv_mfma8<<<dim3(8, 128), 256, 0, stream>>>(xres8, Bc1, c1b, h18, (short*)nullptr, 1);
    conv_mfma8<<<dim3(8, 128), 256, 0, stream>>>(h18, Bc2, c2b, (uchar*)nullptr, c2buf, 0);
    final_kernel<<<BN*SS, 256, 0, stream>>>(c2buf, xres, mask, lng, lnb, out);
}

// Round 18
// 298.149 us; speedup vs baseline: 1.6838x; 1.0016x over previous
//
#include <hip/hip_runtime.h>
#include <hip/hip_bf16.h>

#define BN 8
#define SS 1024
#define CC 512
#define HH 8
#define DD 64
#define PP 16
#define KT 1040

typedef __hip_bfloat16 bf16;
typedef unsigned char uchar;
typedef unsigned short ushort;
typedef unsigned int uint;
typedef __attribute__((ext_vector_type(8))) short short8;
typedef __attribute__((ext_vector_type(4))) float f32x4;
typedef __attribute__((ext_vector_type(2))) float f32x2;

__device__ __forceinline__ short f2s(float v){ bf16 b = __float2bfloat16(v); return *(short*)&b; }
__device__ __forceinline__ float s2f(short s){ bf16 b; *(short*)&b = s; return __bfloat162float(b); }
__device__ __forceinline__ uchar f2q(float v){          // f32 -> fp8 e4m3 byte
    return (uchar)__builtin_amdgcn_cvt_pk_fp8_f32(v, v, 0, false);
}

#define MFMA16(a,b,c)  __builtin_amdgcn_mfma_f32_16x16x32_bf16(a,b,c,0,0,0)
#define MFMAF8(a,b,c)  __builtin_amdgcn_mfma_f32_16x16x32_fp8_fp8(a,b,c,0,0,0)

// ---------------------------------------------------------------------------
// P0: weight pre-conversion. fc -> bf16 with th_post FOLDED IN:
//   Bfc[c, g*64+d] = sum_h fc_w[c, h*64+d] * th_post[h,g]
// conv weights -> fp8 scaled x16; qkv -> bf16.
// ---------------------------------------------------------------------------
__global__ __launch_bounds__(256) void prep_kernel(
    const float* __restrict__ fc_w, const float* __restrict__ c1w,
    const float* __restrict__ c2w, const float* __restrict__ Wq,
    const float* __restrict__ Wk, const float* __restrict__ Wv,
    const float* __restrict__ th_post,
    short* __restrict__ Bfc, uchar* __restrict__ Bc1,
    uchar* __restrict__ Bc2, short* __restrict__ Bqkv)
{
    int i = blockIdx.x*256 + threadIdx.x;
    const int NFC = 512*512, NCV = 512*1536, NQ = 3*64*64;
    if (i < NFC) {
        int c = i >> 9, r = i & 511;
        int g = r >> 6, d = r & 63;
        float s = 0.f;
        #pragma unroll
        for (int h = 0; h < 8; ++h)
            s += fc_w[(size_t)c*512 + h*64 + d] * th_post[h*8 + g];
        Bfc[i] = f2s(s);
        return;
    }
    i -= NFC;
    if (i < NCV) {
        int o = i/1536, r = i%1536, dk = r>>9, ci = r&511;
        Bc1[i] = f2q(c1w[(o*512+ci)*3+dk] * 16.f); return;
    }
    i -= NCV;
    if (i < NCV) {
        int o = i/1536, r = i%1536, dk = r>>9, ci = r&511;
        Bc2[i] = f2q(c2w[(o*512+ci)*3+dk] * 16.f); return;
    }
    i -= NCV;
    if (i < NQ) {
        int w = i >> 12, rest = i & 4095;
        const float* W = (w==0)?Wq:(w==1)?Wk:Wv;
        Bqkv[i] = f2s(W[((rest>>6)&63)*64 + (rest&63)]);
    }
}

// ---------------------------------------------------------------------------
// K1: QKV projection, bf16 MFMA. q/k out fp8 [s][d]; V written DIRECTLY into
// transposed fp8 vt[nh][d][k=s].
// ---------------------------------------------------------------------------
__global__ __launch_bounds__(256) void qkv_mfma(
    const float* __restrict__ x, const short* __restrict__ Bqkv,
    uchar* __restrict__ qf, uchar* __restrict__ kf, uchar* __restrict__ vt)
{
    __shared__ short Xs[64*72];
    __shared__ short Ws[192*72];
    const int tid = threadIdx.x;
    const int m0 = blockIdx.x * 64;
    const int h = blockIdx.y;
    const int wave = tid >> 6, lane = tid & 63;
    const int lr = lane & 15, lq = lane >> 4;

    for (int i = tid; i < 1024; i += 256) {
        int r = i >> 4, cg = (i & 15)*4;
        float4 v = *(const float4*)(x + (size_t)(m0+r)*CC + h*64 + cg);
        Xs[r*72+cg+0] = f2s(v.x); Xs[r*72+cg+1] = f2s(v.y);
        Xs[r*72+cg+2] = f2s(v.z); Xs[r*72+cg+3] = f2s(v.w);
    }
    for (int i = tid; i < 3072; i += 256) {
        int r = i >> 4, cg = (i & 15)*4;
        *(short4*)(Ws + r*72 + cg) = *(const short4*)(Bqkv + (size_t)r*64 + cg);
    }
    __syncthreads();

    f32x4 acc[12];
    #pragma unroll
    for (int nt = 0; nt < 12; ++nt) acc[nt] = {0.f,0.f,0.f,0.f};
    #pragma unroll
    for (int ks = 0; ks < 2; ++ks) {
        int ko = ks*32 + lq*8;
        short8 a = *(const short8*)(Xs + (wave*16 + lr)*72 + ko);
        #pragma unroll
        for (int nt = 0; nt < 12; ++nt) {
            short8 b = *(const short8*)(Ws + (nt*16 + lr)*72 + ko);
            acc[nt] = MFMA16(a, b, acc[nt]);
        }
    }
    #pragma unroll
    for (int nt = 0; nt < 12; ++nt) {
        int ep = nt*16 + lr;
        int w = ep >> 6, e = ep & 63;
        #pragma unroll
        for (int reg = 0; reg < 4; ++reg) {
            int m = m0 + wave*16 + lq*4 + reg;
            int n = m >> 10, s = m & 1023;
            float v = acc[nt][reg];
            if (w == 0)      qf[((size_t)(n*HH+h)*SS + s)*DD + e] = f2q(v);
            else if (w == 1) kf[((size_t)(n*HH+h)*KT + s)*DD + e] = f2q(v);
            else             vt[(((size_t)(n*HH+h))*DD + e)*KT + s] = f2q(v);
        }
    }
}

// ---------------------------------------------------------------------------
// K1b: persistent tokens -> kf tail (fp8 [k][d]) and vt tail (fp8 [d][k]).
// ---------------------------------------------------------------------------
__global__ __launch_bounds__(256) void persist_kernel(
    const float* __restrict__ pk, const float* __restrict__ pv,
    uchar* __restrict__ kf, uchar* __restrict__ vt)
{
    int idx = blockIdx.x*256 + threadIdx.x;
    if (idx >= BN*HH*PP*DD) return;
    int d = idx & 63, p = (idx >> 6) & 15, h = (idx >> 10) & 7, n = idx >> 13;
    size_t src = ((size_t)p*HH + h)*DD + d;
    kf[(((size_t)(n*HH+h))*KT + SS + p)*DD + d] = f2q(pk[src]);
    vt[(((size_t)(n*HH+h))*DD + d)*KT + SS + p] = f2q(pv[src]);
}

// ---------------------------------------------------------------------------
// K2 v2: energy, fp8 MFMA NT. Block = (mt, nh), grid 1024. Q staged ONCE;
// loop over 17 k-tiles with register-prefetch dbuf.
// ---------------------------------------------------------------------------
__device__ __forceinline__ void en_loadK(const uchar* __restrict__ kf,
    int nh, int kt, int tid, uint2* rk)
{
    #pragma unroll
    for (int j = 0; j < 2; ++j) {
        int i = tid + j*256;
        int r = i >> 3, c8 = (i & 7)*8;
        int kcol = kt*64 + r;
        uint2 v = {0u, 0u};
        if (kcol < KT)
            v = *(const uint2*)(kf + ((size_t)nh*KT + kcol)*DD + c8);
        rk[j] = v;
    }
}

__global__ __launch_bounds__(256) void energy_mfma8(
    const uchar* __restrict__ qf, const uchar* __restrict__ kf,
    uchar* __restrict__ E)
{
    __shared__ uchar Qs[64*72];
    __shared__ uchar Ks[64*72];
    const int tid = threadIdx.x;
    const int mt = blockIdx.x;
    const int nh = blockIdx.y;
    const int wave = tid >> 6, lane = tid & 63;
    const int lr = lane & 15, lq = lane >> 4;
    const int n = nh >> 3, h = nh & 7;

    #pragma unroll
    for (int j = 0; j < 2; ++j) {
        int i = tid + j*256;
        int r = i >> 3, c8 = (i & 7)*8;
        *(uint2*)(Qs + r*72 + c8) =
            *(const uint2*)(qf + ((size_t)nh*SS + mt*64 + r)*DD + c8);
    }

    uint2 rk[2];
    en_loadK(kf, nh, 0, tid, rk);

    for (int kt = 0; kt < 17; ++kt) {
        if (kt) __syncthreads();
        #pragma unroll
        for (int j = 0; j < 2; ++j) {
            int i = tid + j*256;
            *(uint2*)(Ks + (i >> 3)*72 + (i & 7)*8) = rk[j];
        }
        __syncthreads();
        if (kt + 1 < 17) en_loadK(kf, nh, kt+1, tid, rk);

        f32x4 acc[4];
        #pragma unroll
        for (int nt = 0; nt < 4; ++nt) acc[nt] = {0.f,0.f,0.f,0.f};
        #pragma unroll
        for (int ks = 0; ks < 2; ++ks) {
            int ko = ks*32 + lq*8;
            long a = *(const long*)(Qs + (wave*16 + lr)*72 + ko);
            #pragma unroll
            for (int nt = 0; nt < 4; ++nt) {
                long b = *(const long*)(Ks + (nt*16 + lr)*72 + ko);
                acc[nt] = MFMAF8(a, b, acc[nt]);
            }
        }
        #pragma unroll
        for (int nt = 0; nt < 4; ++nt) {
            int kcol = kt*64 + nt*16 + lr;
            if (kcol >= KT) continue;
            #pragma unroll
            for (int reg = 0; reg < 4; ++reg) {
                int q = mt*64 + wave*16 + lq*4 + reg;
                E[(((size_t)(n*SS + q))*HH + h)*KT + kcol] = f2q(acc[nt][reg]);
            }
        }
    }
}

// ---------------------------------------------------------------------------
// K3: softmax (r15 version — 52 VGPR sweet spot): no-max, fp8 in/out,
// premix in-kernel, postmix folded into fc. 4 adjacent cols per thread.
// ---------------------------------------------------------------------------
__global__ __launch_bounds__(256) void softmax_kernel(
    uchar* __restrict__ E, const int* __restrict__ mask,
    const float* __restrict__ th_pre)
{
    __shared__ float thp[64];
    __shared__ float wred[4][8];
    const int tid = threadIdx.x;
    const int wave = tid >> 6, lane = tid & 63;
    const int blk = blockIdx.x;              // n*SS + q
    const int n = blk >> 10, q = blk & 1023;
    const float invs = 0.044194173824159216f;   // 1/sqrt(512)
    const float l2e  = 1.4426950408889634f;
    if (tid < 64) thp[tid] = th_pre[tid]*(invs*l2e);
    __syncthreads();
    uchar* Eb = E + (size_t)blk*HH*KT;

    const float sl[8] = {0.5f,0.25f,0.125f,0.0625f,
                         0.03125f,0.015625f,0.0078125f,0.00390625f};
    const int* mrow = mask + (size_t)n*SS*SS + (size_t)q*SS;

    const int k0 = tid*4;                    // 4 adjacent columns
    const int4 mk = *(const int4*)(mrow + k0);
    f32x4 dist;
    dist.x = fabsf((float)(q - k0));
    dist.y = fabsf((float)(q - k0 - 1));
    dist.z = fabsf((float)(q - k0 - 2));
    dist.w = fabsf((float)(q - k0 - 3));

    f32x4 tp[8];
    float tl[8];
    float sm[8];
    #pragma unroll
    for (int g = 0; g < 8; ++g) { sm[g] = 0.f; tl[g] = 0.f; }

    {
        f32x4 a[8];
        #pragma unroll
        for (int g = 0; g < 8; ++g) {
            uint u = *(const uint*)(Eb + g*KT + k0);
            f32x2 lo = __builtin_amdgcn_cvt_pk_f32_fp8((int)u, false);
            f32x2 hi = __builtin_amdgcn_cvt_pk_f32_fp8((int)u, true);
            f32x4 r; r.x = lo.x; r.y = lo.y; r.z = hi.x; r.w = hi.y;
            a[g] = r - dist*sl[g];
        }
        #pragma unroll
        for (int h = 0; h < 8; ++h) {
            f32x4 t = {0.f,0.f,0.f,0.f};
            #pragma unroll
            for (int g = 0; g < 8; ++g)
                t += a[g] * thp[h*8 + g];    // packed-f32 FMA candidates
            f32x4 e;
            e.x = (mk.x == 0) ? 0.f : exp2f(t.x);
            e.y = (mk.y == 0) ? 0.f : exp2f(t.y);
            e.z = (mk.z == 0) ? 0.f : exp2f(t.z);
            e.w = (mk.w == 0) ? 0.f : exp2f(t.w);
            tp[h] = e;
            sm[h] += e.x + e.y + e.z + e.w;
        }
    }
    if (tid < 16) {                          // persistent keys
        const int k = 1024 + tid;
        float a[8];
        #pragma unroll
        for (int g = 0; g < 8; ++g) {
            f32x2 r = __builtin_amdgcn_cvt_pk_f32_fp8((int)Eb[g*KT + k], false);
            a[g] = r.x;
        }
        #pragma unroll
        for (int h = 0; h < 8; ++h) {
            float t = 0.f;
            #pragma unroll
            for (int g = 0; g < 8; ++g) t = fmaf(thp[h*8 + g], a[g], t);
            float e = exp2f(t);
            tl[h] = e;
            sm[h] += e;
        }
    }
    #pragma unroll
    for (int g = 0; g < 8; ++g) {
        #pragma unroll
        for (int off = 32; off > 0; off >>= 1)
            sm[g] += __shfl_xor(sm[g], off);
    }
    if (lane == 0) {
        #pragma unroll
        for (int g = 0; g < 8; ++g) wred[wave][g] = sm[g];
    }
    __syncthreads();
    float lred[8];
    #pragma unroll
    for (int g = 0; g < 8; ++g)
        lred[g] = 1.0f / (wred[0][g] + wred[1][g] + wred[2][g] + wred[3][g]);

    // normalized probs out: one uint store per head
    #pragma unroll
    for (int h = 0; h < 8; ++h) {
        f32x4 e = tp[h] * lred[h];
        int p = __builtin_amdgcn_cvt_pk_fp8_f32(e.x, e.y, 0, false);
        p = __builtin_amdgcn_cvt_pk_fp8_f32(e.z, e.w, p, true);
        *(uint*)(Eb + h*KT + k0) = (uint)p;
    }
    if (tid < 16) {
        const int k = 1024 + tid;
        #pragma unroll
        for (int g = 0; g < 8; ++g)
            Eb[g*KT + k] = f2q(tl[g] * lred[g]);
    }
}

// ---------------------------------------------------------------------------
// K4 v2: PV fp8 MFMA, q-tile 64 (grid 1024), 4 waves own 32x32 quadrants
// -> 16 MFMA/block/iter (2x better barrier amortization).
// ---------------------------------------------------------------------------
__device__ __forceinline__ void pv_loadP(const uchar* __restrict__ E,
    int n, int h, int ql0, int kt, int tid, uint2* rp)
{
    #pragma unroll
    for (int j = 0; j < 2; ++j) {
        int i = tid + j*256;
        int r = i >> 3, cg = (i & 7)*8;
        int k = kt*64 + cg;
        uint2 v = {0u, 0u};
        if (k < KT)
            v = *(const uint2*)(E + (((size_t)(n*SS + ql0 + r))*HH + h)*KT + k);
        rp[j] = v;
    }
}
__device__ __forceinline__ void pv_loadV(const uchar* __restrict__ vt,
    int nh, int kt, int tid, uint2* rv)
{
    #pragma unroll
    for (int j = 0; j < 2; ++j) {
        int i = tid + j*256;
        int r = i >> 3, cg = (i & 7)*8;
        int k = kt*64 + cg;
        uint2 v = {0u, 0u};
        if (k < KT)
            v = *(const uint2*)(vt + ((size_t)nh*DD + r)*KT + k);
        rv[j] = v;
    }
}

__global__ __launch_bounds__(256) void pv_mfma(
    const uchar* __restrict__ E, const uchar* __restrict__ vt,
    short* __restrict__ AO)
{
    __shared__ uchar Ps[64*72];
    __shared__ uchar Vs[64*72];
    const int tid = threadIdx.x;
    const int ql0 = blockIdx.x * 64;
    const int nh = blockIdx.y;
    const int n = nh >> 3, h = nh & 7;
    const int wave = tid >> 6, lane = tid & 63;
    const int lr = lane & 15, lq = lane >> 4;
    const int mq = (wave & 1)*32, nq = (wave >> 1)*32;

    uint2 rp[2], rv[2];
    pv_loadP(E, n, h, ql0, 0, tid, rp);
    pv_loadV(vt, nh, 0, tid, rv);

    f32x4 acc[2][2];
    #pragma unroll
    for (int i = 0; i < 2; ++i)
        #pragma unroll
        for (int j = 0; j < 2; ++j) acc[i][j] = {0.f,0.f,0.f,0.f};

    for (int kt = 0; kt < 17; ++kt) {
        if (kt) __syncthreads();
        #pragma unroll
        for (int j = 0; j < 2; ++j) {
            int i = tid + j*256;
            *(uint2*)(Ps + (i >> 3)*72 + (i & 7)*8) = rp[j];
        }
        #pragma unroll
        for (int j = 0; j < 2; ++j) {
            int i = tid + j*256;
            *(uint2*)(Vs + (i >> 3)*72 + (i & 7)*8) = rv[j];
        }
        __syncthreads();
        if (kt + 1 < 17) {
            pv_loadP(E, n, h, ql0, kt+1, tid, rp);
            pv_loadV(vt, nh, kt+1, tid, rv);
        }
        #pragma unroll
        for (int ks = 0; ks < 2; ++ks) {
            int ko = ks*32 + lq*8;
            long a0 = *(const long*)(Ps + (mq + lr)*72 + ko);
            long a1 = *(const long*)(Ps + (mq + 16 + lr)*72 + ko);
            long b0 = *(const long*)(Vs + (nq + lr)*72 + ko);
            long b1 = *(const long*)(Vs + (nq + 16 + lr)*72 + ko);
            acc[0][0] = MFMAF8(a0, b0, acc[0][0]);
            acc[0][1] = MFMAF8(a0, b1, acc[0][1]);
            acc[1][0] = MFMAF8(a1, b0, acc[1][0]);
            acc[1][1] = MFMAF8(a1, b1, acc[1][1]);
        }
    }
    #pragma unroll
    for (int mt = 0; mt < 2; ++mt)
        #pragma unroll
        for (int nt = 0; nt < 2; ++nt) {
            int d = nq + nt*16 + lr;
            #pragma unroll
            for (int reg = 0; reg < 4; ++reg) {
                int qg = ql0 + mq + mt*16 + lq*4 + reg;
                AO[((size_t)(n*SS) + qg)*CC + h*64 + d] = f2s(acc[mt][nt][reg]);
            }
        }
}

// ---------------------------------------------------------------------------
// K5: fc (th_post folded into weights), bf16 MFMA, 64x64, XCD-swizzled.
// Writes xres (bf16) AND xres8 (fp8 copy for conv1's A operand).
// ---------------------------------------------------------------------------
__device__ __forceinline__ void g_load4(const short* __restrict__ src,
    size_t rowstride, int row0, int col0, int tid, short4* r)
{
    #pragma unroll
    for (int j = 0; j < 4; ++j) {
        int i = tid + j*256;
        int rr = i >> 4, cg = (i & 15)*4;
        r[j] = *(const short4*)(src + (size_t)(row0 + rr)*rowstride + col0 + cg);
    }
}
__device__ __forceinline__ void lds_store4(short* __restrict__ dst,
    int tid, const short4* r)
{
    #pragma unroll
    for (int j = 0; j < 4; ++j) {
        int i = tid + j*256;
        *(short4*)(dst + (i >> 4)*72 + (i & 15)*4) = r[j];
    }
}

__global__ __launch_bounds__(256) void fc_mfma(
    const short* __restrict__ A, const short* __restrict__ Bt,
    const float* __restrict__ bias, const float* __restrict__ x,
    short* __restrict__ out, uchar* __restrict__ out8)
{
    __shared__ short As[64*72];
    __shared__ short Bs[64*72];
    const int tid = threadIdx.x;
    const int lin = blockIdx.x + 8*blockIdx.y;      // grid (8,128)
    const int xcd = lin & 7, slot = lin >> 3;
    const int m0 = (xcd*16 + (slot & 15))*64;
    const int n0 = (slot >> 4)*64;
    const int wave = tid >> 6, lane = tid & 63;
    const int lr = lane & 15, lq = lane >> 4;

    short4 ra[4], rb[4];
    g_load4(A, CC, m0, 0, tid, ra);
    g_load4(Bt, CC, n0, 0, tid, rb);

    f32x4 acc[4];
    #pragma unroll
    for (int nt = 0; nt < 4; ++nt) acc[nt] = {0.f,0.f,0.f,0.f};

    for (int kt = 0; kt < CC; kt += 64) {
        if (kt) __syncthreads();
        lds_store4(As, tid, ra);
        lds_store4(Bs, tid, rb);
        __syncthreads();
        if (kt + 64 < CC) {
            g_load4(A, CC, m0, kt+64, tid, ra);
            g_load4(Bt, CC, n0, kt+64, tid, rb);
        }
        #pragma unroll
        for (int ks = 0; ks < 2; ++ks) {
            int ko = ks*32 + lq*8;
            short8 a = *(const short8*)(As + (wave*16 + lr)*72 + ko);
            #pragma unroll
            for (int nt = 0; nt < 4; ++nt) {
                short8 b = *(const short8*)(Bs + (nt*16 + lr)*72 + ko);
                acc[nt] = MFMA16(a, b, acc[nt]);
            }
        }
    }
    #pragma unroll
    for (int nt = 0; nt < 4; ++nt) {
        int nn = n0 + nt*16 + lr;
        #pragma unroll
        for (int reg = 0; reg < 4; ++reg) {
            int m = m0 + wave*16 + lq*4 + reg;
            float v = acc[nt][reg] + bias[nn] + x[(size_t)m*CC + nn];
            out[(size_t)m*CC + nn]  = f2s(v);
            out8[(size_t)m*CC + nn] = f2q(v);
        }
    }
}

// ---------------------------------------------------------------------------
// K6 v2: causal conv fp8 NT GEMM, BK=128 (12 K-iters, 16 MFMA/wave/iter).
// 128-chunks never straddle the 512 boundary -> dk constant per chunk.
// Row stride 136B = 34 banks -> 2-way aliasing (free).
// ---------------------------------------------------------------------------
__device__ __forceinline__ void conv_loadA8w(const uchar* __restrict__ A,
    int m0, int kt, int tid, uint2* ra)
{
    const int shift = (kt >> 9) - 2;
    const int ci0 = kt & 511;
    #pragma unroll
    for (int j = 0; j < 4; ++j) {
        int i = tid + j*256;
        int rr = i >> 4, c8 = (i & 15)*8;
        int m = m0 + rr;
        int s = m & (SS-1);
        uint2 v = {0u, 0u};
        if (s + shift >= 0)
            v = *(const uint2*)(A + (size_t)(m + shift)*CC + ci0 + c8);
        ra[j] = v;
    }
}
__device__ __forceinline__ void g_load8w(const uchar* __restrict__ src,
    size_t rowstride, int row0, int col0, int tid, uint2* r)
{
    #pragma unroll
    for (int j = 0; j < 4; ++j) {
        int i = tid + j*256;
        int rr = i >> 4, c8 = (i & 15)*8;
        r[j] = *(const uint2*)(src + (size_t)(row0 + rr)*rowstride + col0 + c8);
    }
}
__device__ __forceinline__ void lds_store8w(uchar* __restrict__ dst,
    int tid, const uint2* r)
{
    #pragma unroll
    for (int j = 0; j < 4; ++j) {
        int i = tid + j*256;
        *(uint2*)(dst + (i >> 4)*136 + (i & 15)*8) = r[j];
    }
}

__global__ __launch_bounds__(256) void conv_mfma8(
    const uchar* __restrict__ A, const uchar* __restrict__ Bt,
    const float* __restrict__ bias, uchar* __restrict__ out8,
    short* __restrict__ out16, int f8out)
{
    __shared__ uchar As[64*136];
    __shared__ uchar Bs[64*136];
    const int tid = threadIdx.x;
    const int lin = blockIdx.x + 8*blockIdx.y;      // grid (8,128)
    const int xcd = lin & 7, slot = lin >> 3;
    const int m0 = (xcd*16 + (slot & 15))*64;
    const int n0 = (slot >> 4)*64;
    const int wave = tid >> 6, lane = tid & 63;
    const int lr = lane & 15, lq = lane >> 4;

    uint2 ra[4], rb[4];
    conv_loadA8w(A, m0, 0, tid, ra);
    g_load8w(Bt, 1536, n0, 0, tid, rb);

    f32x4 acc[4];
    #pragma unroll
    for (int nt = 0; nt < 4; ++nt) acc[nt] = {0.f,0.f,0.f,0.f};

    for (int kt = 0; kt < 1536; kt += 128) {
        if (kt) __syncthreads();
        lds_store8w(As, tid, ra);
        lds_store8w(Bs, tid, rb);
        __syncthreads();
        if (kt + 128 < 1536) {
            conv_loadA8w(A, m0, kt+128, tid, ra);
            g_load8w(Bt, 1536, n0, kt+128, tid, rb);
        }
        #pragma unroll
        for (int ks = 0; ks < 4; ++ks) {
            int ko = ks*32 + lq*8;
            long a = *(const long*)(As + (wave*16 + lr)*136 + ko);
            #pragma unroll
            for (int nt = 0; nt < 4; ++nt) {
                long b = *(const long*)(Bs + (nt*16 + lr)*136 + ko);
                acc[nt] = MFMAF8(a, b, acc[nt]);
            }
        }
    }
    #pragma unroll
    for (int nt = 0; nt < 4; ++nt) {
        int nn = n0 + nt*16 + lr;
        #pragma unroll
        for (int reg = 0; reg < 4; ++reg) {
            int m = m0 + wave*16 + lq*4 + reg;
            float v = fmaxf(acc[nt][reg]*0.0625f + bias[nn], 0.f);
            if (f8out) out8[(size_t)m*CC + nn]  = f2q(v);
            else       out16[(size_t)m*CC + nn] = f2s(v);
        }
    }
}

// ---------------------------------------------------------------------------
// K7: out = LN(relu(c2 + xres) masked) * g + b.  short2 in / float2 out.
// ---------------------------------------------------------------------------
__global__ __launch_bounds__(256) void final_kernel(
    const short* __restrict__ c2, const short* __restrict__ xres,
    const int* __restrict__ mask, const float* __restrict__ g,
    const float* __restrict__ b, float* __restrict__ out)
{
    __shared__ float red[256];
    const int tid = threadIdx.x;
    const int m = blockIdx.x;
    const int n = m >> 10, s = m & 1023;
    const int mk = mask[(size_t)n*SS*SS + (size_t)s*SS];
    const int c0 = tid*2;

    short2 ca = *(const short2*)(c2 + (size_t)m*CC + c0);
    short2 xa = *(const short2*)(xres + (size_t)m*CC + c0);
    float v0 = fmaxf(s2f(ca.x) + s2f(xa.x), 0.f);
    float v1 = fmaxf(s2f(ca.y) + s2f(xa.y), 0.f);
    if (mk == 0) { v0 = 0.f; v1 = 0.f; }

    red[tid] = v0 + v1;
    __syncthreads();
    for (int off = 128; off > 0; off >>= 1) {
        if (tid < off) red[tid] += red[tid + off];
        __syncthreads();
    }
    float mu = red[0] * (1.0f/512.0f);
    __syncthreads();
    float d0 = v0 - mu, d1 = v1 - mu;
    red[tid] = d0*d0 + d1*d1;
    __syncthreads();
    for (int off = 128; off > 0; off >>= 1) {
        if (tid < off) red[tid] += red[tid + off];
        __syncthreads();
    }
    float rstd = rsqrtf(red[0] * (1.0f/512.0f) + 1e-5f);
    float2 gg = *(const float2*)(g + c0);
    float2 bb = *(const float2*)(b + c0);
    float2 o;
    o.x = d0*rstd*gg.x + bb.x;
    o.y = d1*rstd*gg.y + bb.y;
    *(float2*)(out + (size_t)m*CC + c0) = o;
}

// ---------------------------------------------------------------------------
extern "C" void kernel_launch(void* const* d_in, const int* in_sizes, int n_in,
                              void* d_out, int out_size, void* d_ws, size_t ws_size,
                              hipStream_t stream)
{
    const float* x      = (const float*)d_in[0];
    const int*   mask   = (const int*)  d_in[1];
    const float* Wq     = (const float*)d_in[2];
    const float* Wk     = (const float*)d_in[3];
    const float* Wv     = (const float*)d_in[4];
    const float* pk     = (const float*)d_in[5];
    const float* pv     = (const float*)d_in[6];
    const float* th_pre = (const float*)d_in[7];
    const float* th_post= (const float*)d_in[8];
    const float* fc_w   = (const float*)d_in[9];
    const float* fc_b   = (const float*)d_in[10];
    const float* c1w    = (const float*)d_in[11];
    const float* c1b    = (const float*)d_in[12];
    const float* c2w    = (const float*)d_in[13];
    const float* c2b    = (const float*)d_in[14];
    const float* lng    = (const float*)d_in[15];
    const float* lnb    = (const float*)d_in[16];
    float* out = (float*)d_out;
    (void)in_sizes; (void)n_in; (void)out_size; (void)ws_size;

    char* ws = (char*)d_ws;
    const size_t SZ_Q  = (size_t)BN*HH*SS*DD;      //  4.19 MB (fp8)
    const size_t SZ_K  = (size_t)BN*HH*KT*DD;      //  4.26 MB (fp8)
    const size_t SZ_VT = (size_t)BN*HH*DD*KT;      //  4.26 MB (fp8)
    const size_t SZ_E  = (size_t)BN*SS*HH*KT;      // 68.2 MB (fp8)
    const size_t SZ_A  = (size_t)BN*SS*CC*2;       //  8.39 MB (bf16)
    const size_t SZ_A8 = (size_t)BN*SS*CC;         //  4.19 MB (fp8)

    uchar* qf  = (uchar*)(ws);
    uchar* kf  = (uchar*)(ws + SZ_Q);
    uchar* vt  = (uchar*)(ws + SZ_Q + SZ_K);
    uchar* E   = (uchar*)(ws + SZ_Q + SZ_K + SZ_VT);
    short* AO  = (short*)(ws + SZ_Q + SZ_K + SZ_VT + SZ_E);
    char*  wend = ws + SZ_Q + SZ_K + SZ_VT + SZ_E + SZ_A;
    short* Bfc = (short*)(wend);
    uchar* Bc1 = (uchar*)(wend + 512*512*2);
    uchar* Bc2 = (uchar*)(wend + 512*512*2 + 512*1536);
    short* Bqkv= (short*)(wend + 512*512*2 + 2*512*1536);
    uchar* xres8 = (uchar*)(wend + 512*512*2 + 2*512*1536 + 3*64*64*2);
    short* c2buf = (short*)(wend + 512*512*2 + 2*512*1536 + 3*64*64*2 + SZ_A8);
    // Aliases (dead regions): xres(bf16) over qf+kf (dead after energy);
    // h1(fp8) over E (dead after pv).
    short* xres = (short*)(ws);
    uchar* h18  = (uchar*)E;
    // total ws ~= 103 MB (ws_size >= 256 MiB)

    {
        int total = 512*512 + 2*512*1536 + 3*64*64;
        prep_kernel<<<(total + 255)/256, 256, 0, stream>>>(
            fc_w, c1w, c2w, Wq, Wk, Wv, th_post, Bfc, Bc1, Bc2, Bqkv);
    }
    qkv_mfma<<<dim3(BN*SS/64, HH), 256, 0, stream>>>(x, Bqkv, qf, kf, vt);
    persist_kernel<<<(BN*HH*PP*DD + 255)/256, 256, 0, stream>>>(pk, pv, kf, vt);

    energy_mfma8<<<dim3(SS/64, BN*HH), 256, 0, stream>>>(qf, kf, E);
    softmax_kernel<<<BN*SS, 256, 0, stream>>>(E, mask, th_pre);
    pv_mfma<<<dim3(SS/64, BN*HH), 256, 0, stream>>>(E, vt, AO);

    fc_mfma<<<dim3(8, 128), 256, 0, stream>>>(AO, Bfc, fc_b, x, xres, xres8);
    conv_mfma8<<<dim3(8, 128), 256, 0, stream>>>(xres8, Bc1, c1b, h18, (short*)nullptr, 1);
    conv_mfma8<<<dim3(8, 128), 256, 0, stream>>>(h18, Bc2, c2b, (uchar*)nullptr, c2buf, 0);
    final_kernel<<<BN*SS, 256, 0, stream>>>(c2buf, xres, mask, lng, lnb, out);
}

// Round 19
// 293.126 us; speedup vs baseline: 1.7126x; 1.0171x over previous
//
#include <hip/hip_runtime.h>
#include <hip/hip_bf16.h>

#define BN 8
#define SS 1024
#define CC 512
#define HH 8
#define DD 64
#define PP 16
#define KT 1040

typedef __hip_bfloat16 bf16;
typedef unsigned char uchar;
typedef unsigned short ushort;
typedef unsigned int uint;
typedef __attribute__((ext_vector_type(8))) short short8;
typedef __attribute__((ext_vector_type(4))) float f32x4;
typedef __attribute__((ext_vector_type(2))) float f32x2;

__device__ __forceinline__ short f2s(float v){ bf16 b = __float2bfloat16(v); return *(short*)&b; }
__device__ __forceinline__ float s2f(short s){ bf16 b; *(short*)&b = s; return __bfloat162float(b); }
__device__ __forceinline__ uchar f2q(float v){          // f32 -> fp8 e4m3 byte
    return (uchar)__builtin_amdgcn_cvt_pk_fp8_f32(v, v, 0, false);
}

#define MFMA16(a,b,c)  __builtin_amdgcn_mfma_f32_16x16x32_bf16(a,b,c,0,0,0)
#define MFMAF8(a,b,c)  __builtin_amdgcn_mfma_f32_16x16x32_fp8_fp8(a,b,c,0,0,0)

// ---------------------------------------------------------------------------
// P0: weight pre-conversion + persistent-token tails (persist merged in).
// fc -> bf16 with th_post folded; conv weights -> fp8 x16; qkv -> bf16.
// ---------------------------------------------------------------------------
__global__ __launch_bounds__(256) void prep_kernel(
    const float* __restrict__ fc_w, const float* __restrict__ c1w,
    const float* __restrict__ c2w, const float* __restrict__ Wq,
    const float* __restrict__ Wk, const float* __restrict__ Wv,
    const float* __restrict__ th_post,
    const float* __restrict__ pk, const float* __restrict__ pv,
    short* __restrict__ Bfc, uchar* __restrict__ Bc1,
    uchar* __restrict__ Bc2, short* __restrict__ Bqkv,
    uchar* __restrict__ kf, uchar* __restrict__ vt)
{
    int i = blockIdx.x*256 + threadIdx.x;
    const int NFC = 512*512, NCV = 512*1536, NQ = 3*64*64, NP = BN*HH*PP*DD;
    if (i < NFC) {
        int c = i >> 9, r = i & 511;
        int g = r >> 6, d = r & 63;
        float s = 0.f;
        #pragma unroll
        for (int h = 0; h < 8; ++h)
            s += fc_w[(size_t)c*512 + h*64 + d] * th_post[h*8 + g];
        Bfc[i] = f2s(s);
        return;
    }
    i -= NFC;
    if (i < NCV) {
        int o = i/1536, r = i%1536, dk = r>>9, ci = r&511;
        Bc1[i] = f2q(c1w[(o*512+ci)*3+dk] * 16.f); return;
    }
    i -= NCV;
    if (i < NCV) {
        int o = i/1536, r = i%1536, dk = r>>9, ci = r&511;
        Bc2[i] = f2q(c2w[(o*512+ci)*3+dk] * 16.f); return;
    }
    i -= NCV;
    if (i < NQ) {
        int w = i >> 12, rest = i & 4095;
        const float* W = (w==0)?Wq:(w==1)?Wk:Wv;
        Bqkv[i] = f2s(W[((rest>>6)&63)*64 + (rest&63)]);
        return;
    }
    i -= NQ;
    if (i < NP) {
        int d = i & 63, p = (i >> 6) & 15, h = (i >> 10) & 7, n = i >> 13;
        size_t src = ((size_t)p*HH + h)*DD + d;
        kf[(((size_t)(n*HH+h))*KT + SS + p)*DD + d] = f2q(pk[src]);
        vt[(((size_t)(n*HH+h))*DD + d)*KT + SS + p] = f2q(pv[src]);
    }
}

// ---------------------------------------------------------------------------
// K1: QKV projection, bf16 MFMA. q/k out fp8 [s][d]; V written DIRECTLY into
// transposed fp8 vt[nh][d][k=s].
// ---------------------------------------------------------------------------
__global__ __launch_bounds__(256) void qkv_mfma(
    const float* __restrict__ x, const short* __restrict__ Bqkv,
    uchar* __restrict__ qf, uchar* __restrict__ kf, uchar* __restrict__ vt)
{
    __shared__ short Xs[64*72];
    __shared__ short Ws[192*72];
    const int tid = threadIdx.x;
    const int m0 = blockIdx.x * 64;
    const int h = blockIdx.y;
    const int wave = tid >> 6, lane = tid & 63;
    const int lr = lane & 15, lq = lane >> 4;

    for (int i = tid; i < 1024; i += 256) {
        int r = i >> 4, cg = (i & 15)*4;
        float4 v = *(const float4*)(x + (size_t)(m0+r)*CC + h*64 + cg);
        Xs[r*72+cg+0] = f2s(v.x); Xs[r*72+cg+1] = f2s(v.y);
        Xs[r*72+cg+2] = f2s(v.z); Xs[r*72+cg+3] = f2s(v.w);
    }
    for (int i = tid; i < 3072; i += 256) {
        int r = i >> 4, cg = (i & 15)*4;
        *(short4*)(Ws + r*72 + cg) = *(const short4*)(Bqkv + (size_t)r*64 + cg);
    }
    __syncthreads();

    f32x4 acc[12];
    #pragma unroll
    for (int nt = 0; nt < 12; ++nt) acc[nt] = {0.f,0.f,0.f,0.f};
    #pragma unroll
    for (int ks = 0; ks < 2; ++ks) {
        int ko = ks*32 + lq*8;
        short8 a = *(const short8*)(Xs + (wave*16 + lr)*72 + ko);
        #pragma unroll
        for (int nt = 0; nt < 12; ++nt) {
            short8 b = *(const short8*)(Ws + (nt*16 + lr)*72 + ko);
            acc[nt] = MFMA16(a, b, acc[nt]);
        }
    }
    #pragma unroll
    for (int nt = 0; nt < 12; ++nt) {
        int ep = nt*16 + lr;
        int w = ep >> 6, e = ep & 63;
        #pragma unroll
        for (int reg = 0; reg < 4; ++reg) {
            int m = m0 + wave*16 + lq*4 + reg;
            int n = m >> 10, s = m & 1023;
            float v = acc[nt][reg];
            if (w == 0)      qf[((size_t)(n*HH+h)*SS + s)*DD + e] = f2q(v);
            else if (w == 1) kf[((size_t)(n*HH+h)*KT + s)*DD + e] = f2q(v);
            else             vt[(((size_t)(n*HH+h))*DD + e)*KT + s] = f2q(v);
        }
    }
}

// ---------------------------------------------------------------------------
// K2 v2: energy, fp8 MFMA NT. Block = (mt, nh), grid 1024. Q staged ONCE;
// loop over 17 k-tiles with register-prefetch dbuf.
// ---------------------------------------------------------------------------
__device__ __forceinline__ void en_loadK(const uchar* __restrict__ kf,
    int nh, int kt, int tid, uint2* rk)
{
    #pragma unroll
    for (int j = 0; j < 2; ++j) {
        int i = tid + j*256;
        int r = i >> 3, c8 = (i & 7)*8;
        int kcol = kt*64 + r;
        uint2 v = {0u, 0u};
        if (kcol < KT)
            v = *(const uint2*)(kf + ((size_t)nh*KT + kcol)*DD + c8);
        rk[j] = v;
    }
}

__global__ __launch_bounds__(256) void energy_mfma8(
    const uchar* __restrict__ qf, const uchar* __restrict__ kf,
    uchar* __restrict__ E)
{
    __shared__ uchar Qs[64*72];
    __shared__ uchar Ks[64*72];
    const int tid = threadIdx.x;
    const int mt = blockIdx.x;
    const int nh = blockIdx.y;
    const int wave = tid >> 6, lane = tid & 63;
    const int lr = lane & 15, lq = lane >> 4;
    const int n = nh >> 3, h = nh & 7;

    #pragma unroll
    for (int j = 0; j < 2; ++j) {
        int i = tid + j*256;
        int r = i >> 3, c8 = (i & 7)*8;
        *(uint2*)(Qs + r*72 + c8) =
            *(const uint2*)(qf + ((size_t)nh*SS + mt*64 + r)*DD + c8);
    }

    uint2 rk[2];
    en_loadK(kf, nh, 0, tid, rk);

    for (int kt = 0; kt < 17; ++kt) {
        if (kt) __syncthreads();
        #pragma unroll
        for (int j = 0; j < 2; ++j) {
            int i = tid + j*256;
            *(uint2*)(Ks + (i >> 3)*72 + (i & 7)*8) = rk[j];
        }
        __syncthreads();
        if (kt + 1 < 17) en_loadK(kf, nh, kt+1, tid, rk);

        f32x4 acc[4];
        #pragma unroll
        for (int nt = 0; nt < 4; ++nt) acc[nt] = {0.f,0.f,0.f,0.f};
        #pragma unroll
        for (int ks = 0; ks < 2; ++ks) {
            int ko = ks*32 + lq*8;
            long a = *(const long*)(Qs + (wave*16 + lr)*72 + ko);
            #pragma unroll
            for (int nt = 0; nt < 4; ++nt) {
                long b = *(const long*)(Ks + (nt*16 + lr)*72 + ko);
                acc[nt] = MFMAF8(a, b, acc[nt]);
            }
        }
        #pragma unroll
        for (int nt = 0; nt < 4; ++nt) {
            int kcol = kt*64 + nt*16 + lr;
            if (kcol >= KT) continue;
            #pragma unroll
            for (int reg = 0; reg < 4; ++reg) {
                int q = mt*64 + wave*16 + lq*4 + reg;
                E[(((size_t)(n*SS + q))*HH + h)*KT + kcol] = f2q(acc[nt][reg]);
            }
        }
    }
}

// ---------------------------------------------------------------------------
// K3: softmax (r15 body — 52 VGPR sweet spot), now 4 q-rows per block
// (grid 2048) to amortize dispatch of tiny blocks. thp hoisted; barrier at
// row end protects wred reuse.
// ---------------------------------------------------------------------------
__global__ __launch_bounds__(256) void softmax_kernel(
    uchar* __restrict__ E, const int* __restrict__ mask,
    const float* __restrict__ th_pre)
{
    __shared__ float thp[64];
    __shared__ float wred[4][8];
    const int tid = threadIdx.x;
    const int wave = tid >> 6, lane = tid & 63;
    const int blk0 = blockIdx.x * 4;         // 4 consecutive rows (same n)
    const float invs = 0.044194173824159216f;   // 1/sqrt(512)
    const float l2e  = 1.4426950408889634f;
    if (tid < 64) thp[tid] = th_pre[tid]*(invs*l2e);
    __syncthreads();

    const float sl[8] = {0.5f,0.25f,0.125f,0.0625f,
                         0.03125f,0.015625f,0.0078125f,0.00390625f};
    const int k0 = tid*4;                    // 4 adjacent columns

    for (int rr = 0; rr < 4; ++rr) {
        const int blk = blk0 + rr;
        const int n = blk >> 10, q = blk & 1023;
        uchar* Eb = E + (size_t)blk*HH*KT;
        const int* mrow = mask + (size_t)n*SS*SS + (size_t)q*SS;

        const int4 mk = *(const int4*)(mrow + k0);
        f32x4 dist;
        dist.x = fabsf((float)(q - k0));
        dist.y = fabsf((float)(q - k0 - 1));
        dist.z = fabsf((float)(q - k0 - 2));
        dist.w = fabsf((float)(q - k0 - 3));

        f32x4 tp[8];
        float tl[8];
        float sm[8];
        #pragma unroll
        for (int g = 0; g < 8; ++g) { sm[g] = 0.f; tl[g] = 0.f; }

        {
            f32x4 a[8];
            #pragma unroll
            for (int g = 0; g < 8; ++g) {
                uint u = *(const uint*)(Eb + g*KT + k0);
                f32x2 lo = __builtin_amdgcn_cvt_pk_f32_fp8((int)u, false);
                f32x2 hi = __builtin_amdgcn_cvt_pk_f32_fp8((int)u, true);
                f32x4 r; r.x = lo.x; r.y = lo.y; r.z = hi.x; r.w = hi.y;
                a[g] = r - dist*sl[g];
            }
            #pragma unroll
            for (int h = 0; h < 8; ++h) {
                f32x4 t = {0.f,0.f,0.f,0.f};
                #pragma unroll
                for (int g = 0; g < 8; ++g)
                    t += a[g] * thp[h*8 + g];
                f32x4 e;
                e.x = (mk.x == 0) ? 0.f : exp2f(t.x);
                e.y = (mk.y == 0) ? 0.f : exp2f(t.y);
                e.z = (mk.z == 0) ? 0.f : exp2f(t.z);
                e.w = (mk.w == 0) ? 0.f : exp2f(t.w);
                tp[h] = e;
                sm[h] += e.x + e.y + e.z + e.w;
            }
        }
        if (tid < 16) {                      // persistent keys
            const int k = 1024 + tid;
            float a[8];
            #pragma unroll
            for (int g = 0; g < 8; ++g) {
                f32x2 r = __builtin_amdgcn_cvt_pk_f32_fp8((int)Eb[g*KT + k], false);
                a[g] = r.x;
            }
            #pragma unroll
            for (int h = 0; h < 8; ++h) {
                float t = 0.f;
                #pragma unroll
                for (int g = 0; g < 8; ++g) t = fmaf(thp[h*8 + g], a[g], t);
                float e = exp2f(t);
                tl[h] = e;
                sm[h] += e;
            }
        }
        #pragma unroll
        for (int g = 0; g < 8; ++g) {
            #pragma unroll
            for (int off = 32; off > 0; off >>= 1)
                sm[g] += __shfl_xor(sm[g], off);
        }
        if (lane == 0) {
            #pragma unroll
            for (int g = 0; g < 8; ++g) wred[wave][g] = sm[g];
        }
        __syncthreads();
        float lred[8];
        #pragma unroll
        for (int g = 0; g < 8; ++g)
            lred[g] = 1.0f / (wred[0][g] + wred[1][g] + wred[2][g] + wred[3][g]);

        #pragma unroll
        for (int h = 0; h < 8; ++h) {
            f32x4 e = tp[h] * lred[h];
            int p = __builtin_amdgcn_cvt_pk_fp8_f32(e.x, e.y, 0, false);
            p = __builtin_amdgcn_cvt_pk_fp8_f32(e.z, e.w, p, true);
            *(uint*)(Eb + h*KT + k0) = (uint)p;
        }
        if (tid < 16) {
            const int k = 1024 + tid;
            #pragma unroll
            for (int g = 0; g < 8; ++g)
                Eb[g*KT + k] = f2q(tl[g] * lred[g]);
        }
        __syncthreads();                     // wred reuse next row
    }
}

// ---------------------------------------------------------------------------
// K4 v2: PV fp8 MFMA, q-tile 64 (grid 1024), 4 waves own 32x32 quadrants.
// ---------------------------------------------------------------------------
__device__ __forceinline__ void pv_loadP(const uchar* __restrict__ E,
    int n, int h, int ql0, int kt, int tid, uint2* rp)
{
    #pragma unroll
    for (int j = 0; j < 2; ++j) {
        int i = tid + j*256;
        int r = i >> 3, cg = (i & 7)*8;
        int k = kt*64 + cg;
        uint2 v = {0u, 0u};
        if (k < KT)
            v = *(const uint2*)(E + (((size_t)(n*SS + ql0 + r))*HH + h)*KT + k);
        rp[j] = v;
    }
}
__device__ __forceinline__ void pv_loadV(const uchar* __restrict__ vt,
    int nh, int kt, int tid, uint2* rv)
{
    #pragma unroll
    for (int j = 0; j < 2; ++j) {
        int i = tid + j*256;
        int r = i >> 3, cg = (i & 7)*8;
        int k = kt*64 + cg;
        uint2 v = {0u, 0u};
        if (k < KT)
            v = *(const uint2*)(vt + ((size_t)nh*DD + r)*KT + k);
        rv[j] = v;
    }
}

__global__ __launch_bounds__(256) void pv_mfma(
    const uchar* __restrict__ E, const uchar* __restrict__ vt,
    short* __restrict__ AO)
{
    __shared__ uchar Ps[64*72];
    __shared__ uchar Vs[64*72];
    const int tid = threadIdx.x;
    const int ql0 = blockIdx.x * 64;
    const int nh = blockIdx.y;
    const int n = nh >> 3, h = nh & 7;
    const int wave = tid >> 6, lane = tid & 63;
    const int lr = lane & 15, lq = lane >> 4;
    const int mq = (wave & 1)*32, nq = (wave >> 1)*32;

    uint2 rp[2], rv[2];
    pv_loadP(E, n, h, ql0, 0, tid, rp);
    pv_loadV(vt, nh, 0, tid, rv);

    f32x4 acc[2][2];
    #pragma unroll
    for (int i = 0; i < 2; ++i)
        #pragma unroll
        for (int j = 0; j < 2; ++j) acc[i][j] = {0.f,0.f,0.f,0.f};

    for (int kt = 0; kt < 17; ++kt) {
        if (kt) __syncthreads();
        #pragma unroll
        for (int j = 0; j < 2; ++j) {
            int i = tid + j*256;
            *(uint2*)(Ps + (i >> 3)*72 + (i & 7)*8) = rp[j];
        }
        #pragma unroll
        for (int j = 0; j < 2; ++j) {
            int i = tid + j*256;
            *(uint2*)(Vs + (i >> 3)*72 + (i & 7)*8) = rv[j];
        }
        __syncthreads();
        if (kt + 1 < 17) {
            pv_loadP(E, n, h, ql0, kt+1, tid, rp);
            pv_loadV(vt, nh, kt+1, tid, rv);
        }
        #pragma unroll
        for (int ks = 0; ks < 2; ++ks) {
            int ko = ks*32 + lq*8;
            long a0 = *(const long*)(Ps + (mq + lr)*72 + ko);
            long a1 = *(const long*)(Ps + (mq + 16 + lr)*72 + ko);
            long b0 = *(const long*)(Vs + (nq + lr)*72 + ko);
            long b1 = *(const long*)(Vs + (nq + 16 + lr)*72 + ko);
            acc[0][0] = MFMAF8(a0, b0, acc[0][0]);
            acc[0][1] = MFMAF8(a0, b1, acc[0][1]);
            acc[1][0] = MFMAF8(a1, b0, acc[1][0]);
            acc[1][1] = MFMAF8(a1, b1, acc[1][1]);
        }
    }
    #pragma unroll
    for (int mt = 0; mt < 2; ++mt)
        #pragma unroll
        for (int nt = 0; nt < 2; ++nt) {
            int d = nq + nt*16 + lr;
            #pragma unroll
            for (int reg = 0; reg < 4; ++reg) {
                int qg = ql0 + mq + mt*16 + lq*4 + reg;
                AO[((size_t)(n*SS) + qg)*CC + h*64 + d] = f2s(acc[mt][nt][reg]);
            }
        }
}

// ---------------------------------------------------------------------------
// K5: fc (th_post folded into weights), bf16 MFMA, 64x64, XCD-swizzled.
// Writes xres (bf16) AND xres8 (fp8 copy for conv1's A operand).
// ---------------------------------------------------------------------------
__device__ __forceinline__ void g_load4(const short* __restrict__ src,
    size_t rowstride, int row0, int col0, int tid, short4* r)
{
    #pragma unroll
    for (int j = 0; j < 4; ++j) {
        int i = tid + j*256;
        int rr = i >> 4, cg = (i & 15)*4;
        r[j] = *(const short4*)(src + (size_t)(row0 + rr)*rowstride + col0 + cg);
    }
}
__device__ __forceinline__ void lds_store4(short* __restrict__ dst,
    int tid, const short4* r)
{
    #pragma unroll
    for (int j = 0; j < 4; ++j) {
        int i = tid + j*256;
        *(short4*)(dst + (i >> 4)*72 + (i & 15)*4) = r[j];
    }
}

__global__ __launch_bounds__(256) void fc_mfma(
    const short* __restrict__ A, const short* __restrict__ Bt,
    const float* __restrict__ bias, const float* __restrict__ x,
    short* __restrict__ out, uchar* __restrict__ out8)
{
    __shared__ short As[64*72];
    __shared__ short Bs[64*72];
    const int tid = threadIdx.x;
    const int lin = blockIdx.x + 8*blockIdx.y;      // grid (8,128)
    const int xcd = lin & 7, slot = lin >> 3;
    const int m0 = (xcd*16 + (slot & 15))*64;
    const int n0 = (slot >> 4)*64;
    const int wave = tid >> 6, lane = tid & 63;
    const int lr = lane & 15, lq = lane >> 4;

    short4 ra[4], rb[4];
    g_load4(A, CC, m0, 0, tid, ra);
    g_load4(Bt, CC, n0, 0, tid, rb);

    f32x4 acc[4];
    #pragma unroll
    for (int nt = 0; nt < 4; ++nt) acc[nt] = {0.f,0.f,0.f,0.f};

    for (int kt = 0; kt < CC; kt += 64) {
        if (kt) __syncthreads();
        lds_store4(As, tid, ra);
        lds_store4(Bs, tid, rb);
        __syncthreads();
        if (kt + 64 < CC) {
            g_load4(A, CC, m0, kt+64, tid, ra);
            g_load4(Bt, CC, n0, kt+64, tid, rb);
        }
        #pragma unroll
        for (int ks = 0; ks < 2; ++ks) {
            int ko = ks*32 + lq*8;
            short8 a = *(const short8*)(As + (wave*16 + lr)*72 + ko);
            #pragma unroll
            for (int nt = 0; nt < 4; ++nt) {
                short8 b = *(const short8*)(Bs + (nt*16 + lr)*72 + ko);
                acc[nt] = MFMA16(a, b, acc[nt]);
            }
        }
    }
    #pragma unroll
    for (int nt = 0; nt < 4; ++nt) {
        int nn = n0 + nt*16 + lr;
        #pragma unroll
        for (int reg = 0; reg < 4; ++reg) {
            int m = m0 + wave*16 + lq*4 + reg;
            float v = acc[nt][reg] + bias[nn] + x[(size_t)m*CC + nn];
            out[(size_t)m*CC + nn]  = f2s(v);
            out8[(size_t)m*CC + nn] = f2q(v);
        }
    }
}

// ---------------------------------------------------------------------------
// K6 v2: causal conv fp8 NT GEMM, BK=128 (12 K-iters).
// ---------------------------------------------------------------------------
__device__ __forceinline__ void conv_loadA8w(const uchar* __restrict__ A,
    int m0, int kt, int tid, uint2* ra)
{
    const int shift = (kt >> 9) - 2;
    const int ci0 = kt & 511;
    #pragma unroll
    for (int j = 0; j < 4; ++j) {
        int i = tid + j*256;
        int rr = i >> 4, c8 = (i & 15)*8;
        int m = m0 + rr;
        int s = m & (SS-1);
        uint2 v = {0u, 0u};
        if (s + shift >= 0)
            v = *(const uint2*)(A + (size_t)(m + shift)*CC + ci0 + c8);
        ra[j] = v;
    }
}
__device__ __forceinline__ void g_load8w(const uchar* __restrict__ src,
    size_t rowstride, int row0, int col0, int tid, uint2* r)
{
    #pragma unroll
    for (int j = 0; j < 4; ++j) {
        int i = tid + j*256;
        int rr = i >> 4, c8 = (i & 15)*8;
        r[j] = *(const uint2*)(src + (size_t)(row0 + rr)*rowstride + col0 + c8);
    }
}
__device__ __forceinline__ void lds_store8w(uchar* __restrict__ dst,
    int tid, const uint2* r)
{
    #pragma unroll
    for (int j = 0; j < 4; ++j) {
        int i = tid + j*256;
        *(uint2*)(dst + (i >> 4)*136 + (i & 15)*8) = r[j];
    }
}

__global__ __launch_bounds__(256) void conv_mfma8(
    const uchar* __restrict__ A, const uchar* __restrict__ Bt,
    const float* __restrict__ bias, uchar* __restrict__ out8,
    short* __restrict__ out16, int f8out)
{
    __shared__ uchar As[64*136];
    __shared__ uchar Bs[64*136];
    const int tid = threadIdx.x;
    const int lin = blockIdx.x + 8*blockIdx.y;      // grid (8,128)
    const int xcd = lin & 7, slot = lin >> 3;
    const int m0 = (xcd*16 + (slot & 15))*64;
    const int n0 = (slot >> 4)*64;
    const int wave = tid >> 6, lane = tid & 63;
    const int lr = lane & 15, lq = lane >> 4;

    uint2 ra[4], rb[4];
    conv_loadA8w(A, m0, 0, tid, ra);
    g_load8w(Bt, 1536, n0, 0, tid, rb);

    f32x4 acc[4];
    #pragma unroll
    for (int nt = 0; nt < 4; ++nt) acc[nt] = {0.f,0.f,0.f,0.f};

    for (int kt = 0; kt < 1536; kt += 128) {
        if (kt) __syncthreads();
        lds_store8w(As, tid, ra);
        lds_store8w(Bs, tid, rb);
        __syncthreads();
        if (kt + 128 < 1536) {
            conv_loadA8w(A, m0, kt+128, tid, ra);
            g_load8w(Bt, 1536, n0, kt+128, tid, rb);
        }
        #pragma unroll
        for (int ks = 0; ks < 4; ++ks) {
            int ko = ks*32 + lq*8;
            long a = *(const long*)(As + (wave*16 + lr)*136 + ko);
            #pragma unroll
            for (int nt = 0; nt < 4; ++nt) {
                long b = *(const long*)(Bs + (nt*16 + lr)*136 + ko);
                acc[nt] = MFMAF8(a, b, acc[nt]);
            }
        }
    }
    #pragma unroll
    for (int nt = 0; nt < 4; ++nt) {
        int nn = n0 + nt*16 + lr;
        #pragma unroll
        for (int reg = 0; reg < 4; ++reg) {
            int m = m0 + wave*16 + lq*4 + reg;
            float v = fmaxf(acc[nt][reg]*0.0625f + bias[nn], 0.f);
            if (f8out) out8[(size_t)m*CC + nn]  = f2q(v);
            else       out16[(size_t)m*CC + nn] = f2s(v);
        }
    }
}

// ---------------------------------------------------------------------------
// K7: out = LN(relu(c2 + xres) masked) * g + b.  4 rows per block.
// ---------------------------------------------------------------------------
__global__ __launch_bounds__(256) void final_kernel(
    const short* __restrict__ c2, const short* __restrict__ xres,
    const int* __restrict__ mask, const float* __restrict__ g,
    const float* __restrict__ b, float* __restrict__ out)
{
    __shared__ float red[256];
    const int tid = threadIdx.x;
    const int m0 = blockIdx.x * 4;
    const int c0 = tid*2;
    const float2 gg = *(const float2*)(g + c0);
    const float2 bb = *(const float2*)(b + c0);

    for (int rr = 0; rr < 4; ++rr) {
        const int m = m0 + rr;
        const int n = m >> 10, s = m & 1023;
        const int mk = mask[(size_t)n*SS*SS + (size_t)s*SS];

        short2 ca = *(const short2*)(c2 + (size_t)m*CC + c0);
        short2 xa = *(const short2*)(xres + (size_t)m*CC + c0);
        float v0 = fmaxf(s2f(ca.x) + s2f(xa.x), 0.f);
        float v1 = fmaxf(s2f(ca.y) + s2f(xa.y), 0.f);
        if (mk == 0) { v0 = 0.f; v1 = 0.f; }

        red[tid] = v0 + v1;
        __syncthreads();
        for (int off = 128; off > 0; off >>= 1) {
            if (tid < off) red[tid] += red[tid + off];
            __syncthreads();
        }
        float mu = red[0] * (1.0f/512.0f);
        __syncthreads();
        float d0 = v0 - mu, d1 = v1 - mu;
        red[tid] = d0*d0 + d1*d1;
        __syncthreads();
        for (int off = 128; off > 0; off >>= 1) {
            if (tid < off) red[tid] += red[tid + off];
            __syncthreads();
        }
        float rstd = rsqrtf(red[0] * (1.0f/512.0f) + 1e-5f);
        float2 o;
        o.x = d0*rstd*gg.x + bb.x;
        o.y = d1*rstd*gg.y + bb.y;
        *(float2*)(out + (size_t)m*CC + c0) = o;
        __syncthreads();                     // red reuse next row
    }
}

// ---------------------------------------------------------------------------
extern "C" void kernel_launch(void* const* d_in, const int* in_sizes, int n_in,
                              void* d_out, int out_size, void* d_ws, size_t ws_size,
                              hipStream_t stream)
{
    const float* x      = (const float*)d_in[0];
    const int*   mask   = (const int*)  d_in[1];
    const float* Wq     = (const float*)d_in[2];
    const float* Wk     = (const float*)d_in[3];
    const float* Wv     = (const float*)d_in[4];
    const float* pk     = (const float*)d_in[5];
    const float* pv     = (const float*)d_in[6];
    const float* th_pre = (const float*)d_in[7];
    const float* th_post= (const float*)d_in[8];
    const float* fc_w   = (const float*)d_in[9];
    const float* fc_b   = (const float*)d_in[10];
    const float* c1w    = (const float*)d_in[11];
    const float* c1b    = (const float*)d_in[12];
    const float* c2w    = (const float*)d_in[13];
    const float* c2b    = (const float*)d_in[14];
    const float* lng    = (const float*)d_in[15];
    const float* lnb    = (const float*)d_in[16];
    float* out = (float*)d_out;
    (void)in_sizes; (void)n_in; (void)out_size; (void)ws_size;

    char* ws = (char*)d_ws;
    const size_t SZ_Q  = (size_t)BN*HH*SS*DD;      //  4.19 MB (fp8)
    const size_t SZ_K  = (size_t)BN*HH*KT*DD;      //  4.26 MB (fp8)
    const size_t SZ_VT = (size_t)BN*HH*DD*KT;      //  4.26 MB (fp8)
    const size_t SZ_E  = (size_t)BN*SS*HH*KT;      // 68.2 MB (fp8)
    const size_t SZ_A  = (size_t)BN*SS*CC*2;       //  8.39 MB (bf16)
    const size_t SZ_A8 = (size_t)BN*SS*CC;         //  4.19 MB (fp8)

    uchar* qf  = (uchar*)(ws);
    uchar* kf  = (uchar*)(ws + SZ_Q);
    uchar* vt  = (uchar*)(ws + SZ_Q + SZ_K);
    uchar* E   = (uchar*)(ws + SZ_Q + SZ_K + SZ_VT);
    short* AO  = (short*)(ws + SZ_Q + SZ_K + SZ_VT + SZ_E);
    char*  wend = ws + SZ_Q + SZ_K + SZ_VT + SZ_E + SZ_A;
    short* Bfc = (short*)(wend);
    uchar* Bc1 = (uchar*)(wend + 512*512*2);
    uchar* Bc2 = (uchar*)(wend + 512*512*2 + 512*1536);
    short* Bqkv= (short*)(wend + 512*512*2 + 2*512*1536);
    uchar* xres8 = (uchar*)(wend + 512*512*2 + 2*512*1536 + 3*64*64*2);
    short* c2buf = (short*)(wend + 512*512*2 + 2*512*1536 + 3*64*64*2 + SZ_A8);
    // Aliases (dead regions): xres(bf16) over qf+kf (dead after energy);
    // h1(fp8) over E (dead after pv).
    short* xres = (short*)(ws);
    uchar* h18  = (uchar*)E;
    // total ws ~= 103 MB (ws_size >= 256 MiB)

    {
        int total = 512*512 + 2*512*1536 + 3*64*64 + BN*HH*PP*DD;
        prep_kernel<<<(total + 255)/256, 256, 0, stream>>>(
            fc_w, c1w, c2w, Wq, Wk, Wv, th_post, pk, pv,
            Bfc, Bc1, Bc2, Bqkv, kf, vt);
    }
    qkv_mfma<<<dim3(BN*SS/64, HH), 256, 0, stream>>>(x, Bqkv, qf, kf, vt);

    energy_mfma8<<<dim3(SS/64, BN*HH), 256, 0, stream>>>(qf, kf, E);
    softmax_kernel<<<BN*SS/4, 256, 0, stream>>>(E, mask, th_pre);
    pv_mfma<<<dim3(SS/64, BN*HH), 256, 0, stream>>>(E, vt, AO);

    fc_mfma<<<dim3(8, 128), 256, 0, stream>>>(AO, Bfc, fc_b, x, xres, xres8);
    conv_mfma8<<<dim3(8, 128), 256, 0, stream>>>(xres8, Bc1, c1b, h18, (short*)nullptr, 1);
    conv_mfma8<<<dim3(8, 128), 256, 0, stream>>>(h18, Bc2, c2b, (uchar*)nullptr, c2buf, 0);
    final_kernel<<<BN*SS/4, 256, 0, stream>>>(c2buf, xres, mask, lng, lnb, out);
}

// Round 20
// 286.029 us; speedup vs baseline: 1.7551x; 1.0248x over previous
//
#include <hip/hip_runtime.h>
#include <hip/hip_bf16.h>

#define BN 8
#define SS 1024
#define CC 512
#define HH 8
#define DD 64
#define PP 16
#define KT 1040

typedef __hip_bfloat16 bf16;
typedef unsigned char uchar;
typedef unsigned short ushort;
typedef unsigned int uint;
typedef __attribute__((ext_vector_type(8))) short short8;
typedef __attribute__((ext_vector_type(4))) float f32x4;
typedef __attribute__((ext_vector_type(2))) float f32x2;

__device__ __forceinline__ short f2s(float v){ bf16 b = __float2bfloat16(v); return *(short*)&b; }
__device__ __forceinline__ float s2f(short s){ bf16 b; *(short*)&b = s; return __bfloat162float(b); }
__device__ __forceinline__ uchar f2q(float v){          // f32 -> fp8 e4m3 byte
    return (uchar)__builtin_amdgcn_cvt_pk_fp8_f32(v, v, 0, false);
}

#define MFMA16(a,b,c)  __builtin_amdgcn_mfma_f32_16x16x32_bf16(a,b,c,0,0,0)
#define MFMAF8(a,b,c)  __builtin_amdgcn_mfma_f32_16x16x32_fp8_fp8(a,b,c,0,0,0)

// ---------------------------------------------------------------------------
// P0: weight pre-conversion + persistent-token tails.
// ---------------------------------------------------------------------------
__global__ __launch_bounds__(256) void prep_kernel(
    const float* __restrict__ fc_w, const float* __restrict__ c1w,
    const float* __restrict__ c2w, const float* __restrict__ Wq,
    const float* __restrict__ Wk, const float* __restrict__ Wv,
    const float* __restrict__ th_post,
    const float* __restrict__ pk, const float* __restrict__ pv,
    short* __restrict__ Bfc, uchar* __restrict__ Bc1,
    uchar* __restrict__ Bc2, short* __restrict__ Bqkv,
    uchar* __restrict__ kf, uchar* __restrict__ vt)
{
    int i = blockIdx.x*256 + threadIdx.x;
    const int NFC = 512*512, NCV = 512*1536, NQ = 3*64*64, NP = BN*HH*PP*DD;
    if (i < NFC) {
        int c = i >> 9, r = i & 511;
        int g = r >> 6, d = r & 63;
        float s = 0.f;
        #pragma unroll
        for (int h = 0; h < 8; ++h)
            s += fc_w[(size_t)c*512 + h*64 + d] * th_post[h*8 + g];
        Bfc[i] = f2s(s);
        return;
    }
    i -= NFC;
    if (i < NCV) {
        int o = i/1536, r = i%1536, dk = r>>9, ci = r&511;
        Bc1[i] = f2q(c1w[(o*512+ci)*3+dk] * 16.f); return;
    }
    i -= NCV;
    if (i < NCV) {
        int o = i/1536, r = i%1536, dk = r>>9, ci = r&511;
        Bc2[i] = f2q(c2w[(o*512+ci)*3+dk] * 16.f); return;
    }
    i -= NCV;
    if (i < NQ) {
        int w = i >> 12, rest = i & 4095;
        const float* W = (w==0)?Wq:(w==1)?Wk:Wv;
        Bqkv[i] = f2s(W[((rest>>6)&63)*64 + (rest&63)]);
        return;
    }
    i -= NQ;
    if (i < NP) {
        int d = i & 63, p = (i >> 6) & 15, h = (i >> 10) & 7, n = i >> 13;
        size_t src = ((size_t)p*HH + h)*DD + d;
        kf[(((size_t)(n*HH+h))*KT + SS + p)*DD + d] = f2q(pk[src]);
        vt[(((size_t)(n*HH+h))*DD + d)*KT + SS + p] = f2q(pv[src]);
    }
}

// ---------------------------------------------------------------------------
// K1: QKV projection, bf16 MFMA. q/k out fp8 [s][d]; V -> transposed vt.
// ---------------------------------------------------------------------------
__global__ __launch_bounds__(256) void qkv_mfma(
    const float* __restrict__ x, const short* __restrict__ Bqkv,
    uchar* __restrict__ qf, uchar* __restrict__ kf, uchar* __restrict__ vt)
{
    __shared__ short Xs[64*72];
    __shared__ short Ws[192*72];
    const int tid = threadIdx.x;
    const int m0 = blockIdx.x * 64;
    const int h = blockIdx.y;
    const int wave = tid >> 6, lane = tid & 63;
    const int lr = lane & 15, lq = lane >> 4;

    for (int i = tid; i < 1024; i += 256) {
        int r = i >> 4, cg = (i & 15)*4;
        float4 v = *(const float4*)(x + (size_t)(m0+r)*CC + h*64 + cg);
        Xs[r*72+cg+0] = f2s(v.x); Xs[r*72+cg+1] = f2s(v.y);
        Xs[r*72+cg+2] = f2s(v.z); Xs[r*72+cg+3] = f2s(v.w);
    }
    for (int i = tid; i < 3072; i += 256) {
        int r = i >> 4, cg = (i & 15)*4;
        *(short4*)(Ws + r*72 + cg) = *(const short4*)(Bqkv + (size_t)r*64 + cg);
    }
    __syncthreads();

    f32x4 acc[12];
    #pragma unroll
    for (int nt = 0; nt < 12; ++nt) acc[nt] = {0.f,0.f,0.f,0.f};
    #pragma unroll
    for (int ks = 0; ks < 2; ++ks) {
        int ko = ks*32 + lq*8;
        short8 a = *(const short8*)(Xs + (wave*16 + lr)*72 + ko);
        #pragma unroll
        for (int nt = 0; nt < 12; ++nt) {
            short8 b = *(const short8*)(Ws + (nt*16 + lr)*72 + ko);
            acc[nt] = MFMA16(a, b, acc[nt]);
        }
    }
    #pragma unroll
    for (int nt = 0; nt < 12; ++nt) {
        int ep = nt*16 + lr;
        int w = ep >> 6, e = ep & 63;
        #pragma unroll
        for (int reg = 0; reg < 4; ++reg) {
            int m = m0 + wave*16 + lq*4 + reg;
            int n = m >> 10, s = m & 1023;
            float v = acc[nt][reg];
            if (w == 0)      qf[((size_t)(n*HH+h)*SS + s)*DD + e] = f2q(v);
            else if (w == 1) kf[((size_t)(n*HH+h)*KT + s)*DD + e] = f2q(v);
            else             vt[(((size_t)(n*HH+h))*DD + e)*KT + s] = f2q(v);
        }
    }
}

// ---------------------------------------------------------------------------
// K2 v3: energy, fp8 MFMA NT, XCD-swizzled: each XCD owns 8 consecutive nh
// (K working set 528 KB per XCD L2 -> no cross-XCD refetch).
// ---------------------------------------------------------------------------
__device__ __forceinline__ void en_loadK(const uchar* __restrict__ kf,
    int nh, int kt, int tid, uint2* rk)
{
    #pragma unroll
    for (int j = 0; j < 2; ++j) {
        int i = tid + j*256;
        int r = i >> 3, c8 = (i & 7)*8;
        int kcol = kt*64 + r;
        uint2 v = {0u, 0u};
        if (kcol < KT)
            v = *(const uint2*)(kf + ((size_t)nh*KT + kcol)*DD + c8);
        rk[j] = v;
    }
}

__global__ __launch_bounds__(256) void energy_mfma8(
    const uchar* __restrict__ qf, const uchar* __restrict__ kf,
    uchar* __restrict__ E)
{
    __shared__ uchar Qs[64*72];
    __shared__ uchar Ks[64*72];
    const int tid = threadIdx.x;
    // XCD swizzle: lin%8 = XCD (round-robin dispatch). Give each XCD 8 nh.
    const int lin = blockIdx.x + 16*blockIdx.y;     // grid (16, 64)
    const int xcd = lin & 7, slot = lin >> 3;       // slot in [0,128)
    const int nh = xcd*8 + (slot & 7);
    const int mt = slot >> 3;
    const int wave = tid >> 6, lane = tid & 63;
    const int lr = lane & 15, lq = lane >> 4;
    const int n = nh >> 3, h = nh & 7;

    #pragma unroll
    for (int j = 0; j < 2; ++j) {
        int i = tid + j*256;
        int r = i >> 3, c8 = (i & 7)*8;
        *(uint2*)(Qs + r*72 + c8) =
            *(const uint2*)(qf + ((size_t)nh*SS + mt*64 + r)*DD + c8);
    }

    uint2 rk[2];
    en_loadK(kf, nh, 0, tid, rk);

    for (int kt = 0; kt < 17; ++kt) {
        if (kt) __syncthreads();
        #pragma unroll
        for (int j = 0; j < 2; ++j) {
            int i = tid + j*256;
            *(uint2*)(Ks + (i >> 3)*72 + (i & 7)*8) = rk[j];
        }
        __syncthreads();
        if (kt + 1 < 17) en_loadK(kf, nh, kt+1, tid, rk);

        f32x4 acc[4];
        #pragma unroll
        for (int nt = 0; nt < 4; ++nt) acc[nt] = {0.f,0.f,0.f,0.f};
        #pragma unroll
        for (int ks = 0; ks < 2; ++ks) {
            int ko = ks*32 + lq*8;
            long a = *(const long*)(Qs + (wave*16 + lr)*72 + ko);
            #pragma unroll
            for (int nt = 0; nt < 4; ++nt) {
                long b = *(const long*)(Ks + (nt*16 + lr)*72 + ko);
                acc[nt] = MFMAF8(a, b, acc[nt]);
            }
        }
        #pragma unroll
        for (int nt = 0; nt < 4; ++nt) {
            int kcol = kt*64 + nt*16 + lr;
            if (kcol >= KT) continue;
            #pragma unroll
            for (int reg = 0; reg < 4; ++reg) {
                int q = mt*64 + wave*16 + lq*4 + reg;
                E[(((size_t)(n*SS + q))*HH + h)*KT + kcol] = f2q(acc[nt][reg]);
            }
        }
    }
}

// ---------------------------------------------------------------------------
// K3: softmax (r15 body), 4 q-rows per block (grid 2048).
// ---------------------------------------------------------------------------
__global__ __launch_bounds__(256) void softmax_kernel(
    uchar* __restrict__ E, const int* __restrict__ mask,
    const float* __restrict__ th_pre)
{
    __shared__ float thp[64];
    __shared__ float wred[4][8];
    const int tid = threadIdx.x;
    const int wave = tid >> 6, lane = tid & 63;
    const int blk0 = blockIdx.x * 4;         // 4 consecutive rows (same n)
    const float invs = 0.044194173824159216f;   // 1/sqrt(512)
    const float l2e  = 1.4426950408889634f;
    if (tid < 64) thp[tid] = th_pre[tid]*(invs*l2e);
    __syncthreads();

    const float sl[8] = {0.5f,0.25f,0.125f,0.0625f,
                         0.03125f,0.015625f,0.0078125f,0.00390625f};
    const int k0 = tid*4;                    // 4 adjacent columns

    for (int rr = 0; rr < 4; ++rr) {
        const int blk = blk0 + rr;
        const int n = blk >> 10, q = blk & 1023;
        uchar* Eb = E + (size_t)blk*HH*KT;
        const int* mrow = mask + (size_t)n*SS*SS + (size_t)q*SS;

        const int4 mk = *(const int4*)(mrow + k0);
        f32x4 dist;
        dist.x = fabsf((float)(q - k0));
        dist.y = fabsf((float)(q - k0 - 1));
        dist.z = fabsf((float)(q - k0 - 2));
        dist.w = fabsf((float)(q - k0 - 3));

        f32x4 tp[8];
        float tl[8];
        float sm[8];
        #pragma unroll
        for (int g = 0; g < 8; ++g) { sm[g] = 0.f; tl[g] = 0.f; }

        {
            f32x4 a[8];
            #pragma unroll
            for (int g = 0; g < 8; ++g) {
                uint u = *(const uint*)(Eb + g*KT + k0);
                f32x2 lo = __builtin_amdgcn_cvt_pk_f32_fp8((int)u, false);
                f32x2 hi = __builtin_amdgcn_cvt_pk_f32_fp8((int)u, true);
                f32x4 r; r.x = lo.x; r.y = lo.y; r.z = hi.x; r.w = hi.y;
                a[g] = r - dist*sl[g];
            }
            #pragma unroll
            for (int h = 0; h < 8; ++h) {
                f32x4 t = {0.f,0.f,0.f,0.f};
                #pragma unroll
                for (int g = 0; g < 8; ++g)
                    t += a[g] * thp[h*8 + g];
                f32x4 e;
                e.x = (mk.x == 0) ? 0.f : exp2f(t.x);
                e.y = (mk.y == 0) ? 0.f : exp2f(t.y);
                e.z = (mk.z == 0) ? 0.f : exp2f(t.z);
                e.w = (mk.w == 0) ? 0.f : exp2f(t.w);
                tp[h] = e;
                sm[h] += e.x + e.y + e.z + e.w;
            }
        }
        if (tid < 16) {                      // persistent keys
            const int k = 1024 + tid;
            float a[8];
            #pragma unroll
            for (int g = 0; g < 8; ++g) {
                f32x2 r = __builtin_amdgcn_cvt_pk_f32_fp8((int)Eb[g*KT + k], false);
                a[g] = r.x;
            }
            #pragma unroll
            for (int h = 0; h < 8; ++h) {
                float t = 0.f;
                #pragma unroll
                for (int g = 0; g < 8; ++g) t = fmaf(thp[h*8 + g], a[g], t);
                float e = exp2f(t);
                tl[h] = e;
                sm[h] += e;
            }
        }
        #pragma unroll
        for (int g = 0; g < 8; ++g) {
            #pragma unroll
            for (int off = 32; off > 0; off >>= 1)
                sm[g] += __shfl_xor(sm[g], off);
        }
        if (lane == 0) {
            #pragma unroll
            for (int g = 0; g < 8; ++g) wred[wave][g] = sm[g];
        }
        __syncthreads();
        float lred[8];
        #pragma unroll
        for (int g = 0; g < 8; ++g)
            lred[g] = 1.0f / (wred[0][g] + wred[1][g] + wred[2][g] + wred[3][g]);

        #pragma unroll
        for (int h = 0; h < 8; ++h) {
            f32x4 e = tp[h] * lred[h];
            int p = __builtin_amdgcn_cvt_pk_fp8_f32(e.x, e.y, 0, false);
            p = __builtin_amdgcn_cvt_pk_fp8_f32(e.z, e.w, p, true);
            *(uint*)(Eb + h*KT + k0) = (uint)p;
        }
        if (tid < 16) {
            const int k = 1024 + tid;
            #pragma unroll
            for (int g = 0; g < 8; ++g)
                Eb[g*KT + k] = f2q(tl[g] * lred[g]);
        }
        __syncthreads();                     // wred reuse next row
    }
}

// ---------------------------------------------------------------------------
// K4 v3: PV fp8 MFMA, q-tile 64, XCD-swizzled (each XCD owns 8 nh -> V
// stays in its L2).
// ---------------------------------------------------------------------------
__device__ __forceinline__ void pv_loadP(const uchar* __restrict__ E,
    int n, int h, int ql0, int kt, int tid, uint2* rp)
{
    #pragma unroll
    for (int j = 0; j < 2; ++j) {
        int i = tid + j*256;
        int r = i >> 3, cg = (i & 7)*8;
        int k = kt*64 + cg;
        uint2 v = {0u, 0u};
        if (k < KT)
            v = *(const uint2*)(E + (((size_t)(n*SS + ql0 + r))*HH + h)*KT + k);
        rp[j] = v;
    }
}
__device__ __forceinline__ void pv_loadV(const uchar* __restrict__ vt,
    int nh, int kt, int tid, uint2* rv)
{
    #pragma unroll
    for (int j = 0; j < 2; ++j) {
        int i = tid + j*256;
        int r = i >> 3, cg = (i & 7)*8;
        int k = kt*64 + cg;
        uint2 v = {0u, 0u};
        if (k < KT)
            v = *(const uint2*)(vt + ((size_t)nh*DD + r)*KT + k);
        rv[j] = v;
    }
}

__global__ __launch_bounds__(256) void pv_mfma(
    const uchar* __restrict__ E, const uchar* __restrict__ vt,
    short* __restrict__ AO)
{
    __shared__ uchar Ps[64*72];
    __shared__ uchar Vs[64*72];
    const int tid = threadIdx.x;
    const int lin = blockIdx.x + 16*blockIdx.y;     // grid (16, 64)
    const int xcd = lin & 7, slot = lin >> 3;
    const int nh = xcd*8 + (slot & 7);
    const int ql0 = (slot >> 3) * 64;
    const int n = nh >> 3, h = nh & 7;
    const int wave = tid >> 6, lane = tid & 63;
    const int lr = lane & 15, lq = lane >> 4;
    const int mq = (wave & 1)*32, nq = (wave >> 1)*32;

    uint2 rp[2], rv[2];
    pv_loadP(E, n, h, ql0, 0, tid, rp);
    pv_loadV(vt, nh, 0, tid, rv);

    f32x4 acc[2][2];
    #pragma unroll
    for (int i = 0; i < 2; ++i)
        #pragma unroll
        for (int j = 0; j < 2; ++j) acc[i][j] = {0.f,0.f,0.f,0.f};

    for (int kt = 0; kt < 17; ++kt) {
        if (kt) __syncthreads();
        #pragma unroll
        for (int j = 0; j < 2; ++j) {
            int i = tid + j*256;
            *(uint2*)(Ps + (i >> 3)*72 + (i & 7)*8) = rp[j];
        }
        #pragma unroll
        for (int j = 0; j < 2; ++j) {
            int i = tid + j*256;
            *(uint2*)(Vs + (i >> 3)*72 + (i & 7)*8) = rv[j];
        }
        __syncthreads();
        if (kt + 1 < 17) {
            pv_loadP(E, n, h, ql0, kt+1, tid, rp);
            pv_loadV(vt, nh, kt+1, tid, rv);
        }
        #pragma unroll
        for (int ks = 0; ks < 2; ++ks) {
            int ko = ks*32 + lq*8;
            long a0 = *(const long*)(Ps + (mq + lr)*72 + ko);
            long a1 = *(const long*)(Ps + (mq + 16 + lr)*72 + ko);
            long b0 = *(const long*)(Vs + (nq + lr)*72 + ko);
            long b1 = *(const long*)(Vs + (nq + 16 + lr)*72 + ko);
            acc[0][0] = MFMAF8(a0, b0, acc[0][0]);
            acc[0][1] = MFMAF8(a0, b1, acc[0][1]);
            acc[1][0] = MFMAF8(a1, b0, acc[1][0]);
            acc[1][1] = MFMAF8(a1, b1, acc[1][1]);
        }
    }
    #pragma unroll
    for (int mt = 0; mt < 2; ++mt)
        #pragma unroll
        for (int nt = 0; nt < 2; ++nt) {
            int d = nq + nt*16 + lr;
            #pragma unroll
            for (int reg = 0; reg < 4; ++reg) {
                int qg = ql0 + mq + mt*16 + lq*4 + reg;
                AO[((size_t)(n*SS) + qg)*CC + h*64 + d] = f2s(acc[mt][nt][reg]);
            }
        }
}

// ---------------------------------------------------------------------------
// K5: fc (th_post folded into weights), bf16 MFMA, 64x64, XCD-swizzled.
// ---------------------------------------------------------------------------
__device__ __forceinline__ void g_load4(const short* __restrict__ src,
    size_t rowstride, int row0, int col0, int tid, short4* r)
{
    #pragma unroll
    for (int j = 0; j < 4; ++j) {
        int i = tid + j*256;
        int rr = i >> 4, cg = (i & 15)*4;
        r[j] = *(const short4*)(src + (size_t)(row0 + rr)*rowstride + col0 + cg);
    }
}
__device__ __forceinline__ void lds_store4(short* __restrict__ dst,
    int tid, const short4* r)
{
    #pragma unroll
    for (int j = 0; j < 4; ++j) {
        int i = tid + j*256;
        *(short4*)(dst + (i >> 4)*72 + (i & 15)*4) = r[j];
    }
}

__global__ __launch_bounds__(256) void fc_mfma(
    const short* __restrict__ A, const short* __restrict__ Bt,
    const float* __restrict__ bias, const float* __restrict__ x,
    short* __restrict__ out, uchar* __restrict__ out8)
{
    __shared__ short As[64*72];
    __shared__ short Bs[64*72];
    const int tid = threadIdx.x;
    const int lin = blockIdx.x + 8*blockIdx.y;      // grid (8,128)
    const int xcd = lin & 7, slot = lin >> 3;
    const int m0 = (xcd*16 + (slot & 15))*64;
    const int n0 = (slot >> 4)*64;
    const int wave = tid >> 6, lane = tid & 63;
    const int lr = lane & 15, lq = lane >> 4;

    short4 ra[4], rb[4];
    g_load4(A, CC, m0, 0, tid, ra);
    g_load4(Bt, CC, n0, 0, tid, rb);

    f32x4 acc[4];
    #pragma unroll
    for (int nt = 0; nt < 4; ++nt) acc[nt] = {0.f,0.f,0.f,0.f};

    for (int kt = 0; kt < CC; kt += 64) {
        if (kt) __syncthreads();
        lds_store4(As, tid, ra);
        lds_store4(Bs, tid, rb);
        __syncthreads();
        if (kt + 64 < CC) {
            g_load4(A, CC, m0, kt+64, tid, ra);
            g_load4(Bt, CC, n0, kt+64, tid, rb);
        }
        #pragma unroll
        for (int ks = 0; ks < 2; ++ks) {
            int ko = ks*32 + lq*8;
            short8 a = *(const short8*)(As + (wave*16 + lr)*72 + ko);
            #pragma unroll
            for (int nt = 0; nt < 4; ++nt) {
                short8 b = *(const short8*)(Bs + (nt*16 + lr)*72 + ko);
                acc[nt] = MFMA16(a, b, acc[nt]);
            }
        }
    }
    #pragma unroll
    for (int nt = 0; nt < 4; ++nt) {
        int nn = n0 + nt*16 + lr;
        #pragma unroll
        for (int reg = 0; reg < 4; ++reg) {
            int m = m0 + wave*16 + lq*4 + reg;
            float v = acc[nt][reg] + bias[nn] + x[(size_t)m*CC + nn];
            out[(size_t)m*CC + nn]  = f2s(v);
            out8[(size_t)m*CC + nn] = f2q(v);
        }
    }
}

// ---------------------------------------------------------------------------
// K6 v2: causal conv fp8 NT GEMM, BK=128 (12 K-iters), XCD-swizzled.
// ---------------------------------------------------------------------------
__device__ __forceinline__ void conv_loadA8w(const uchar* __restrict__ A,
    int m0, int kt, int tid, uint2* ra)
{
    const int shift = (kt >> 9) - 2;
    const int ci0 = kt & 511;
    #pragma unroll
    for (int j = 0; j < 4; ++j) {
        int i = tid + j*256;
        int rr = i >> 4, c8 = (i & 15)*8;
        int m = m0 + rr;
        int s = m & (SS-1);
        uint2 v = {0u, 0u};
        if (s + shift >= 0)
            v = *(const uint2*)(A + (size_t)(m + shift)*CC + ci0 + c8);
        ra[j] = v;
    }
}
__device__ __forceinline__ void g_load8w(const uchar* __restrict__ src,
    size_t rowstride, int row0, int col0, int tid, uint2* r)
{
    #pragma unroll
    for (int j = 0; j < 4; ++j) {
        int i = tid + j*256;
        int rr = i >> 4, c8 = (i & 15)*8;
        r[j] = *(const uint2*)(src + (size_t)(row0 + rr)*rowstride + col0 + c8);
    }
}
__device__ __forceinline__ void lds_store8w(uchar* __restrict__ dst,
    int tid, const uint2* r)
{
    #pragma unroll
    for (int j = 0; j < 4; ++j) {
        int i = tid + j*256;
        *(uint2*)(dst + (i >> 4)*136 + (i & 15)*8) = r[j];
    }
}

__global__ __launch_bounds__(256) void conv_mfma8(
    const uchar* __restrict__ A, const uchar* __restrict__ Bt,
    const float* __restrict__ bias, uchar* __restrict__ out8,
    short* __restrict__ out16, int f8out)
{
    __shared__ uchar As[64*136];
    __shared__ uchar Bs[64*136];
    const int tid = threadIdx.x;
    const int lin = blockIdx.x + 8*blockIdx.y;      // grid (8,128)
    const int xcd = lin & 7, slot = lin >> 3;
    const int m0 = (xcd*16 + (slot & 15))*64;
    const int n0 = (slot >> 4)*64;
    const int wave = tid >> 6, lane = tid & 63;
    const int lr = lane & 15, lq = lane >> 4;

    uint2 ra[4], rb[4];
    conv_loadA8w(A, m0, 0, tid, ra);
    g_load8w(Bt, 1536, n0, 0, tid, rb);

    f32x4 acc[4];
    #pragma unroll
    for (int nt = 0; nt < 4; ++nt) acc[nt] = {0.f,0.f,0.f,0.f};

    for (int kt = 0; kt < 1536; kt += 128) {
        if (kt) __syncthreads();
        lds_store8w(As, tid, ra);
        lds_store8w(Bs, tid, rb);
        __syncthreads();
        if (kt + 128 < 1536) {
            conv_loadA8w(A, m0, kt+128, tid, ra);
            g_load8w(Bt, 1536, n0, kt+128, tid, rb);
        }
        #pragma unroll
        for (int ks = 0; ks < 4; ++ks) {
            int ko = ks*32 + lq*8;
            long a = *(const long*)(As + (wave*16 + lr)*136 + ko);
            #pragma unroll
            for (int nt = 0; nt < 4; ++nt) {
                long b = *(const long*)(Bs + (nt*16 + lr)*136 + ko);
                acc[nt] = MFMAF8(a, b, acc[nt]);
            }
        }
    }
    #pragma unroll
    for (int nt = 0; nt < 4; ++nt) {
        int nn = n0 + nt*16 + lr;
        #pragma unroll
        for (int reg = 0; reg < 4; ++reg) {
            int m = m0 + wave*16 + lq*4 + reg;
            float v = fmaxf(acc[nt][reg]*0.0625f + bias[nn], 0.f);
            if (f8out) out8[(size_t)m*CC + nn]  = f2q(v);
            else       out16[(size_t)m*CC + nn] = f2s(v);
        }
    }
}

// ---------------------------------------------------------------------------
// K7: out = LN(relu(c2 + xres) masked) * g + b.  4 rows per block.
// ---------------------------------------------------------------------------
__global__ __launch_bounds__(256) void final_kernel(
    const short* __restrict__ c2, const short* __restrict__ xres,
    const int* __restrict__ mask, const float* __restrict__ g,
    const float* __restrict__ b, float* __restrict__ out)
{
    __shared__ float red[256];
    const int tid = threadIdx.x;
    const int m0 = blockIdx.x * 4;
    const int c0 = tid*2;
    const float2 gg = *(const float2*)(g + c0);
    const float2 bb = *(const float2*)(b + c0);

    for (int rr = 0; rr < 4; ++rr) {
        const int m = m0 + rr;
        const int n = m >> 10, s = m & 1023;
        const int mk = mask[(size_t)n*SS*SS + (size_t)s*SS];

        short2 ca = *(const short2*)(c2 + (size_t)m*CC + c0);
        short2 xa = *(const short2*)(xres + (size_t)m*CC + c0);
        float v0 = fmaxf(s2f(ca.x) + s2f(xa.x), 0.f);
        float v1 = fmaxf(s2f(ca.y) + s2f(xa.y), 0.f);
        if (mk == 0) { v0 = 0.f; v1 = 0.f; }

        red[tid] = v0 + v1;
        __syncthreads();
        for (int off = 128; off > 0; off >>= 1) {
            if (tid < off) red[tid] += red[tid + off];
            __syncthreads();
        }
        float mu = red[0] * (1.0f/512.0f);
        __syncthreads();
        float d0 = v0 - mu, d1 = v1 - mu;
        red[tid] = d0*d0 + d1*d1;
        __syncthreads();
        for (int off = 128; off > 0; off >>= 1) {
            if (tid < off) red[tid] += red[tid + off];
            __syncthreads();
        }
        float rstd = rsqrtf(red[0] * (1.0f/512.0f) + 1e-5f);
        float2 o;
        o.x = d0*rstd*gg.x + bb.x;
        o.y = d1*rstd*gg.y + bb.y;
        *(float2*)(out + (size_t)m*CC + c0) = o;
        __syncthreads();                     // red reuse next row
    }
}

// ---------------------------------------------------------------------------
extern "C" void kernel_launch(void* const* d_in, const int* in_sizes, int n_in,
                              void* d_out, int out_size, void* d_ws, size_t ws_size,
                              hipStream_t stream)
{
    const float* x      = (const float*)d_in[0];
    const int*   mask   = (const int*)  d_in[1];
    const float* Wq     = (const float*)d_in[2];
    const float* Wk     = (const float*)d_in[3];
    const float* Wv     = (const float*)d_in[4];
    const float* pk     = (const float*)d_in[5];
    const float* pv     = (const float*)d_in[6];
    const float* th_pre = (const float*)d_in[7];
    const float* th_post= (const float*)d_in[8];
    const float* fc_w   = (const float*)d_in[9];
    const float* fc_b   = (const float*)d_in[10];
    const float* c1w    = (const float*)d_in[11];
    const float* c1b    = (const float*)d_in[12];
    const float* c2w    = (const float*)d_in[13];
    const float* c2b    = (const float*)d_in[14];
    const float* lng    = (const float*)d_in[15];
    const float* lnb    = (const float*)d_in[16];
    float* out = (float*)d_out;
    (void)in_sizes; (void)n_in; (void)out_size; (void)ws_size;

    char* ws = (char*)d_ws;
    const size_t SZ_Q  = (size_t)BN*HH*SS*DD;      //  4.19 MB (fp8)
    const size_t SZ_K  = (size_t)BN*HH*KT*DD;      //  4.26 MB (fp8)
    const size_t SZ_VT = (size_t)BN*HH*DD*KT;      //  4.26 MB (fp8)
    const size_t SZ_E  = (size_t)BN*SS*HH*KT;      // 68.2 MB (fp8)
    const size_t SZ_A  = (size_t)BN*SS*CC*2;       //  8.39 MB (bf16)
    const size_t SZ_A8 = (size_t)BN*SS*CC;         //  4.19 MB (fp8)

    uchar* qf  = (uchar*)(ws);
    uchar* kf  = (uchar*)(ws + SZ_Q);
    uchar* vt  = (uchar*)(ws + SZ_Q + SZ_K);
    uchar* E   = (uchar*)(ws + SZ_Q + SZ_K + SZ_VT);
    short* AO  = (short*)(ws + SZ_Q + SZ_K + SZ_VT + SZ_E);
    char*  wend = ws + SZ_Q + SZ_K + SZ_VT + SZ_E + SZ_A;
    short* Bfc = (short*)(wend);
    uchar* Bc1 = (uchar*)(wend + 512*512*2);
    uchar* Bc2 = (uchar*)(wend + 512*512*2 + 512*1536);
    short* Bqkv= (short*)(wend + 512*512*2 + 2*512*1536);
    uchar* xres8 = (uchar*)(wend + 512*512*2 + 2*512*1536 + 3*64*64*2);
    short* c2buf = (short*)(wend + 512*512*2 + 2*512*1536 + 3*64*64*2 + SZ_A8);
    // Aliases (dead regions): xres(bf16) over qf+kf (dead after energy);
    // h1(fp8) over E (dead after pv).
    short* xres = (short*)(ws);
    uchar* h18  = (uchar*)E;
    // total ws ~= 103 MB (ws_size >= 256 MiB)

    {
        int total = 512*512 + 2*512*1536 + 3*64*64 + BN*HH*PP*DD;
        prep_kernel<<<(total + 255)/256, 256, 0, stream>>>(
            fc_w, c1w, c2w, Wq, Wk, Wv, th_post, pk, pv,
            Bfc, Bc1, Bc2, Bqkv, kf, vt);
    }
    qkv_mfma<<<dim3(BN*SS/64, HH), 256, 0, stream>>>(x, Bqkv, qf, kf, vt);

    energy_mfma8<<<dim3(16, 64), 256, 0, stream>>>(qf, kf, E);
    softmax_kernel<<<BN*SS/4, 256, 0, stream>>>(E, mask, th_pre);
    pv_mfma<<<dim3(16, 64), 256, 0, stream>>>(E, vt, AO);

    fc_mfma<<<dim3(8, 128), 256, 0, stream>>>(AO, Bfc, fc_b, x, xres, xres8);
    conv_mfma8<<<dim3(8, 128), 256, 0, stream>>>(xres8, Bc1, c1b, h18, (short*)nullptr, 1);
    conv_mfma8<<<dim3(8, 128), 256, 0, stream>>>(h18, Bc2, c2b, (uchar*)nullptr, c2buf, 0);
    final_kernel<<<BN*SS/4, 256, 0, stream>>>(c2buf, xres, mask, lng, lnb, out);
}

// Round 21
// 283.849 us; speedup vs baseline: 1.7686x; 1.0077x over previous
//
#include <hip/hip_runtime.h>
#include <hip/hip_bf16.h>

#define BN 8
#define SS 1024
#define CC 512
#define HH 8
#define DD 64
#define PP 16
#define KT 1040

typedef __hip_bfloat16 bf16;
typedef unsigned char uchar;
typedef unsigned short ushort;
typedef unsigned int uint;
typedef __attribute__((ext_vector_type(8))) short short8;
typedef __attribute__((ext_vector_type(4))) float f32x4;
typedef __attribute__((ext_vector_type(2))) float f32x2;

__device__ __forceinline__ short f2s(float v){ bf16 b = __float2bfloat16(v); return *(short*)&b; }
__device__ __forceinline__ float s2f(short s){ bf16 b; *(short*)&b = s; return __bfloat162float(b); }
__device__ __forceinline__ uchar f2q(float v){          // f32 -> fp8 e4m3 byte
    return (uchar)__builtin_amdgcn_cvt_pk_fp8_f32(v, v, 0, false);
}

#define MFMA16(a,b,c)  __builtin_amdgcn_mfma_f32_16x16x32_bf16(a,b,c,0,0,0)
#define MFMAF8(a,b,c)  __builtin_amdgcn_mfma_f32_16x16x32_fp8_fp8(a,b,c,0,0,0)

// ---------------------------------------------------------------------------
// P0: weight pre-conversion + persistent-token tails.
// ---------------------------------------------------------------------------
__global__ __launch_bounds__(256) void prep_kernel(
    const float* __restrict__ fc_w, const float* __restrict__ c1w,
    const float* __restrict__ c2w, const float* __restrict__ Wq,
    const float* __restrict__ Wk, const float* __restrict__ Wv,
    const float* __restrict__ th_post,
    const float* __restrict__ pk, const float* __restrict__ pv,
    short* __restrict__ Bfc, uchar* __restrict__ Bc1,
    uchar* __restrict__ Bc2, short* __restrict__ Bqkv,
    uchar* __restrict__ kf, uchar* __restrict__ vt)
{
    int i = blockIdx.x*256 + threadIdx.x;
    const int NFC = 512*512, NCV = 512*1536, NQ = 3*64*64, NP = BN*HH*PP*DD;
    if (i < NFC) {
        int c = i >> 9, r = i & 511;
        int g = r >> 6, d = r & 63;
        float s = 0.f;
        #pragma unroll
        for (int h = 0; h < 8; ++h)
            s += fc_w[(size_t)c*512 + h*64 + d] * th_post[h*8 + g];
        Bfc[i] = f2s(s);
        return;
    }
    i -= NFC;
    if (i < NCV) {
        int o = i/1536, r = i%1536, dk = r>>9, ci = r&511;
        Bc1[i] = f2q(c1w[(o*512+ci)*3+dk] * 16.f); return;
    }
    i -= NCV;
    if (i < NCV) {
        int o = i/1536, r = i%1536, dk = r>>9, ci = r&511;
        Bc2[i] = f2q(c2w[(o*512+ci)*3+dk] * 16.f); return;
    }
    i -= NCV;
    if (i < NQ) {
        int w = i >> 12, rest = i & 4095;
        const float* W = (w==0)?Wq:(w==1)?Wk:Wv;
        Bqkv[i] = f2s(W[((rest>>6)&63)*64 + (rest&63)]);
        return;
    }
    i -= NQ;
    if (i < NP) {
        int d = i & 63, p = (i >> 6) & 15, h = (i >> 10) & 7, n = i >> 13;
        size_t src = ((size_t)p*HH + h)*DD + d;
        kf[(((size_t)(n*HH+h))*KT + SS + p)*DD + d] = f2q(pk[src]);
        vt[(((size_t)(n*HH+h))*DD + d)*KT + SS + p] = f2q(pv[src]);
    }
}

// ---------------------------------------------------------------------------
// K1 v2: QKV projection, bf16 MFMA, XCD-swizzled: each XCD owns 16 m-tiles
// x all 8 heads (x working set 2 MB per XCD L2 -> x fetched once per XCD).
// q/k out fp8 [s][d]; V -> transposed fp8 vt[nh][d][k=s].
// ---------------------------------------------------------------------------
__global__ __launch_bounds__(256) void qkv_mfma(
    const float* __restrict__ x, const short* __restrict__ Bqkv,
    uchar* __restrict__ qf, uchar* __restrict__ kf, uchar* __restrict__ vt)
{
    __shared__ short Xs[64*72];
    __shared__ short Ws[192*72];
    const int tid = threadIdx.x;
    const int lin = blockIdx.x;                     // grid 1024 linear
    const int xcd = lin & 7, slot = lin >> 3;       // slot in [0,128)
    const int m0 = (xcd*16 + (slot & 15))*64;
    const int h = slot >> 4;
    const int wave = tid >> 6, lane = tid & 63;
    const int lr = lane & 15, lq = lane >> 4;

    for (int i = tid; i < 1024; i += 256) {
        int r = i >> 4, cg = (i & 15)*4;
        float4 v = *(const float4*)(x + (size_t)(m0+r)*CC + h*64 + cg);
        Xs[r*72+cg+0] = f2s(v.x); Xs[r*72+cg+1] = f2s(v.y);
        Xs[r*72+cg+2] = f2s(v.z); Xs[r*72+cg+3] = f2s(v.w);
    }
    for (int i = tid; i < 3072; i += 256) {
        int r = i >> 4, cg = (i & 15)*4;
        *(short4*)(Ws + r*72 + cg) = *(const short4*)(Bqkv + (size_t)r*64 + cg);
    }
    __syncthreads();

    f32x4 acc[12];
    #pragma unroll
    for (int nt = 0; nt < 12; ++nt) acc[nt] = {0.f,0.f,0.f,0.f};
    #pragma unroll
    for (int ks = 0; ks < 2; ++ks) {
        int ko = ks*32 + lq*8;
        short8 a = *(const short8*)(Xs + (wave*16 + lr)*72 + ko);
        #pragma unroll
        for (int nt = 0; nt < 12; ++nt) {
            short8 b = *(const short8*)(Ws + (nt*16 + lr)*72 + ko);
            acc[nt] = MFMA16(a, b, acc[nt]);
        }
    }
    #pragma unroll
    for (int nt = 0; nt < 12; ++nt) {
        int ep = nt*16 + lr;
        int w = ep >> 6, e = ep & 63;
        #pragma unroll
        for (int reg = 0; reg < 4; ++reg) {
            int m = m0 + wave*16 + lq*4 + reg;
            int n = m >> 10, s = m & 1023;
            float v = acc[nt][reg];
            if (w == 0)      qf[((size_t)(n*HH+h)*SS + s)*DD + e] = f2q(v);
            else if (w == 1) kf[((size_t)(n*HH+h)*KT + s)*DD + e] = f2q(v);
            else             vt[(((size_t)(n*HH+h))*DD + e)*KT + s] = f2q(v);
        }
    }
}

// ---------------------------------------------------------------------------
// K2 v3: energy, fp8 MFMA NT, XCD-swizzled (each XCD owns 8 consecutive nh).
// ---------------------------------------------------------------------------
__device__ __forceinline__ void en_loadK(const uchar* __restrict__ kf,
    int nh, int kt, int tid, uint2* rk)
{
    #pragma unroll
    for (int j = 0; j < 2; ++j) {
        int i = tid + j*256;
        int r = i >> 3, c8 = (i & 7)*8;
        int kcol = kt*64 + r;
        uint2 v = {0u, 0u};
        if (kcol < KT)
            v = *(const uint2*)(kf + ((size_t)nh*KT + kcol)*DD + c8);
        rk[j] = v;
    }
}

__global__ __launch_bounds__(256) void energy_mfma8(
    const uchar* __restrict__ qf, const uchar* __restrict__ kf,
    uchar* __restrict__ E)
{
    __shared__ uchar Qs[64*72];
    __shared__ uchar Ks[64*72];
    const int tid = threadIdx.x;
    const int lin = blockIdx.x + 16*blockIdx.y;     // grid (16, 64)
    const int xcd = lin & 7, slot = lin >> 3;       // slot in [0,128)
    const int nh = xcd*8 + (slot & 7);
    const int mt = slot >> 3;
    const int wave = tid >> 6, lane = tid & 63;
    const int lr = lane & 15, lq = lane >> 4;
    const int n = nh >> 3, h = nh & 7;

    #pragma unroll
    for (int j = 0; j < 2; ++j) {
        int i = tid + j*256;
        int r = i >> 3, c8 = (i & 7)*8;
        *(uint2*)(Qs + r*72 + c8) =
            *(const uint2*)(qf + ((size_t)nh*SS + mt*64 + r)*DD + c8);
    }

    uint2 rk[2];
    en_loadK(kf, nh, 0, tid, rk);

    for (int kt = 0; kt < 17; ++kt) {
        if (kt) __syncthreads();
        #pragma unroll
        for (int j = 0; j < 2; ++j) {
            int i = tid + j*256;
            *(uint2*)(Ks + (i >> 3)*72 + (i & 7)*8) = rk[j];
        }
        __syncthreads();
        if (kt + 1 < 17) en_loadK(kf, nh, kt+1, tid, rk);

        f32x4 acc[4];
        #pragma unroll
        for (int nt = 0; nt < 4; ++nt) acc[nt] = {0.f,0.f,0.f,0.f};
        #pragma unroll
        for (int ks = 0; ks < 2; ++ks) {
            int ko = ks*32 + lq*8;
            long a = *(const long*)(Qs + (wave*16 + lr)*72 + ko);
            #pragma unroll
            for (int nt = 0; nt < 4; ++nt) {
                long b = *(const long*)(Ks + (nt*16 + lr)*72 + ko);
                acc[nt] = MFMAF8(a, b, acc[nt]);
            }
        }
        #pragma unroll
        for (int nt = 0; nt < 4; ++nt) {
            int kcol = kt*64 + nt*16 + lr;
            if (kcol >= KT) continue;
            #pragma unroll
            for (int reg = 0; reg < 4; ++reg) {
                int q = mt*64 + wave*16 + lq*4 + reg;
                E[(((size_t)(n*SS + q))*HH + h)*KT + kcol] = f2q(acc[nt][reg]);
            }
        }
    }
}

// ---------------------------------------------------------------------------
// K3: softmax (r17 single-row body — 52 VGPR sweet spot): no-max, fp8
// in/out, premix in-kernel, postmix folded into fc. Grid BN*SS.
// ---------------------------------------------------------------------------
__global__ __launch_bounds__(256) void softmax_kernel(
    uchar* __restrict__ E, const int* __restrict__ mask,
    const float* __restrict__ th_pre)
{
    __shared__ float thp[64];
    __shared__ float wred[4][8];
    const int tid = threadIdx.x;
    const int wave = tid >> 6, lane = tid & 63;
    const int blk = blockIdx.x;              // n*SS + q
    const int n = blk >> 10, q = blk & 1023;
    const float invs = 0.044194173824159216f;   // 1/sqrt(512)
    const float l2e  = 1.4426950408889634f;
    if (tid < 64) thp[tid] = th_pre[tid]*(invs*l2e);
    __syncthreads();
    uchar* Eb = E + (size_t)blk*HH*KT;

    const float sl[8] = {0.5f,0.25f,0.125f,0.0625f,
                         0.03125f,0.015625f,0.0078125f,0.00390625f};
    const int* mrow = mask + (size_t)n*SS*SS + (size_t)q*SS;

    const int k0 = tid*4;                    // 4 adjacent columns
    const int4 mk = *(const int4*)(mrow + k0);
    f32x4 dist;
    dist.x = fabsf((float)(q - k0));
    dist.y = fabsf((float)(q - k0 - 1));
    dist.z = fabsf((float)(q - k0 - 2));
    dist.w = fabsf((float)(q - k0 - 3));

    f32x4 tp[8];
    float tl[8];
    float sm[8];
    #pragma unroll
    for (int g = 0; g < 8; ++g) { sm[g] = 0.f; tl[g] = 0.f; }

    {
        f32x4 a[8];
        #pragma unroll
        for (int g = 0; g < 8; ++g) {
            uint u = *(const uint*)(Eb + g*KT + k0);
            f32x2 lo = __builtin_amdgcn_cvt_pk_f32_fp8((int)u, false);
            f32x2 hi = __builtin_amdgcn_cvt_pk_f32_fp8((int)u, true);
            f32x4 r; r.x = lo.x; r.y = lo.y; r.z = hi.x; r.w = hi.y;
            a[g] = r - dist*sl[g];
        }
        #pragma unroll
        for (int h = 0; h < 8; ++h) {
            f32x4 t = {0.f,0.f,0.f,0.f};
            #pragma unroll
            for (int g = 0; g < 8; ++g)
                t += a[g] * thp[h*8 + g];    // packed-f32 FMA candidates
            f32x4 e;
            e.x = (mk.x == 0) ? 0.f : exp2f(t.x);
            e.y = (mk.y == 0) ? 0.f : exp2f(t.y);
            e.z = (mk.z == 0) ? 0.f : exp2f(t.z);
            e.w = (mk.w == 0) ? 0.f : exp2f(t.w);
            tp[h] = e;
            sm[h] += e.x + e.y + e.z + e.w;
        }
    }
    if (tid < 16) {                          // persistent keys
        const int k = 1024 + tid;
        float a[8];
        #pragma unroll
        for (int g = 0; g < 8; ++g) {
            f32x2 r = __builtin_amdgcn_cvt_pk_f32_fp8((int)Eb[g*KT + k], false);
            a[g] = r.x;
        }
        #pragma unroll
        for (int h = 0; h < 8; ++h) {
            float t = 0.f;
            #pragma unroll
            for (int g = 0; g < 8; ++g) t = fmaf(thp[h*8 + g], a[g], t);
            float e = exp2f(t);
            tl[h] = e;
            sm[h] += e;
        }
    }
    #pragma unroll
    for (int g = 0; g < 8; ++g) {
        #pragma unroll
        for (int off = 32; off > 0; off >>= 1)
            sm[g] += __shfl_xor(sm[g], off);
    }
    if (lane == 0) {
        #pragma unroll
        for (int g = 0; g < 8; ++g) wred[wave][g] = sm[g];
    }
    __syncthreads();
    float lred[8];
    #pragma unroll
    for (int g = 0; g < 8; ++g)
        lred[g] = 1.0f / (wred[0][g] + wred[1][g] + wred[2][g] + wred[3][g]);

    // normalized probs out: one uint store per head
    #pragma unroll
    for (int h = 0; h < 8; ++h) {
        f32x4 e = tp[h] * lred[h];
        int p = __builtin_amdgcn_cvt_pk_fp8_f32(e.x, e.y, 0, false);
        p = __builtin_amdgcn_cvt_pk_fp8_f32(e.z, e.w, p, true);
        *(uint*)(Eb + h*KT + k0) = (uint)p;
    }
    if (tid < 16) {
        const int k = 1024 + tid;
        #pragma unroll
        for (int g = 0; g < 8; ++g)
            Eb[g*KT + k] = f2q(tl[g] * lred[g]);
    }
}

// ---------------------------------------------------------------------------
// K4 v3: PV fp8 MFMA, q-tile 64, XCD-swizzled (each XCD owns 8 nh).
// ---------------------------------------------------------------------------
__device__ __forceinline__ void pv_loadP(const uchar* __restrict__ E,
    int n, int h, int ql0, int kt, int tid, uint2* rp)
{
    #pragma unroll
    for (int j = 0; j < 2; ++j) {
        int i = tid + j*256;
        int r = i >> 3, cg = (i & 7)*8;
        int k = kt*64 + cg;
        uint2 v = {0u, 0u};
        if (k < KT)
            v = *(const uint2*)(E + (((size_t)(n*SS + ql0 + r))*HH + h)*KT + k);
        rp[j] = v;
    }
}
__device__ __forceinline__ void pv_loadV(const uchar* __restrict__ vt,
    int nh, int kt, int tid, uint2* rv)
{
    #pragma unroll
    for (int j = 0; j < 2; ++j) {
        int i = tid + j*256;
        int r = i >> 3, cg = (i & 7)*8;
        int k = kt*64 + cg;
        uint2 v = {0u, 0u};
        if (k < KT)
            v = *(const uint2*)(vt + ((size_t)nh*DD + r)*KT + k);
        rv[j] = v;
    }
}

__global__ __launch_bounds__(256) void pv_mfma(
    const uchar* __restrict__ E, const uchar* __restrict__ vt,
    short* __restrict__ AO)
{
    __shared__ uchar Ps[64*72];
    __shared__ uchar Vs[64*72];
    const int tid = threadIdx.x;
    const int lin = blockIdx.x + 16*blockIdx.y;     // grid (16, 64)
    const int xcd = lin & 7, slot = lin >> 3;
    const int nh = xcd*8 + (slot & 7);
    const int ql0 = (slot >> 3) * 64;
    const int n = nh >> 3, h = nh & 7;
    const int wave = tid >> 6, lane = tid & 63;
    const int lr = lane & 15, lq = lane >> 4;
    const int mq = (wave & 1)*32, nq = (wave >> 1)*32;

    uint2 rp[2], rv[2];
    pv_loadP(E, n, h, ql0, 0, tid, rp);
    pv_loadV(vt, nh, 0, tid, rv);

    f32x4 acc[2][2];
    #pragma unroll
    for (int i = 0; i < 2; ++i)
        #pragma unroll
        for (int j = 0; j < 2; ++j) acc[i][j] = {0.f,0.f,0.f,0.f};

    for (int kt = 0; kt < 17; ++kt) {
        if (kt) __syncthreads();
        #pragma unroll
        for (int j = 0; j < 2; ++j) {
            int i = tid + j*256;
            *(uint2*)(Ps + (i >> 3)*72 + (i & 7)*8) = rp[j];
        }
        #pragma unroll
        for (int j = 0; j < 2; ++j) {
            int i = tid + j*256;
            *(uint2*)(Vs + (i >> 3)*72 + (i & 7)*8) = rv[j];
        }
        __syncthreads();
        if (kt + 1 < 17) {
            pv_loadP(E, n, h, ql0, kt+1, tid, rp);
            pv_loadV(vt, nh, kt+1, tid, rv);
        }
        #pragma unroll
        for (int ks = 0; ks < 2; ++ks) {
            int ko = ks*32 + lq*8;
            long a0 = *(const long*)(Ps + (mq + lr)*72 + ko);
            long a1 = *(const long*)(Ps + (mq + 16 + lr)*72 + ko);
            long b0 = *(const long*)(Vs + (nq + lr)*72 + ko);
            long b1 = *(const long*)(Vs + (nq + 16 + lr)*72 + ko);
            acc[0][0] = MFMAF8(a0, b0, acc[0][0]);
            acc[0][1] = MFMAF8(a0, b1, acc[0][1]);
            acc[1][0] = MFMAF8(a1, b0, acc[1][0]);
            acc[1][1] = MFMAF8(a1, b1, acc[1][1]);
        }
    }
    #pragma unroll
    for (int mt = 0; mt < 2; ++mt)
        #pragma unroll
        for (int nt = 0; nt < 2; ++nt) {
            int d = nq + nt*16 + lr;
            #pragma unroll
            for (int reg = 0; reg < 4; ++reg) {
                int qg = ql0 + mq + mt*16 + lq*4 + reg;
                AO[((size_t)(n*SS) + qg)*CC + h*64 + d] = f2s(acc[mt][nt][reg]);
            }
        }
}

// ---------------------------------------------------------------------------
// K5: fc (th_post folded into weights), bf16 MFMA, 64x64, XCD-swizzled.
// ---------------------------------------------------------------------------
__device__ __forceinline__ void g_load4(const short* __restrict__ src,
    size_t rowstride, int row0, int col0, int tid, short4* r)
{
    #pragma unroll
    for (int j = 0; j < 4; ++j) {
        int i = tid + j*256;
        int rr = i >> 4, cg = (i & 15)*4;
        r[j] = *(const short4*)(src + (size_t)(row0 + rr)*rowstride + col0 + cg);
    }
}
__device__ __forceinline__ void lds_store4(short* __restrict__ dst,
    int tid, const short4* r)
{
    #pragma unroll
    for (int j = 0; j < 4; ++j) {
        int i = tid + j*256;
        *(short4*)(dst + (i >> 4)*72 + (i & 15)*4) = r[j];
    }
}

__global__ __launch_bounds__(256) void fc_mfma(
    const short* __restrict__ A, const short* __restrict__ Bt,
    const float* __restrict__ bias, const float* __restrict__ x,
    short* __restrict__ out, uchar* __restrict__ out8)
{
    __shared__ short As[64*72];
    __shared__ short Bs[64*72];
    const int tid = threadIdx.x;
    const int lin = blockIdx.x + 8*blockIdx.y;      // grid (8,128)
    const int xcd = lin & 7, slot = lin >> 3;
    const int m0 = (xcd*16 + (slot & 15))*64;
    const int n0 = (slot >> 4)*64;
    const int wave = tid >> 6, lane = tid & 63;
    const int lr = lane & 15, lq = lane >> 4;

    short4 ra[4], rb[4];
    g_load4(A, CC, m0, 0, tid, ra);
    g_load4(Bt, CC, n0, 0, tid, rb);

    f32x4 acc[4];
    #pragma unroll
    for (int nt = 0; nt < 4; ++nt) acc[nt] = {0.f,0.f,0.f,0.f};

    for (int kt = 0; kt < CC; kt += 64) {
        if (kt) __syncthreads();
        lds_store4(As, tid, ra);
        lds_store4(Bs, tid, rb);
        __syncthreads();
        if (kt + 64 < CC) {
            g_load4(A, CC, m0, kt+64, tid, ra);
            g_load4(Bt, CC, n0, kt+64, tid, rb);
        }
        #pragma unroll
        for (int ks = 0; ks < 2; ++ks) {
            int ko = ks*32 + lq*8;
            short8 a = *(const short8*)(As + (wave*16 + lr)*72 + ko);
            #pragma unroll
            for (int nt = 0; nt < 4; ++nt) {
                short8 b = *(const short8*)(Bs + (nt*16 + lr)*72 + ko);
                acc[nt] = MFMA16(a, b, acc[nt]);
            }
        }
    }
    #pragma unroll
    for (int nt = 0; nt < 4; ++nt) {
        int nn = n0 + nt*16 + lr;
        #pragma unroll
        for (int reg = 0; reg < 4; ++reg) {
            int m = m0 + wave*16 + lq*4 + reg;
            float v = acc[nt][reg] + bias[nn] + x[(size_t)m*CC + nn];
            out[(size_t)m*CC + nn]  = f2s(v);
            out8[(size_t)m*CC + nn] = f2q(v);
        }
    }
}

// ---------------------------------------------------------------------------
// K6 v2: causal conv fp8 NT GEMM, BK=128 (12 K-iters), XCD-swizzled.
// ---------------------------------------------------------------------------
__device__ __forceinline__ void conv_loadA8w(const uchar* __restrict__ A,
    int m0, int kt, int tid, uint2* ra)
{
    const int shift = (kt >> 9) - 2;
    const int ci0 = kt & 511;
    #pragma unroll
    for (int j = 0; j < 4; ++j) {
        int i = tid + j*256;
        int rr = i >> 4, c8 = (i & 15)*8;
        int m = m0 + rr;
        int s = m & (SS-1);
        uint2 v = {0u, 0u};
        if (s + shift >= 0)
            v = *(const uint2*)(A + (size_t)(m + shift)*CC + ci0 + c8);
        ra[j] = v;
    }
}
__device__ __forceinline__ void g_load8w(const uchar* __restrict__ src,
    size_t rowstride, int row0, int col0, int tid, uint2* r)
{
    #pragma unroll
    for (int j = 0; j < 4; ++j) {
        int i = tid + j*256;
        int rr = i >> 4, c8 = (i & 15)*8;
        r[j] = *(const uint2*)(src + (size_t)(row0 + rr)*rowstride + col0 + c8);
    }
}
__device__ __forceinline__ void lds_store8w(uchar* __restrict__ dst,
    int tid, const uint2* r)
{
    #pragma unroll
    for (int j = 0; j < 4; ++j) {
        int i = tid + j*256;
        *(uint2*)(dst + (i >> 4)*136 + (i & 15)*8) = r[j];
    }
}

__global__ __launch_bounds__(256) void conv_mfma8(
    const uchar* __restrict__ A, const uchar* __restrict__ Bt,
    const float* __restrict__ bias, uchar* __restrict__ out8,
    short* __restrict__ out16, int f8out)
{
    __shared__ uchar As[64*136];
    __shared__ uchar Bs[64*136];
    const int tid = threadIdx.x;
    const int lin = blockIdx.x + 8*blockIdx.y;      // grid (8,128)
    const int xcd = lin & 7, slot = lin >> 3;
    const int m0 = (xcd*16 + (slot & 15))*64;
    const int n0 = (slot >> 4)*64;
    const int wave = tid >> 6, lane = tid & 63;
    const int lr = lane & 15, lq = lane >> 4;

    uint2 ra[4], rb[4];
    conv_loadA8w(A, m0, 0, tid, ra);
    g_load8w(Bt, 1536, n0, 0, tid, rb);

    f32x4 acc[4];
    #pragma unroll
    for (int nt = 0; nt < 4; ++nt) acc[nt] = {0.f,0.f,0.f,0.f};

    for (int kt = 0; kt < 1536; kt += 128) {
        if (kt) __syncthreads();
        lds_store8w(As, tid, ra);
        lds_store8w(Bs, tid, rb);
        __syncthreads();
        if (kt + 128 < 1536) {
            conv_loadA8w(A, m0, kt+128, tid, ra);
            g_load8w(Bt, 1536, n0, kt+128, tid, rb);
        }
        #pragma unroll
        for (int ks = 0; ks < 4; ++ks) {
            int ko = ks*32 + lq*8;
            long a = *(const long*)(As + (wave*16 + lr)*136 + ko);
            #pragma unroll
            for (int nt = 0; nt < 4; ++nt) {
                long b = *(const long*)(Bs + (nt*16 + lr)*136 + ko);
                acc[nt] = MFMAF8(a, b, acc[nt]);
            }
        }
    }
    #pragma unroll
    for (int nt = 0; nt < 4; ++nt) {
        int nn = n0 + nt*16 + lr;
        #pragma unroll
        for (int reg = 0; reg < 4; ++reg) {
            int m = m0 + wave*16 + lq*4 + reg;
            float v = fmaxf(acc[nt][reg]*0.0625f + bias[nn], 0.f);
            if (f8out) out8[(size_t)m*CC + nn]  = f2q(v);
            else       out16[(size_t)m*CC + nn] = f2s(v);
        }
    }
}

// ---------------------------------------------------------------------------
// K7: out = LN(relu(c2 + xres) masked) * g + b.  4 rows per block.
// ---------------------------------------------------------------------------
__global__ __launch_bounds__(256) void final_kernel(
    const short* __restrict__ c2, const short* __restrict__ xres,
    const int* __restrict__ mask, const float* __restrict__ g,
    const float* __restrict__ b, float* __restrict__ out)
{
    __shared__ float red[256];
    const int tid = threadIdx.x;
    const int m0 = blockIdx.x * 4;
    const int c0 = tid*2;
    const float2 gg = *(const float2*)(g + c0);
    const float2 bb = *(const float2*)(b + c0);

    for (int rr = 0; rr < 4; ++rr) {
        const int m = m0 + rr;
        const int n = m >> 10, s = m & 1023;
        const int mk = mask[(size_t)n*SS*SS + (size_t)s*SS];

        short2 ca = *(const short2*)(c2 + (size_t)m*CC + c0);
        short2 xa = *(const short2*)(xres + (size_t)m*CC + c0);
        float v0 = fmaxf(s2f(ca.x) + s2f(xa.x), 0.f);
        float v1 = fmaxf(s2f(ca.y) + s2f(xa.y), 0.f);
        if (mk == 0) { v0 = 0.f; v1 = 0.f; }

        red[tid] = v0 + v1;
        __syncthreads();
        for (int off = 128; off > 0; off >>= 1) {
            if (tid < off) red[tid] += red[tid + off];
            __syncthreads();
        }
        float mu = red[0] * (1.0f/512.0f);
        __syncthreads();
        float d0 = v0 - mu, d1 = v1 - mu;
        red[tid] = d0*d0 + d1*d1;
        __syncthreads();
        for (int off = 128; off > 0; off >>= 1) {
            if (tid < off) red[tid] += red[tid + off];
            __syncthreads();
        }
        float rstd = rsqrtf(red[0] * (1.0f/512.0f) + 1e-5f);
        float2 o;
        o.x = d0*rstd*gg.x + bb.x;
        o.y = d1*rstd*gg.y + bb.y;
        *(float2*)(out + (size_t)m*CC + c0) = o;
        __syncthreads();                     // red reuse next row
    }
}

// ---------------------------------------------------------------------------
extern "C" void kernel_launch(void* const* d_in, const int* in_sizes, int n_in,
                              void* d_out, int out_size, void* d_ws, size_t ws_size,
                              hipStream_t stream)
{
    const float* x      = (const float*)d_in[0];
    const int*   mask   = (const int*)  d_in[1];
    const float* Wq     = (const float*)d_in[2];
    const float* Wk     = (const float*)d_in[3];
    const float* Wv     = (const float*)d_in[4];
    const float* pk     = (const float*)d_in[5];
    const float* pv     = (const float*)d_in[6];
    const float* th_pre = (const float*)d_in[7];
    const float* th_post= (const float*)d_in[8];
    const float* fc_w   = (const float*)d_in[9];
    const float* fc_b   = (const float*)d_in[10];
    const float* c1w    = (const float*)d_in[11];
    const float* c1b    = (const float*)d_in[12];
    const float* c2w    = (const float*)d_in[13];
    const float* c2b    = (const float*)d_in[14];
    const float* lng    = (const float*)d_in[15];
    const float* lnb    = (const float*)d_in[16];
    float* out = (float*)d_out;
    (void)in_sizes; (void)n_in; (void)out_size; (void)ws_size;

    char* ws = (char*)d_ws;
    const size_t SZ_Q  = (size_t)BN*HH*SS*DD;      //  4.19 MB (fp8)
    const size_t SZ_K  = (size_t)BN*HH*KT*DD;      //  4.26 MB (fp8)
    const size_t SZ_VT = (size_t)BN*HH*DD*KT;      //  4.26 MB (fp8)
    const size_t SZ_E  = (size_t)BN*SS*HH*KT;      // 68.2 MB (fp8)
    const size_t SZ_A  = (size_t)BN*SS*CC*2;       //  8.39 MB (bf16)
    const size_t SZ_A8 = (size_t)BN*SS*CC;         //  4.19 MB (fp8)

    uchar* qf  = (uchar*)(ws);
    uchar* kf  = (uchar*)(ws + SZ_Q);
    uchar* vt  = (uchar*)(ws + SZ_Q + SZ_K);
    uchar* E   = (uchar*)(ws + SZ_Q + SZ_K + SZ_VT);
    short* AO  = (short*)(ws + SZ_Q + SZ_K + SZ_VT + SZ_E);
    char*  wend = ws + SZ_Q + SZ_K + SZ_VT + SZ_E + SZ_A;
    short* Bfc = (short*)(wend);
    uchar* Bc1 = (uchar*)(wend + 512*512*2);
    uchar* Bc2 = (uchar*)(wend + 512*512*2 + 512*1536);
    short* Bqkv= (short*)(wend + 512*512*2 + 2*512*1536);
    uchar* xres8 = (uchar*)(wend + 512*512*2 + 2*512*1536 + 3*64*64*2);
    short* c2buf = (short*)(wend + 512*512*2 + 2*512*1536 + 3*64*64*2 + SZ_A8);
    // Aliases (dead regions): xres(bf16) over qf+kf (dead after energy);
    // h1(fp8) over E (dead after pv).
    short* xres = (short*)(ws);
    uchar* h18  = (uchar*)E;
    // total ws ~= 103 MB (ws_size >= 256 MiB)

    {
        int total = 512*512 + 2*512*1536 + 3*64*64 + BN*HH*PP*DD;
        prep_kernel<<<(total + 255)/256, 256, 0, stream>>>(
            fc_w, c1w, c2w, Wq, Wk, Wv, th_post, pk, pv,
            Bfc, Bc1, Bc2, Bqkv, kf, vt);
    }
    qkv_mfma<<<BN*SS/64*HH, 256, 0, stream>>>(x, Bqkv, qf, kf, vt);

    energy_mfma8<<<dim3(16, 64), 256, 0, stream>>>(qf, kf, E);
    softmax_kernel<<<BN*SS, 256, 0, stream>>>(E, mask, th_pre);
    pv_mfma<<<dim3(16, 64), 256, 0, stream>>>(E, vt, AO);

    fc_mfma<<<dim3(8, 128), 256, 0, stream>>>(AO, Bfc, fc_b, x, xres, xres8);
    conv_mfma8<<<dim3(8, 128), 256, 0, stream>>>(xres8, Bc1, c1b, h18, (short*)nullptr, 1);
    conv_mfma8<<<dim3(8, 128), 256, 0, stream>>>(h18, Bc2, c2b, (uchar*)nullptr, c2buf, 0);
    final_kernel<<<BN*SS/4, 256, 0, stream>>>(c2buf, xres, mask, lng, lnb, out);
}